// Round 11
// baseline (436.189 us; speedup 1.0000x reference)
//
#include <hip/hip_runtime.h>
#include <hip/hip_bf16.h>

// ---------------- sizes ----------------
#define BATCH 128
#define IMG   28
#define NCAP  1152          // 32*36
#define KDIM  20736         // 256*81
#define HLO_DELTA 13107200  // h_hi -> h_lo element delta (shorts)
#define WLO_DELTA 5308416   // wt_hi -> wt_lo element delta (shorts)

// ws offsets in floats
#define WT_OFF   ((size_t)0)            // wt hi+lo bf16 = 5308416 floats
#define U_OFF    ((size_t)0)            // alias wt (dead after conv2m)
#define H_OFF    ((size_t)5308416)      // h hi+lo bf16 = 13107200 floats
#define UH_OFF   (H_OFF)                // alias h (dead after conv2m): uh bf16 = 11796480 floats
#define H1_OFF   (H_OFF + (size_t)11796480)
#define W1T_OFF  ((size_t)18415616)     // 20736 floats
#define PACC_OFF ((size_t)18436352)     // nz*4608*256 floats

using short8v = __attribute__((ext_vector_type(8))) short;
using f32x4   = __attribute__((ext_vector_type(4))) float;

__device__ inline void split2(float x, __hip_bfloat16& hi, __hip_bfloat16& lo)
{
    hi = __float2bfloat16(x);
    lo = __float2bfloat16(x - __bfloat162float(hi));
}
__device__ inline float bf16s2f(short s)
{
    return __uint_as_float(((unsigned)(unsigned short)s) << 16);
}

// ---------------- W1 (256,81) -> w1t (81,256) ----------------
__global__ __launch_bounds__(256) void k_w1t(const float* __restrict__ w1, float* __restrict__ w1t)
{
    __shared__ float lds[16 * 81];
    const int r0 = blockIdx.x * 16;
    const int tid = threadIdx.x;
    for (int idx = tid; idx < 16 * 81; idx += 256)
        lds[idx] = w1[(size_t)(r0 + idx / 81) * 81 + (idx % 81)];
    __syncthreads();
    for (int idx = tid; idx < 81 * 16; idx += 256) {
        const int i = idx >> 4, rl = idx & 15;
        w1t[(size_t)i * 256 + r0 + rl] = lds[rl * 81 + i];
    }
}

// ---------------- merged: blocks [0,256) = Wp->wt transpose+split; [256,768) = conv1 ----------------
__global__ __launch_bounds__(256) void k_pre(const float* __restrict__ wp,
                                             const float* __restrict__ img,
                                             const float* __restrict__ w1t,
                                             const float* __restrict__ b1,
                                             __hip_bfloat16* __restrict__ wt,
                                             __hip_bfloat16* __restrict__ h)
{
    __shared__ float shl[64 * 82];
    const int tid = threadIdx.x;
    if (blockIdx.x < 256) {
        // ---- Wp (256,256,9,9) -> Wt [co][t][ci] bf16 hi/lo ----
        const int co = blockIdx.x;
        for (int ci0 = 0; ci0 < 256; ci0 += 64) {
            for (int idx = tid; idx < 64 * 81; idx += 256) {
                const int cil = idx / 81, t = idx - cil * 81;
                shl[cil * 82 + t] = wp[(size_t)co * KDIM + (size_t)(ci0 + cil) * 81 + t];
            }
            __syncthreads();
            for (int idx = tid; idx < 81 * 64; idx += 256) {
                const int t = idx >> 6, cil = idx & 63;
                __hip_bfloat16 hi, lo;
                split2(shl[cil * 82 + t], hi, lo);
                const size_t o = (size_t)co * KDIM + (size_t)t * 256 + ci0 + cil;
                wt[o] = hi;
                wt[o + WLO_DELTA] = lo;
            }
            __syncthreads();
        }
    } else {
        // ---- conv1: 28x28x1 -> 20x20x256 (NHWC, bf16 hi/lo), relu ----
        const int idx = blockIdx.x - 256;
        const int b = idx >> 2;
        const int y0 = (idx & 3) * 5;
        float* simg = shl;
        for (int i = tid; i < IMG * IMG; i += 256) simg[i] = img[(size_t)b * IMG * IMG + i];
        float w[81];
#pragma unroll
        for (int i = 0; i < 81; ++i) w[i] = w1t[(size_t)i * 256 + tid];
        const float bias = b1[tid];
        __syncthreads();
        for (int y = y0; y < y0 + 5; ++y) {
            for (int xg = 0; xg < 5; ++xg) {
                float a0 = 0.f, a1 = 0.f, a2 = 0.f, a3 = 0.f;
#pragma unroll
                for (int ky = 0; ky < 9; ++ky) {
                    const float* rp = &simg[(y + ky) * IMG + xg * 4];
                    const float4 r0 = *(const float4*)(rp);
                    const float4 r1 = *(const float4*)(rp + 4);
                    const float4 r2 = *(const float4*)(rp + 8);
                    const float rb[12] = {r0.x, r0.y, r0.z, r0.w, r1.x, r1.y, r1.z, r1.w,
                                          r2.x, r2.y, r2.z, r2.w};
#pragma unroll
                    for (int kx = 0; kx < 9; ++kx) {
                        const float wv = w[ky * 9 + kx];
                        a0 += wv * rb[kx + 0];
                        a1 += wv * rb[kx + 1];
                        a2 += wv * rb[kx + 2];
                        a3 += wv * rb[kx + 3];
                    }
                }
                const size_t ob = (((size_t)b * 20 + y) * 20 + xg * 4) * 256 + tid;
                float av[4] = {a0, a1, a2, a3};
#pragma unroll
                for (int q = 0; q < 4; ++q) {
                    __hip_bfloat16 hi, lo;
                    split2(fmaxf(av[q] + bias, 0.f), hi, lo);
                    h[ob + q * 256] = hi;
                    h[ob + q * 256 + HLO_DELTA] = lo;
                }
            }
        }
    }
}

// ---------------- conv2 split-bf16 MFMA implicit GEMM (R5/v4 structure, nz=12) ----------------
__global__ __launch_bounds__(256, 2) void k_conv2m(const __hip_bfloat16* __restrict__ hH,
                                                   const __hip_bfloat16* __restrict__ wH,
                                                   float* __restrict__ pacc,
                                                   int ksteps, int lgci, int ncg, int tpz)
{
    __shared__ short Alds[128 * 64];
    __shared__ short Blds[256 * 64];
    const int q = gridDim.x >> 3;
    const int wg = blockIdx.x;
    const int wgid = (wg & 7) * q + (wg >> 3);
    const int z = wgid / 36;
    const int mt = wgid - z * 36;
    const int tg = z / ncg, cg = z - tg * ncg;
    const int tapbase = tg * tpz;
    const int cibase = cg * (32 << lgci);
    const int cimask = (1 << lgci) - 1;

    const int tid = threadIdx.x;
    const int lane = tid & 63, wid = tid >> 6;
    const int wm = wid >> 1, wn = wid & 1;
    const int lr = lane & 15, kg = lane >> 4;

    const int arow = tid >> 3, asub = tid & 7;
    const int aseg = asub & 3;
    const unsigned lodelA = (asub >= 4) ? (unsigned)HLO_DELTA : 0u;
    const unsigned lodelB = (asub >= 4) ? (unsigned)WLO_DELTA : 0u;

    unsigned aoffA[4];
#pragma unroll
    for (int i = 0; i < 4; ++i) {
        const int row = arow + 32 * i;
        const int m = mt * 128 + row;
        const int bb = m / 36, s = m - bb * 36;
        const int sy = s / 6, sx = s - sy * 6;
        aoffA[i] = (unsigned)((((bb * 20 + 2 * sy) * 20 + 2 * sx) * 256) + aseg * 8) + lodelA;
    }
    unsigned boffB[8];
#pragma unroll
    for (int i = 0; i < 8; ++i)
        boffB[i] = (unsigned)((arow + 32 * i) * KDIM + aseg * 8) + lodelB;
    int awr[4], bwr[8];
#pragma unroll
    for (int i = 0; i < 4; ++i) {
        const int row = arow + 32 * i;
        awr[i] = row * 64 + ((asub * 8) ^ ((row & 7) * 8));
    }
#pragma unroll
    for (int i = 0; i < 8; ++i) {
        const int row = arow + 32 * i;
        bwr[i] = row * 64 + ((asub * 8) ^ ((row & 7) * 8));
    }

    int ardH[4], ardL[4];
#pragma unroll
    for (int f = 0; f < 4; ++f) {
        const int row = wm * 64 + f * 16 + lr;
        const int sw = (row & 7) * 8;
        ardH[f] = row * 64 + ((kg * 8) ^ sw);
        ardL[f] = row * 64 + ((32 + kg * 8) ^ sw);
    }
    int brdH[8], brdL[8];
#pragma unroll
    for (int f = 0; f < 8; ++f) {
        const int row = wn * 128 + f * 16 + lr;
        const int sw = (row & 7) * 8;
        brdH[f] = row * 64 + ((kg * 8) ^ sw);
        brdL[f] = row * 64 + ((32 + kg * 8) ^ sw);
    }

    f32x4 acc[4][8];
#pragma unroll
    for (int i = 0; i < 4; ++i)
#pragma unroll
        for (int j = 0; j < 8; ++j)
            acc[i][j] = (f32x4){0.f, 0.f, 0.f, 0.f};

    short8v ra[4], rb[8];
    auto do_load = [&](int s) {
        const int tap = tapbase + (s >> lgci);
        const int ci0 = cibase + (s & cimask) * 32;
        const int ky = tap / 9, kx = tap - ky * 9;
        const unsigned aoff = (unsigned)((ky * 20 + kx) * 256 + ci0);
        const unsigned boff = (unsigned)(tap * 256 + ci0);
#pragma unroll
        for (int i = 0; i < 4; ++i) ra[i] = *(const short8v*)(hH + aoffA[i] + aoff);
#pragma unroll
        for (int i = 0; i < 8; ++i) rb[i] = *(const short8v*)(wH + boffB[i] + boff);
    };

    do_load(0);
    for (int s = 0; s < ksteps; ++s) {
        __syncthreads();
#pragma unroll
        for (int i = 0; i < 4; ++i) *(short8v*)&Alds[awr[i]] = ra[i];
#pragma unroll
        for (int i = 0; i < 8; ++i) *(short8v*)&Blds[bwr[i]] = rb[i];
        __syncthreads();
        if (s + 1 < ksteps) do_load(s + 1);
        short8v ah[4], al[4];
#pragma unroll
        for (int f = 0; f < 4; ++f) {
            ah[f] = *(const short8v*)&Alds[ardH[f]];
            al[f] = *(const short8v*)&Alds[ardL[f]];
        }
#pragma unroll
        for (int nf = 0; nf < 8; ++nf) {
            const short8v bh = *(const short8v*)&Blds[brdH[nf]];
            const short8v bl = *(const short8v*)&Blds[brdL[nf]];
#pragma unroll
            for (int f = 0; f < 4; ++f) {
                f32x4 a = acc[f][nf];
                a = __builtin_amdgcn_mfma_f32_16x16x32_bf16(al[f], bh, a, 0, 0, 0);
                a = __builtin_amdgcn_mfma_f32_16x16x32_bf16(ah[f], bl, a, 0, 0, 0);
                a = __builtin_amdgcn_mfma_f32_16x16x32_bf16(ah[f], bh, a, 0, 0, 0);
                acc[f][nf] = a;
            }
        }
    }

    float* po = pacc + (size_t)z * 4608 * 256;
    const int r4 = (lane >> 4) * 4, cc = lane & 15;
#pragma unroll
    for (int f = 0; f < 4; ++f) {
        const int row = mt * 128 + wm * 64 + f * 16 + r4;
#pragma unroll
        for (int nf = 0; nf < 8; ++nf) {
            const int col = wn * 128 + nf * 16 + cc;
#pragma unroll
            for (int j = 0; j < 4; ++j)
                po[(size_t)(row + j) * 256 + col] = acc[f][nf][j];
        }
    }
}

// ---------------- reduce split-K partials + bias + squash -> u layout ----------------
__global__ __launch_bounds__(256) void k_cred(const float* __restrict__ pacc,
                                              const float* __restrict__ bp,
                                              float* __restrict__ u, int nz)
{
    __shared__ float sv[256];
    const int m = blockIdx.x;
    const int co = threadIdx.x;
    float v = bp[co];
    for (int z = 0; z < nz; ++z) v += pacc[((size_t)z * 4608 + m) * 256 + co];
    sv[co] = v;
    __syncthreads();
    const int g = co & 31, d = co >> 5;
    float sq = 0.f;
#pragma unroll
    for (int dd = 0; dd < 8; ++dd) {
        const float t = sv[dd * 32 + g];
        sq += t * t;
    }
    const float sc = sqrtf(sq) / (1.f + sq);
    const int bo = m / 36, so = m - bo * 36;
    u[((size_t)bo * NCAP + g * 36 + so) * 8 + d] = v * sc;
}

// ---------------- u_hat v3: wdig via LDS (coalesced), u double-buffered ----------------
__global__ __launch_bounds__(256) void k_uhat(const float* __restrict__ u,
                                              const float* __restrict__ wdig,
                                              __hip_bfloat16* __restrict__ uh)
{
    __shared__ float wlds[16 * 128];    // 8 KB: [nl][d*16+e]
    __shared__ float ulds[2][8 * 16 * 8]; // 2 x 4 KB: [bl][nl][d]
    const int n0 = blockIdx.x * 16, c = blockIdx.y;
    const int tid = threadIdx.x;
    const int nl = tid >> 4, e = tid & 15;

    // coalesced wdig stage: 2048 floats
    {
        const float* wsrc = wdig + ((size_t)c * NCAP + n0) * 128;
        *(float4*)&wlds[tid * 4] = *(const float4*)&wsrc[tid * 4];
        *(float4*)&wlds[1024 + tid * 4] = *(const float4*)&wsrc[1024 + tid * 4];
    }
    const int sbl = tid >> 5, srem = tid & 31;
    const int snn = srem >> 1, shalf = (srem & 1) * 4;
    // stage u chunk 0
    *(float4*)&ulds[0][(sbl * 16 + snn) * 8 + shalf] =
        *(const float4*)&u[((size_t)sbl * NCAP + n0 + snn) * 8 + shalf];
    __syncthreads();

    float wreg[8];
#pragma unroll
    for (int d = 0; d < 8; ++d) wreg[d] = wlds[nl * 128 + d * 16 + e];

    for (int bc = 0; bc < 16; ++bc) {
        const int p = bc & 1;
        if (bc + 1 < 16) {
            const int b1 = (bc + 1) * 8;
            *(float4*)&ulds[p ^ 1][(sbl * 16 + snn) * 8 + shalf] =
                *(const float4*)&u[((size_t)(b1 + sbl) * NCAP + n0 + snn) * 8 + shalf];
        }
        const int b0 = bc * 8;
        __hip_bfloat16 ov[8];
#pragma unroll
        for (int bl = 0; bl < 8; ++bl) {
            float a = 0.f;
#pragma unroll
            for (int d = 0; d < 8; ++d) a += ulds[p][(bl * 16 + nl) * 8 + d] * wreg[d];
            ov[bl] = __float2bfloat16(a);
        }
#pragma unroll
        for (int bl = 0; bl < 8; ++bl)
            uh[(((size_t)c * 128 + b0 + bl) * NCAP + n0 + nl) * 16 + e] = ov[bl];
        __syncthreads();
    }
}

// ---------------- 3-iter routing per (c,b): u_hat rows in REGISTERS ----------------
__global__ __launch_bounds__(256) void k_routing(const __hip_bfloat16* __restrict__ uhg,
                                                 float* __restrict__ caps)
{
    __shared__ float sred[4][17];
    __shared__ float vvs[16];
    const int c = blockIdx.x, b = blockIdx.y;
    const int tid = threadIdx.x;
    const int w = tid >> 6;

    const __hip_bfloat16* base = uhg + ((size_t)c * 128 + b) * NCAP * 16;
    short8v uhr0[5], uhr1[5];
#pragma unroll
    for (int k = 0; k < 5; ++k) {
        if (k < 4 || tid < 128) {
            const int n = tid + (k << 8);
            uhr0[k] = *(const short8v*)(base + (size_t)n * 16);
            uhr1[k] = *(const short8v*)(base + (size_t)n * 16 + 8);
        }
    }
    float breg[5] = {0.f, 0.f, 0.f, 0.f, 0.f};
    float vv[16];

    for (int it = 0; it < 3; ++it) {
        float lm = fmaxf(fmaxf(breg[0], breg[1]), fmaxf(breg[2], breg[3]));
        if (tid < 128) lm = fmaxf(lm, breg[4]);
#pragma unroll
        for (int o = 1; o < 64; o <<= 1) lm = fmaxf(lm, __shfl_xor(lm, o));
        if ((tid & 63) == 0) sred[w][16] = lm;
        __syncthreads();
        const float mx = fmaxf(fmaxf(sred[0][16], sred[1][16]), fmaxf(sred[2][16], sred[3][16]));
        __syncthreads();
        float wl[5];
        float lz = 0.f;
        float ps[16];
#pragma unroll
        for (int e = 0; e < 16; ++e) ps[e] = 0.f;
#pragma unroll
        for (int k = 0; k < 5; ++k) {
            if (k < 4 || tid < 128) {
                wl[k] = __expf(breg[k] - mx);
                lz += wl[k];
#pragma unroll
                for (int q = 0; q < 8; ++q) {
                    ps[q]     += wl[k] * bf16s2f(uhr0[k][q]);
                    ps[q + 8] += wl[k] * bf16s2f(uhr1[k][q]);
                }
            }
        }
#pragma unroll
        for (int o = 1; o < 64; o <<= 1) {
            lz += __shfl_xor(lz, o);
#pragma unroll
            for (int e = 0; e < 16; ++e) ps[e] += __shfl_xor(ps[e], o);
        }
        if ((tid & 63) == 0) {
#pragma unroll
            for (int e = 0; e < 16; ++e) sred[w][e] = ps[e];
            sred[w][16] = lz;
        }
        __syncthreads();
        if (tid == 0) {
            const float Z = sred[0][16] + sred[1][16] + sred[2][16] + sred[3][16];
            float sv[16], sq = 0.f;
#pragma unroll
            for (int e = 0; e < 16; ++e) {
                sv[e] = (sred[0][e] + sred[1][e] + sred[2][e] + sred[3][e]) / Z;
                sq += sv[e] * sv[e];
            }
            const float sc = sqrtf(sq) / (1.f + sq);
#pragma unroll
            for (int e = 0; e < 16; ++e) vvs[e] = sv[e] * sc;
        }
        __syncthreads();
#pragma unroll
        for (int e = 0; e < 16; ++e) vv[e] = vvs[e];
        if (it < 2) {
#pragma unroll
            for (int k = 0; k < 5; ++k) {
                if (k < 4 || tid < 128) {
                    float dot = 0.f;
#pragma unroll
                    for (int q = 0; q < 8; ++q)
                        dot += bf16s2f(uhr0[k][q]) * vv[q] + bf16s2f(uhr1[k][q]) * vv[q + 8];
                    breg[k] += dot;
                }
            }
        }
    }
    if (tid < 16) caps[((size_t)b * 10 + c) * 16 + tid] = vv[tid];
}

// ---------------- fused argmax-mask + one-hot + decoder fc1 ----------------
__global__ __launch_bounds__(512) void k_self(const float* __restrict__ caps,
                                              const float* __restrict__ Wd1,
                                              const float* __restrict__ bd1,
                                              float* __restrict__ yout,
                                              float* __restrict__ h1)
{
    __shared__ float nrm[16];
    __shared__ float f[16];
    __shared__ int bi;
    const int b = blockIdx.x, j = threadIdx.x;
    if (j < 10) {
        const float* cp = caps + ((size_t)b * 10 + j) * 16;
        float s = 0.f;
#pragma unroll
        for (int q = 0; q < 16; ++q) s += cp[q] * cp[q];
        nrm[j] = s;
    }
    __syncthreads();
    if (j == 0) {
        int best = 0; float bv = nrm[0];
        for (int q = 1; q < 10; ++q) if (nrm[q] > bv) { bv = nrm[q]; best = q; }
        bi = best;
    }
    __syncthreads();
    if (j < 10) yout[b * 10 + j] = (j == bi) ? 1.f : 0.f;
    if (j < 16) f[j] = caps[((size_t)b * 10 + bi) * 16 + j];
    __syncthreads();
    float a = bd1[j];
    const float* w = Wd1 + (size_t)(bi * 16) * 512 + j;
#pragma unroll
    for (int q = 0; q < 16; ++q) a += f[q] * w[q * 512];
    h1[(size_t)b * 512 + j] = fmaxf(a, 0.f);
}

// ---------------- decoder fc2: 512 -> 1024, relu (32-row b-tiles) ----------------
__global__ __launch_bounds__(256) void k_fc2(const float* __restrict__ h1,
                                             const float* __restrict__ Wd2,
                                             const float* __restrict__ bd2,
                                             float* __restrict__ h2)
{
    __shared__ float lh[32 * 512];
    const int jt = blockIdx.x, bt = blockIdx.y * 32;
    const int tid = threadIdx.x;
    for (int idx = tid; idx < 32 * 512; idx += 256)
        lh[idx] = h1[(size_t)(bt + (idx >> 9)) * 512 + (idx & 511)];
    __syncthreads();
    const int j = jt * 256 + tid;
    float acc[32];
#pragma unroll
    for (int q = 0; q < 32; ++q) acc[q] = 0.f;
    for (int k = 0; k < 512; k += 4) {
        const float w0 = Wd2[(size_t)(k + 0) * 1024 + j];
        const float w1 = Wd2[(size_t)(k + 1) * 1024 + j];
        const float w2 = Wd2[(size_t)(k + 2) * 1024 + j];
        const float w3 = Wd2[(size_t)(k + 3) * 1024 + j];
#pragma unroll
        for (int q = 0; q < 32; ++q) {
            const float4 lv = *(const float4*)&lh[q * 512 + k];
            acc[q] += lv.x * w0 + lv.y * w1 + lv.z * w2 + lv.w * w3;
        }
    }
    const float bias = bd2[j];
#pragma unroll
    for (int q = 0; q < 32; ++q)
        h2[(size_t)(bt + q) * 1024 + j] = fmaxf(acc[q] + bias, 0.f);
}

// ---------------- decoder fc3: 1024 -> 784, sigmoid (16-row b-tiles) ----------------
__global__ __launch_bounds__(256) void k_fc3(const float* __restrict__ h2,
                                             const float* __restrict__ Wd3,
                                             const float* __restrict__ bd3,
                                             float* __restrict__ rec)
{
    __shared__ float lh[16 * 1024];
    const int jt = blockIdx.x, bt = blockIdx.y * 16;
    const int tid = threadIdx.x;
    for (int idx = tid; idx < 16 * 1024; idx += 256)
        lh[idx] = h2[(size_t)(bt + (idx >> 10)) * 1024 + (idx & 1023)];
    __syncthreads();
    const int j = jt * 256 + tid;
    if (j < 784) {
        float acc[16];
#pragma unroll
        for (int q = 0; q < 16; ++q) acc[q] = 0.f;
        for (int k = 0; k < 1024; k += 4) {
            const float w0 = Wd3[(size_t)(k + 0) * 784 + j];
            const float w1 = Wd3[(size_t)(k + 1) * 784 + j];
            const float w2 = Wd3[(size_t)(k + 2) * 784 + j];
            const float w3 = Wd3[(size_t)(k + 3) * 784 + j];
#pragma unroll
            for (int q = 0; q < 16; ++q) {
                const float4 lv = *(const float4*)&lh[q * 1024 + k];
                acc[q] += lv.x * w0 + lv.y * w1 + lv.z * w2 + lv.w * w3;
            }
        }
        const float bias = bd3[j];
#pragma unroll
        for (int q = 0; q < 16; ++q) {
            const float x = acc[q] + bias;
            rec[(size_t)(bt + q) * 784 + j] = 1.f / (1.f + __expf(-x));
        }
    }
}

extern "C" void kernel_launch(void* const* d_in, const int* in_sizes, int n_in,
                              void* d_out, int out_size, void* d_ws, size_t ws_size,
                              hipStream_t stream)
{
    const float* images = (const float*)d_in[0];
    const float* W1   = (const float*)d_in[1];
    const float* b1   = (const float*)d_in[2];
    const float* Wp   = (const float*)d_in[3];
    const float* bp   = (const float*)d_in[4];
    const float* Wdig = (const float*)d_in[5];
    const float* Wd1  = (const float*)d_in[6];
    const float* bd1  = (const float*)d_in[7];
    const float* Wd2  = (const float*)d_in[8];
    const float* bd2  = (const float*)d_in[9];
    const float* Wd3  = (const float*)d_in[10];
    const float* bd3  = (const float*)d_in[11];
    float* ws  = (float*)d_ws;
    float* out = (float*)d_out;
    __hip_bfloat16* wt = (__hip_bfloat16*)(ws + WT_OFF);   // hi then lo
    __hip_bfloat16* h  = (__hip_bfloat16*)(ws + H_OFF);    // hi then lo
    __hip_bfloat16* uh = (__hip_bfloat16*)(ws + UH_OFF);   // aliases h (dead after conv2m)
    float* u    = ws + U_OFF;     // aliases wt (dead after conv2m)
    float* h1   = ws + H1_OFF;
    float* h2   = ws + H1_OFF + 65536;
    float* w1t  = ws + W1T_OFF;
    float* pacc = ws + PACC_OFF;
    float* caps = out;                       // 128*10*16
    float* rec  = out + 20480;               // 128*784
    float* yout = out + 20480 + 100352;      // 128*10

    // split-K: proven best nz=12 (3 tap-groups(27) x 4 ci-chunks(64), ci-disjoint)
    const int nz = 12, tpz = 27, ncg = 4, lgci = 1;
    const int ksteps = (KDIM / nz) / 32;

    k_w1t   <<<16, 256, 0, stream>>>(W1, w1t);
    k_pre   <<<768, 256, 0, stream>>>(Wp, images, w1t, b1, wt, h);
    k_conv2m<<<36 * nz, 256, 0, stream>>>(h, wt, pacc, ksteps, lgci, ncg, tpz);
    k_cred  <<<4608, 256, 0, stream>>>(pacc, bp, u, nz);
    k_uhat  <<<dim3(72, 10), 256, 0, stream>>>(u, Wdig, uh);
    k_routing<<<dim3(10, 128), 256, 0, stream>>>(uh, caps);
    k_self  <<<128, 512, 0, stream>>>(caps, Wd1, bd1, yout, h1);
    k_fc2   <<<dim3(4, 4), 256, 0, stream>>>(h1, Wd2, bd2, h2);
    k_fc3   <<<dim3(4, 8), 256, 0, stream>>>(h2, Wd3, bd3, rec);
}

// Round 12
// 390.520 us; speedup vs baseline: 1.1169x; 1.1169x over previous
//
#include <hip/hip_runtime.h>
#include <hip/hip_bf16.h>

// ---------------- sizes ----------------
#define BATCH 128
#define IMG   28
#define NCAP  1152          // 32*36
#define KDIM  20736         // 256*81
#define HLO_DELTA 13107200  // h_hi -> h_lo element delta (shorts)
#define WLO_DELTA 5308416   // wt_hi -> wt_lo element delta (shorts)

// ws offsets in floats
#define WT_OFF   ((size_t)0)            // wt hi+lo bf16 = 5308416 floats
#define U_OFF    ((size_t)0)            // alias wt (dead after conv2m)
#define H_OFF    ((size_t)5308416)      // h hi+lo bf16 = 13107200 floats
#define UH_OFF   (H_OFF)                // alias h (dead after conv2m): uh bf16 = 11796480 floats
#define H1_OFF   (H_OFF + (size_t)11796480)
#define W1T_OFF  ((size_t)18415616)     // 20736 floats
#define PACC_OFF ((size_t)18436352)     // nz*4608*256 floats

using short8v = __attribute__((ext_vector_type(8))) short;
using f32x4   = __attribute__((ext_vector_type(4))) float;

__device__ inline void split2(float x, __hip_bfloat16& hi, __hip_bfloat16& lo)
{
    hi = __float2bfloat16(x);
    lo = __float2bfloat16(x - __bfloat162float(hi));
}
__device__ inline float bf16s2f(short s)
{
    return __uint_as_float(((unsigned)(unsigned short)s) << 16);
}

// ---------------- W1 (256,81) -> w1t (81,256) ----------------
__global__ __launch_bounds__(256) void k_w1t(const float* __restrict__ w1, float* __restrict__ w1t)
{
    __shared__ float lds[16 * 81];
    const int r0 = blockIdx.x * 16;
    const int tid = threadIdx.x;
    for (int idx = tid; idx < 16 * 81; idx += 256)
        lds[idx] = w1[(size_t)(r0 + idx / 81) * 81 + (idx % 81)];
    __syncthreads();
    for (int idx = tid; idx < 81 * 16; idx += 256) {
        const int i = idx >> 4, rl = idx & 15;
        w1t[(size_t)i * 256 + r0 + rl] = lds[rl * 81 + i];
    }
}

// ---------------- merged: blocks [0,256) = Wp->wt; [256,768) = conv1 (row-buffer) ----------------
__global__ __launch_bounds__(256) void k_pre(const float* __restrict__ wp,
                                             const float* __restrict__ img,
                                             const float* __restrict__ w1t,
                                             const float* __restrict__ b1,
                                             __hip_bfloat16* __restrict__ wt,
                                             __hip_bfloat16* __restrict__ h)
{
    __shared__ float shl[64 * 82];
    const int tid = threadIdx.x;
    if (blockIdx.x < 256) {
        // ---- Wp (256,256,9,9) -> Wt [co][t][ci] bf16 hi/lo ----
        const int co = blockIdx.x;
        for (int ci0 = 0; ci0 < 256; ci0 += 64) {
            for (int idx = tid; idx < 64 * 81; idx += 256) {
                const int cil = idx / 81, t = idx - cil * 81;
                shl[cil * 82 + t] = wp[(size_t)co * KDIM + (size_t)(ci0 + cil) * 81 + t];
            }
            __syncthreads();
            for (int idx = tid; idx < 81 * 64; idx += 256) {
                const int t = idx >> 6, cil = idx & 63;
                __hip_bfloat16 hi, lo;
                split2(shl[cil * 82 + t], hi, lo);
                const size_t o = (size_t)co * KDIM + (size_t)t * 256 + ci0 + cil;
                wt[o] = hi;
                wt[o + WLO_DELTA] = lo;
            }
            __syncthreads();
        }
    } else {
        // ---- conv1: 28x28x1 -> 20x20x256 (NHWC, bf16 hi/lo), relu ----
        // Row-buffer: per (y,ky) load full 28-float row (7x float4), reuse for all 5 xg.
        const int idx = blockIdx.x - 256;
        const int b = idx >> 2;
        const int y0 = (idx & 3) * 5;
        float* simg = shl;
        for (int i = tid; i < IMG * IMG; i += 256) simg[i] = img[(size_t)b * IMG * IMG + i];
        float w[81];
#pragma unroll
        for (int i = 0; i < 81; ++i) w[i] = w1t[(size_t)i * 256 + tid];
        const float bias = b1[tid];
        __syncthreads();
        for (int y = y0; y < y0 + 5; ++y) {
            float a[5][4];
#pragma unroll
            for (int xg = 0; xg < 5; ++xg)
#pragma unroll
                for (int j = 0; j < 4; ++j) a[xg][j] = 0.f;
#pragma unroll
            for (int ky = 0; ky < 9; ++ky) {
                const float* rp = &simg[(y + ky) * IMG];
                float rb[28];
#pragma unroll
                for (int v = 0; v < 7; ++v) {
                    const float4 r = *(const float4*)(rp + v * 4);
                    rb[v * 4 + 0] = r.x; rb[v * 4 + 1] = r.y;
                    rb[v * 4 + 2] = r.z; rb[v * 4 + 3] = r.w;
                }
#pragma unroll
                for (int kx = 0; kx < 9; ++kx) {
                    const float wv = w[ky * 9 + kx];
#pragma unroll
                    for (int xg = 0; xg < 5; ++xg) {
#pragma unroll
                        for (int j = 0; j < 4; ++j)
                            a[xg][j] += wv * rb[xg * 4 + kx + j];
                    }
                }
            }
#pragma unroll
            for (int xg = 0; xg < 5; ++xg) {
                const size_t ob = (((size_t)b * 20 + y) * 20 + xg * 4) * 256 + tid;
#pragma unroll
                for (int j = 0; j < 4; ++j) {
                    __hip_bfloat16 hi, lo;
                    split2(fmaxf(a[xg][j] + bias, 0.f), hi, lo);
                    h[ob + j * 256] = hi;
                    h[ob + j * 256 + HLO_DELTA] = lo;
                }
            }
        }
    }
}

// ---------------- conv2 split-bf16 MFMA implicit GEMM (R5/v4 structure, nz=12) ----------------
__global__ __launch_bounds__(256, 2) void k_conv2m(const __hip_bfloat16* __restrict__ hH,
                                                   const __hip_bfloat16* __restrict__ wH,
                                                   float* __restrict__ pacc,
                                                   int ksteps, int lgci, int ncg, int tpz)
{
    __shared__ short Alds[128 * 64];
    __shared__ short Blds[256 * 64];
    const int q = gridDim.x >> 3;
    const int wg = blockIdx.x;
    const int wgid = (wg & 7) * q + (wg >> 3);
    const int z = wgid / 36;
    const int mt = wgid - z * 36;
    const int tg = z / ncg, cg = z - tg * ncg;
    const int tapbase = tg * tpz;
    const int cibase = cg * (32 << lgci);
    const int cimask = (1 << lgci) - 1;

    const int tid = threadIdx.x;
    const int lane = tid & 63, wid = tid >> 6;
    const int wm = wid >> 1, wn = wid & 1;
    const int lr = lane & 15, kg = lane >> 4;

    const int arow = tid >> 3, asub = tid & 7;
    const int aseg = asub & 3;
    const unsigned lodelA = (asub >= 4) ? (unsigned)HLO_DELTA : 0u;
    const unsigned lodelB = (asub >= 4) ? (unsigned)WLO_DELTA : 0u;

    unsigned aoffA[4];
#pragma unroll
    for (int i = 0; i < 4; ++i) {
        const int row = arow + 32 * i;
        const int m = mt * 128 + row;
        const int bb = m / 36, s = m - bb * 36;
        const int sy = s / 6, sx = s - sy * 6;
        aoffA[i] = (unsigned)((((bb * 20 + 2 * sy) * 20 + 2 * sx) * 256) + aseg * 8) + lodelA;
    }
    unsigned boffB[8];
#pragma unroll
    for (int i = 0; i < 8; ++i)
        boffB[i] = (unsigned)((arow + 32 * i) * KDIM + aseg * 8) + lodelB;
    int awr[4], bwr[8];
#pragma unroll
    for (int i = 0; i < 4; ++i) {
        const int row = arow + 32 * i;
        awr[i] = row * 64 + ((asub * 8) ^ ((row & 7) * 8));
    }
#pragma unroll
    for (int i = 0; i < 8; ++i) {
        const int row = arow + 32 * i;
        bwr[i] = row * 64 + ((asub * 8) ^ ((row & 7) * 8));
    }

    int ardH[4], ardL[4];
#pragma unroll
    for (int f = 0; f < 4; ++f) {
        const int row = wm * 64 + f * 16 + lr;
        const int sw = (row & 7) * 8;
        ardH[f] = row * 64 + ((kg * 8) ^ sw);
        ardL[f] = row * 64 + ((32 + kg * 8) ^ sw);
    }
    int brdH[8], brdL[8];
#pragma unroll
    for (int f = 0; f < 8; ++f) {
        const int row = wn * 128 + f * 16 + lr;
        const int sw = (row & 7) * 8;
        brdH[f] = row * 64 + ((kg * 8) ^ sw);
        brdL[f] = row * 64 + ((32 + kg * 8) ^ sw);
    }

    f32x4 acc[4][8];
#pragma unroll
    for (int i = 0; i < 4; ++i)
#pragma unroll
        for (int j = 0; j < 8; ++j)
            acc[i][j] = (f32x4){0.f, 0.f, 0.f, 0.f};

    short8v ra[4], rb[8];
    auto do_load = [&](int s) {
        const int tap = tapbase + (s >> lgci);
        const int ci0 = cibase + (s & cimask) * 32;
        const int ky = tap / 9, kx = tap - ky * 9;
        const unsigned aoff = (unsigned)((ky * 20 + kx) * 256 + ci0);
        const unsigned boff = (unsigned)(tap * 256 + ci0);
#pragma unroll
        for (int i = 0; i < 4; ++i) ra[i] = *(const short8v*)(hH + aoffA[i] + aoff);
#pragma unroll
        for (int i = 0; i < 8; ++i) rb[i] = *(const short8v*)(wH + boffB[i] + boff);
    };

    do_load(0);
    for (int s = 0; s < ksteps; ++s) {
        __syncthreads();
#pragma unroll
        for (int i = 0; i < 4; ++i) *(short8v*)&Alds[awr[i]] = ra[i];
#pragma unroll
        for (int i = 0; i < 8; ++i) *(short8v*)&Blds[bwr[i]] = rb[i];
        __syncthreads();
        if (s + 1 < ksteps) do_load(s + 1);
        short8v ah[4], al[4];
#pragma unroll
        for (int f = 0; f < 4; ++f) {
            ah[f] = *(const short8v*)&Alds[ardH[f]];
            al[f] = *(const short8v*)&Alds[ardL[f]];
        }
#pragma unroll
        for (int nf = 0; nf < 8; ++nf) {
            const short8v bh = *(const short8v*)&Blds[brdH[nf]];
            const short8v bl = *(const short8v*)&Blds[brdL[nf]];
#pragma unroll
            for (int f = 0; f < 4; ++f) {
                f32x4 a = acc[f][nf];
                a = __builtin_amdgcn_mfma_f32_16x16x32_bf16(al[f], bh, a, 0, 0, 0);
                a = __builtin_amdgcn_mfma_f32_16x16x32_bf16(ah[f], bl, a, 0, 0, 0);
                a = __builtin_amdgcn_mfma_f32_16x16x32_bf16(ah[f], bh, a, 0, 0, 0);
                acc[f][nf] = a;
            }
        }
    }

    float* po = pacc + (size_t)z * 4608 * 256;
    const int r4 = (lane >> 4) * 4, cc = lane & 15;
#pragma unroll
    for (int f = 0; f < 4; ++f) {
        const int row = mt * 128 + wm * 64 + f * 16 + r4;
#pragma unroll
        for (int nf = 0; nf < 8; ++nf) {
            const int col = wn * 128 + nf * 16 + cc;
#pragma unroll
            for (int j = 0; j < 4; ++j)
                po[(size_t)(row + j) * 256 + col] = acc[f][nf][j];
        }
    }
}

// ---------------- reduce split-K partials + bias + squash -> u layout ----------------
__global__ __launch_bounds__(256) void k_cred(const float* __restrict__ pacc,
                                              const float* __restrict__ bp,
                                              float* __restrict__ u, int nz)
{
    __shared__ float sv[256];
    const int m = blockIdx.x;
    const int co = threadIdx.x;
    float v = bp[co];
    for (int z = 0; z < nz; ++z) v += pacc[((size_t)z * 4608 + m) * 256 + co];
    sv[co] = v;
    __syncthreads();
    const int g = co & 31, d = co >> 5;
    float sq = 0.f;
#pragma unroll
    for (int dd = 0; dd < 8; ++dd) {
        const float t = sv[dd * 32 + g];
        sq += t * t;
    }
    const float sc = sqrtf(sq) / (1.f + sq);
    const int bo = m / 36, so = m - bo * 36;
    u[((size_t)bo * NCAP + g * 36 + so) * 8 + d] = v * sc;
}

// ---------------- u_hat v2: uh[c][b][n][e] (bf16) -- W in regs, b-chunked ----------------
__global__ __launch_bounds__(256) void k_uhat(const float* __restrict__ u,
                                              const float* __restrict__ wdig,
                                              __hip_bfloat16* __restrict__ uh)
{
    __shared__ float ulds[8 * 16 * 8];  // 4 KB: [bl][nl][d]
    const int n0 = blockIdx.x * 16, c = blockIdx.y;
    const int tid = threadIdx.x;
    const int nl = tid >> 4, e = tid & 15;
    float wreg[8];
#pragma unroll
    for (int d = 0; d < 8; ++d)
        wreg[d] = wdig[(((size_t)c * NCAP + n0 + nl) * 8 + d) * 16 + e];
    const int sbl = tid >> 5, srem = tid & 31;
    const int snn = srem >> 1, shalf = (srem & 1) * 4;
    for (int bc = 0; bc < 16; ++bc) {
        const int b0 = bc * 8;
        *(float4*)&ulds[(sbl * 16 + snn) * 8 + shalf] =
            *(const float4*)&u[((size_t)(b0 + sbl) * NCAP + n0 + snn) * 8 + shalf];
        __syncthreads();
        __hip_bfloat16 ov[8];
#pragma unroll
        for (int bl = 0; bl < 8; ++bl) {
            float a = 0.f;
#pragma unroll
            for (int d = 0; d < 8; ++d) a += ulds[(bl * 16 + nl) * 8 + d] * wreg[d];
            ov[bl] = __float2bfloat16(a);
        }
#pragma unroll
        for (int bl = 0; bl < 8; ++bl)
            uh[(((size_t)c * 128 + b0 + bl) * NCAP + n0 + nl) * 16 + e] = ov[bl];
        __syncthreads();
    }
}

// ---------------- 3-iter routing per (c,b): u_hat rows in REGISTERS ----------------
__global__ __launch_bounds__(256) void k_routing(const __hip_bfloat16* __restrict__ uhg,
                                                 float* __restrict__ caps)
{
    __shared__ float sred[4][17];
    __shared__ float vvs[16];
    const int c = blockIdx.x, b = blockIdx.y;
    const int tid = threadIdx.x;
    const int w = tid >> 6;

    const __hip_bfloat16* base = uhg + ((size_t)c * 128 + b) * NCAP * 16;
    short8v uhr0[5], uhr1[5];
#pragma unroll
    for (int k = 0; k < 5; ++k) {
        if (k < 4 || tid < 128) {
            const int n = tid + (k << 8);
            uhr0[k] = *(const short8v*)(base + (size_t)n * 16);
            uhr1[k] = *(const short8v*)(base + (size_t)n * 16 + 8);
        }
    }
    float breg[5] = {0.f, 0.f, 0.f, 0.f, 0.f};
    float vv[16];

    for (int it = 0; it < 3; ++it) {
        float lm = fmaxf(fmaxf(breg[0], breg[1]), fmaxf(breg[2], breg[3]));
        if (tid < 128) lm = fmaxf(lm, breg[4]);
#pragma unroll
        for (int o = 1; o < 64; o <<= 1) lm = fmaxf(lm, __shfl_xor(lm, o));
        if ((tid & 63) == 0) sred[w][16] = lm;
        __syncthreads();
        const float mx = fmaxf(fmaxf(sred[0][16], sred[1][16]), fmaxf(sred[2][16], sred[3][16]));
        __syncthreads();
        float wl[5];
        float lz = 0.f;
        float ps[16];
#pragma unroll
        for (int e = 0; e < 16; ++e) ps[e] = 0.f;
#pragma unroll
        for (int k = 0; k < 5; ++k) {
            if (k < 4 || tid < 128) {
                wl[k] = __expf(breg[k] - mx);
                lz += wl[k];
#pragma unroll
                for (int q = 0; q < 8; ++q) {
                    ps[q]     += wl[k] * bf16s2f(uhr0[k][q]);
                    ps[q + 8] += wl[k] * bf16s2f(uhr1[k][q]);
                }
            }
        }
#pragma unroll
        for (int o = 1; o < 64; o <<= 1) {
            lz += __shfl_xor(lz, o);
#pragma unroll
            for (int e = 0; e < 16; ++e) ps[e] += __shfl_xor(ps[e], o);
        }
        if ((tid & 63) == 0) {
#pragma unroll
            for (int e = 0; e < 16; ++e) sred[w][e] = ps[e];
            sred[w][16] = lz;
        }
        __syncthreads();
        if (tid == 0) {
            const float Z = sred[0][16] + sred[1][16] + sred[2][16] + sred[3][16];
            float sv[16], sq = 0.f;
#pragma unroll
            for (int e = 0; e < 16; ++e) {
                sv[e] = (sred[0][e] + sred[1][e] + sred[2][e] + sred[3][e]) / Z;
                sq += sv[e] * sv[e];
            }
            const float sc = sqrtf(sq) / (1.f + sq);
#pragma unroll
            for (int e = 0; e < 16; ++e) vvs[e] = sv[e] * sc;
        }
        __syncthreads();
#pragma unroll
        for (int e = 0; e < 16; ++e) vv[e] = vvs[e];
        if (it < 2) {
#pragma unroll
            for (int k = 0; k < 5; ++k) {
                if (k < 4 || tid < 128) {
                    float dot = 0.f;
#pragma unroll
                    for (int q = 0; q < 8; ++q)
                        dot += bf16s2f(uhr0[k][q]) * vv[q] + bf16s2f(uhr1[k][q]) * vv[q + 8];
                    breg[k] += dot;
                }
            }
        }
    }
    if (tid < 16) caps[((size_t)b * 10 + c) * 16 + tid] = vv[tid];
}

// ---------------- fused argmax-mask + one-hot + decoder fc1 ----------------
__global__ __launch_bounds__(512) void k_self(const float* __restrict__ caps,
                                              const float* __restrict__ Wd1,
                                              const float* __restrict__ bd1,
                                              float* __restrict__ yout,
                                              float* __restrict__ h1)
{
    __shared__ float nrm[16];
    __shared__ float f[16];
    __shared__ int bi;
    const int b = blockIdx.x, j = threadIdx.x;
    if (j < 10) {
        const float* cp = caps + ((size_t)b * 10 + j) * 16;
        float s = 0.f;
#pragma unroll
        for (int q = 0; q < 16; ++q) s += cp[q] * cp[q];
        nrm[j] = s;
    }
    __syncthreads();
    if (j == 0) {
        int best = 0; float bv = nrm[0];
        for (int q = 1; q < 10; ++q) if (nrm[q] > bv) { bv = nrm[q]; best = q; }
        bi = best;
    }
    __syncthreads();
    if (j < 10) yout[b * 10 + j] = (j == bi) ? 1.f : 0.f;
    if (j < 16) f[j] = caps[((size_t)b * 10 + bi) * 16 + j];
    __syncthreads();
    float a = bd1[j];
    const float* w = Wd1 + (size_t)(bi * 16) * 512 + j;
#pragma unroll
    for (int q = 0; q < 16; ++q) a += f[q] * w[q * 512];
    h1[(size_t)b * 512 + j] = fmaxf(a, 0.f);
}

// ---------------- decoder fc2: 512 -> 1024, relu (16-row b-tiles, grid 4x8) ----------------
__global__ __launch_bounds__(256) void k_fc2(const float* __restrict__ h1,
                                             const float* __restrict__ Wd2,
                                             const float* __restrict__ bd2,
                                             float* __restrict__ h2)
{
    __shared__ float lh[16 * 512];
    const int jt = blockIdx.x, bt = blockIdx.y * 16;
    const int tid = threadIdx.x;
    for (int idx = tid; idx < 16 * 512; idx += 256)
        lh[idx] = h1[(size_t)(bt + (idx >> 9)) * 512 + (idx & 511)];
    __syncthreads();
    const int j = jt * 256 + tid;
    float acc[16];
#pragma unroll
    for (int q = 0; q < 16; ++q) acc[q] = 0.f;
    for (int k = 0; k < 512; k += 4) {
        const float w0 = Wd2[(size_t)(k + 0) * 1024 + j];
        const float w1 = Wd2[(size_t)(k + 1) * 1024 + j];
        const float w2 = Wd2[(size_t)(k + 2) * 1024 + j];
        const float w3 = Wd2[(size_t)(k + 3) * 1024 + j];
#pragma unroll
        for (int q = 0; q < 16; ++q) {
            const float4 lv = *(const float4*)&lh[q * 512 + k];
            acc[q] += lv.x * w0 + lv.y * w1 + lv.z * w2 + lv.w * w3;
        }
    }
    const float bias = bd2[j];
#pragma unroll
    for (int q = 0; q < 16; ++q)
        h2[(size_t)(bt + q) * 1024 + j] = fmaxf(acc[q] + bias, 0.f);
}

// ---------------- decoder fc3: 1024 -> 784, sigmoid (8-row b-tiles, grid 4x16) ----------------
__global__ __launch_bounds__(256) void k_fc3(const float* __restrict__ h2,
                                             const float* __restrict__ Wd3,
                                             const float* __restrict__ bd3,
                                             float* __restrict__ rec)
{
    __shared__ float lh[8 * 1024];
    const int jt = blockIdx.x, bt = blockIdx.y * 8;
    const int tid = threadIdx.x;
    for (int idx = tid; idx < 8 * 1024; idx += 256)
        lh[idx] = h2[(size_t)(bt + (idx >> 10)) * 1024 + (idx & 1023)];
    __syncthreads();
    const int j = jt * 256 + tid;
    if (j < 784) {
        float acc[8];
#pragma unroll
        for (int q = 0; q < 8; ++q) acc[q] = 0.f;
        for (int k = 0; k < 1024; k += 4) {
            const float w0 = Wd3[(size_t)(k + 0) * 784 + j];
            const float w1 = Wd3[(size_t)(k + 1) * 784 + j];
            const float w2 = Wd3[(size_t)(k + 2) * 784 + j];
            const float w3 = Wd3[(size_t)(k + 3) * 784 + j];
#pragma unroll
            for (int q = 0; q < 8; ++q) {
                const float4 lv = *(const float4*)&lh[q * 1024 + k];
                acc[q] += lv.x * w0 + lv.y * w1 + lv.z * w2 + lv.w * w3;
            }
        }
        const float bias = bd3[j];
#pragma unroll
        for (int q = 0; q < 8; ++q) {
            const float x = acc[q] + bias;
            rec[(size_t)(bt + q) * 784 + j] = 1.f / (1.f + __expf(-x));
        }
    }
}

extern "C" void kernel_launch(void* const* d_in, const int* in_sizes, int n_in,
                              void* d_out, int out_size, void* d_ws, size_t ws_size,
                              hipStream_t stream)
{
    const float* images = (const float*)d_in[0];
    const float* W1   = (const float*)d_in[1];
    const float* b1   = (const float*)d_in[2];
    const float* Wp   = (const float*)d_in[3];
    const float* bp   = (const float*)d_in[4];
    const float* Wdig = (const float*)d_in[5];
    const float* Wd1  = (const float*)d_in[6];
    const float* bd1  = (const float*)d_in[7];
    const float* Wd2  = (const float*)d_in[8];
    const float* bd2  = (const float*)d_in[9];
    const float* Wd3  = (const float*)d_in[10];
    const float* bd3  = (const float*)d_in[11];
    float* ws  = (float*)d_ws;
    float* out = (float*)d_out;
    __hip_bfloat16* wt = (__hip_bfloat16*)(ws + WT_OFF);   // hi then lo
    __hip_bfloat16* h  = (__hip_bfloat16*)(ws + H_OFF);    // hi then lo
    __hip_bfloat16* uh = (__hip_bfloat16*)(ws + UH_OFF);   // aliases h (dead after conv2m)
    float* u    = ws + U_OFF;     // aliases wt (dead after conv2m)
    float* h1   = ws + H1_OFF;
    float* h2   = ws + H1_OFF + 65536;
    float* w1t  = ws + W1T_OFF;
    float* pacc = ws + PACC_OFF;
    float* caps = out;                       // 128*10*16
    float* rec  = out + 20480;               // 128*784
    float* yout = out + 20480 + 100352;      // 128*10

    // split-K: proven best nz=12 (3 tap-groups(27) x 4 ci-chunks(64), ci-disjoint)
    const int nz = 12, tpz = 27, ncg = 4, lgci = 1;
    const int ksteps = (KDIM / nz) / 32;

    k_w1t   <<<16, 256, 0, stream>>>(W1, w1t);
    k_pre   <<<768, 256, 0, stream>>>(Wp, images, w1t, b1, wt, h);
    k_conv2m<<<36 * nz, 256, 0, stream>>>(h, wt, pacc, ksteps, lgci, ncg, tpz);
    k_cred  <<<4608, 256, 0, stream>>>(pacc, bp, u, nz);
    k_uhat  <<<dim3(72, 10), 256, 0, stream>>>(u, Wdig, uh);
    k_routing<<<dim3(10, 128), 256, 0, stream>>>(uh, caps);
    k_self  <<<128, 512, 0, stream>>>(caps, Wd1, bd1, yout, h1);
    k_fc2   <<<dim3(4, 8), 256, 0, stream>>>(h1, Wd2, bd2, h2);
    k_fc3   <<<dim3(4, 16), 256, 0, stream>>>(h2, Wd3, bd3, rec);
}

// Round 13
// 388.803 us; speedup vs baseline: 1.1219x; 1.0044x over previous
//
#include <hip/hip_runtime.h>
#include <hip/hip_bf16.h>

// ---------------- sizes ----------------
#define BATCH 128
#define IMG   28
#define NCAP  1152          // 32*36
#define KDIM  20736         // 256*81
#define HLO_DELTA 13107200  // h_hi -> h_lo element delta (shorts)
#define WLO_DELTA 5308416   // wt_hi -> wt_lo element delta (shorts)

// ws offsets in floats
#define WT_OFF   ((size_t)0)            // wt hi+lo bf16 = 5308416 floats
#define U_OFF    ((size_t)0)            // alias wt (dead after conv2m)
#define H_OFF    ((size_t)5308416)      // h hi+lo bf16 = 13107200 floats
#define UH_OFF   (H_OFF)                // alias h (dead after conv2m): uh bf16 = 11796480 floats
#define H1_OFF   (H_OFF + (size_t)11796480)
#define W1T_OFF  ((size_t)18415616)     // 20736 floats
#define PACC_OFF ((size_t)18436352)     // nz*4608*256 floats

using short8v = __attribute__((ext_vector_type(8))) short;
using f32x4   = __attribute__((ext_vector_type(4))) float;

__device__ inline void split2(float x, __hip_bfloat16& hi, __hip_bfloat16& lo)
{
    hi = __float2bfloat16(x);
    lo = __float2bfloat16(x - __bfloat162float(hi));
}
__device__ inline float bf16s2f(short s)
{
    return __uint_as_float(((unsigned)(unsigned short)s) << 16);
}

// ---------------- W1 (256,81) -> w1t (81,256) ----------------
__global__ __launch_bounds__(256) void k_w1t(const float* __restrict__ w1, float* __restrict__ w1t)
{
    __shared__ float lds[16 * 81];
    const int r0 = blockIdx.x * 16;
    const int tid = threadIdx.x;
    for (int idx = tid; idx < 16 * 81; idx += 256)
        lds[idx] = w1[(size_t)(r0 + idx / 81) * 81 + (idx % 81)];
    __syncthreads();
    for (int idx = tid; idx < 81 * 16; idx += 256) {
        const int i = idx >> 4, rl = idx & 15;
        w1t[(size_t)i * 256 + r0 + rl] = lds[rl * 81 + i];
    }
}

// ---------------- merged: blocks [0,256) = Wp->wt; [256,768) = conv1 (row-buffer) ----------------
__global__ __launch_bounds__(256) void k_pre(const float* __restrict__ wp,
                                             const float* __restrict__ img,
                                             const float* __restrict__ w1t,
                                             const float* __restrict__ b1,
                                             __hip_bfloat16* __restrict__ wt,
                                             __hip_bfloat16* __restrict__ h)
{
    __shared__ float shl[64 * 82];
    const int tid = threadIdx.x;
    if (blockIdx.x < 256) {
        // ---- Wp (256,256,9,9) -> Wt [co][t][ci] bf16 hi/lo ----
        const int co = blockIdx.x;
        for (int ci0 = 0; ci0 < 256; ci0 += 64) {
            for (int idx = tid; idx < 64 * 81; idx += 256) {
                const int cil = idx / 81, t = idx - cil * 81;
                shl[cil * 82 + t] = wp[(size_t)co * KDIM + (size_t)(ci0 + cil) * 81 + t];
            }
            __syncthreads();
            for (int idx = tid; idx < 81 * 64; idx += 256) {
                const int t = idx >> 6, cil = idx & 63;
                __hip_bfloat16 hi, lo;
                split2(shl[cil * 82 + t], hi, lo);
                const size_t o = (size_t)co * KDIM + (size_t)t * 256 + ci0 + cil;
                wt[o] = hi;
                wt[o + WLO_DELTA] = lo;
            }
            __syncthreads();
        }
    } else {
        // ---- conv1: 28x28x1 -> 20x20x256 (NHWC, bf16 hi/lo), relu ----
        const int idx = blockIdx.x - 256;
        const int b = idx >> 2;
        const int y0 = (idx & 3) * 5;
        float* simg = shl;
        for (int i = tid; i < IMG * IMG; i += 256) simg[i] = img[(size_t)b * IMG * IMG + i];
        float w[81];
#pragma unroll
        for (int i = 0; i < 81; ++i) w[i] = w1t[(size_t)i * 256 + tid];
        const float bias = b1[tid];
        __syncthreads();
        for (int y = y0; y < y0 + 5; ++y) {
            float a[5][4];
#pragma unroll
            for (int xg = 0; xg < 5; ++xg)
#pragma unroll
                for (int j = 0; j < 4; ++j) a[xg][j] = 0.f;
#pragma unroll
            for (int ky = 0; ky < 9; ++ky) {
                const float* rp = &simg[(y + ky) * IMG];
                float rb[28];
#pragma unroll
                for (int v = 0; v < 7; ++v) {
                    const float4 r = *(const float4*)(rp + v * 4);
                    rb[v * 4 + 0] = r.x; rb[v * 4 + 1] = r.y;
                    rb[v * 4 + 2] = r.z; rb[v * 4 + 3] = r.w;
                }
#pragma unroll
                for (int kx = 0; kx < 9; ++kx) {
                    const float wv = w[ky * 9 + kx];
#pragma unroll
                    for (int xg = 0; xg < 5; ++xg) {
#pragma unroll
                        for (int j = 0; j < 4; ++j)
                            a[xg][j] += wv * rb[xg * 4 + kx + j];
                    }
                }
            }
#pragma unroll
            for (int xg = 0; xg < 5; ++xg) {
                const size_t ob = (((size_t)b * 20 + y) * 20 + xg * 4) * 256 + tid;
#pragma unroll
                for (int j = 0; j < 4; ++j) {
                    __hip_bfloat16 hi, lo;
                    split2(fmaxf(a[xg][j] + bias, 0.f), hi, lo);
                    h[ob + j * 256] = hi;
                    h[ob + j * 256 + HLO_DELTA] = lo;
                }
            }
        }
    }
}

// ---------------- conv2 split-bf16 MFMA implicit GEMM (R5/v4 structure, nz=12) ----------------
__global__ __launch_bounds__(256, 2) void k_conv2m(const __hip_bfloat16* __restrict__ hH,
                                                   const __hip_bfloat16* __restrict__ wH,
                                                   float* __restrict__ pacc,
                                                   int ksteps, int lgci, int ncg, int tpz)
{
    __shared__ short Alds[128 * 64];
    __shared__ short Blds[256 * 64];
    const int q = gridDim.x >> 3;
    const int wg = blockIdx.x;
    const int wgid = (wg & 7) * q + (wg >> 3);
    const int z = wgid / 36;
    const int mt = wgid - z * 36;
    const int tg = z / ncg, cg = z - tg * ncg;
    const int tapbase = tg * tpz;
    const int cibase = cg * (32 << lgci);
    const int cimask = (1 << lgci) - 1;

    const int tid = threadIdx.x;
    const int lane = tid & 63, wid = tid >> 6;
    const int wm = wid >> 1, wn = wid & 1;
    const int lr = lane & 15, kg = lane >> 4;

    const int arow = tid >> 3, asub = tid & 7;
    const int aseg = asub & 3;
    const unsigned lodelA = (asub >= 4) ? (unsigned)HLO_DELTA : 0u;
    const unsigned lodelB = (asub >= 4) ? (unsigned)WLO_DELTA : 0u;

    unsigned aoffA[4];
#pragma unroll
    for (int i = 0; i < 4; ++i) {
        const int row = arow + 32 * i;
        const int m = mt * 128 + row;
        const int bb = m / 36, s = m - bb * 36;
        const int sy = s / 6, sx = s - sy * 6;
        aoffA[i] = (unsigned)((((bb * 20 + 2 * sy) * 20 + 2 * sx) * 256) + aseg * 8) + lodelA;
    }
    unsigned boffB[8];
#pragma unroll
    for (int i = 0; i < 8; ++i)
        boffB[i] = (unsigned)((arow + 32 * i) * KDIM + aseg * 8) + lodelB;
    int awr[4], bwr[8];
#pragma unroll
    for (int i = 0; i < 4; ++i) {
        const int row = arow + 32 * i;
        awr[i] = row * 64 + ((asub * 8) ^ ((row & 7) * 8));
    }
#pragma unroll
    for (int i = 0; i < 8; ++i) {
        const int row = arow + 32 * i;
        bwr[i] = row * 64 + ((asub * 8) ^ ((row & 7) * 8));
    }

    int ardH[4], ardL[4];
#pragma unroll
    for (int f = 0; f < 4; ++f) {
        const int row = wm * 64 + f * 16 + lr;
        const int sw = (row & 7) * 8;
        ardH[f] = row * 64 + ((kg * 8) ^ sw);
        ardL[f] = row * 64 + ((32 + kg * 8) ^ sw);
    }
    int brdH[8], brdL[8];
#pragma unroll
    for (int f = 0; f < 8; ++f) {
        const int row = wn * 128 + f * 16 + lr;
        const int sw = (row & 7) * 8;
        brdH[f] = row * 64 + ((kg * 8) ^ sw);
        brdL[f] = row * 64 + ((32 + kg * 8) ^ sw);
    }

    f32x4 acc[4][8];
#pragma unroll
    for (int i = 0; i < 4; ++i)
#pragma unroll
        for (int j = 0; j < 8; ++j)
            acc[i][j] = (f32x4){0.f, 0.f, 0.f, 0.f};

    short8v ra[4], rb[8];
    auto do_load = [&](int s) {
        const int tap = tapbase + (s >> lgci);
        const int ci0 = cibase + (s & cimask) * 32;
        const int ky = tap / 9, kx = tap - ky * 9;
        const unsigned aoff = (unsigned)((ky * 20 + kx) * 256 + ci0);
        const unsigned boff = (unsigned)(tap * 256 + ci0);
#pragma unroll
        for (int i = 0; i < 4; ++i) ra[i] = *(const short8v*)(hH + aoffA[i] + aoff);
#pragma unroll
        for (int i = 0; i < 8; ++i) rb[i] = *(const short8v*)(wH + boffB[i] + boff);
    };

    do_load(0);
    for (int s = 0; s < ksteps; ++s) {
        __syncthreads();
#pragma unroll
        for (int i = 0; i < 4; ++i) *(short8v*)&Alds[awr[i]] = ra[i];
#pragma unroll
        for (int i = 0; i < 8; ++i) *(short8v*)&Blds[bwr[i]] = rb[i];
        __syncthreads();
        if (s + 1 < ksteps) do_load(s + 1);
        short8v ah[4], al[4];
#pragma unroll
        for (int f = 0; f < 4; ++f) {
            ah[f] = *(const short8v*)&Alds[ardH[f]];
            al[f] = *(const short8v*)&Alds[ardL[f]];
        }
#pragma unroll
        for (int nf = 0; nf < 8; ++nf) {
            const short8v bh = *(const short8v*)&Blds[brdH[nf]];
            const short8v bl = *(const short8v*)&Blds[brdL[nf]];
#pragma unroll
            for (int f = 0; f < 4; ++f) {
                f32x4 a = acc[f][nf];
                a = __builtin_amdgcn_mfma_f32_16x16x32_bf16(al[f], bh, a, 0, 0, 0);
                a = __builtin_amdgcn_mfma_f32_16x16x32_bf16(ah[f], bl, a, 0, 0, 0);
                a = __builtin_amdgcn_mfma_f32_16x16x32_bf16(ah[f], bh, a, 0, 0, 0);
                acc[f][nf] = a;
            }
        }
    }

    float* po = pacc + (size_t)z * 4608 * 256;
    const int r4 = (lane >> 4) * 4, cc = lane & 15;
#pragma unroll
    for (int f = 0; f < 4; ++f) {
        const int row = mt * 128 + wm * 64 + f * 16 + r4;
#pragma unroll
        for (int nf = 0; nf < 8; ++nf) {
            const int col = wn * 128 + nf * 16 + cc;
#pragma unroll
            for (int j = 0; j < 4; ++j)
                po[(size_t)(row + j) * 256 + col] = acc[f][nf][j];
        }
    }
}

// ---------------- reduce split-K partials + bias + squash -> u (coalesced float4 writes) ----------------
__global__ __launch_bounds__(256) void k_cred(const float* __restrict__ pacc,
                                              const float* __restrict__ bp,
                                              float* __restrict__ u, int nz)
{
    __shared__ float sv[256];
    __shared__ float scg[32];
    const int m = blockIdx.x;
    const int co = threadIdx.x;
    float v = bp[co];
    for (int z = 0; z < nz; ++z) v += pacc[((size_t)z * 4608 + m) * 256 + co];
    sv[co] = v;
    __syncthreads();
    if (co < 32) {
        float sq = 0.f;
#pragma unroll
        for (int dd = 0; dd < 8; ++dd) {
            const float t = sv[dd * 32 + co];
            sq += t * t;
        }
        scg[co] = sqrtf(sq) / (1.f + sq);
    }
    __syncthreads();
    if (co < 64) {
        const int g = co >> 1, half = co & 1;
        const float sc = scg[g];
        float4 w;
        w.x = sv[(half * 4 + 0) * 32 + g] * sc;
        w.y = sv[(half * 4 + 1) * 32 + g] * sc;
        w.z = sv[(half * 4 + 2) * 32 + g] * sc;
        w.w = sv[(half * 4 + 3) * 32 + g] * sc;
        const int bo = m / 36, so = m - bo * 36;
        *(float4*)&u[((size_t)bo * NCAP + g * 36 + so) * 8 + half * 4] = w;
    }
}

// ---------------- u_hat v4: W in regs, LDS-transposed 16B output writes ----------------
__global__ __launch_bounds__(256) void k_uhat(const float* __restrict__ u,
                                              const float* __restrict__ wdig,
                                              __hip_bfloat16* __restrict__ uh)
{
    __shared__ float ulds[8 * 16 * 8];          // 4 KB: [bl][nl][d]
    __shared__ __hip_bfloat16 olds[8 * 16 * 16]; // 4 KB: [bl][nl][e]
    const int n0 = blockIdx.x * 16, c = blockIdx.y;
    const int tid = threadIdx.x;
    const int nl = tid >> 4, e = tid & 15;
    float wreg[8];
#pragma unroll
    for (int d = 0; d < 8; ++d)
        wreg[d] = wdig[(((size_t)c * NCAP + n0 + nl) * 8 + d) * 16 + e];
    const int sbl = tid >> 5, srem = tid & 31;
    const int snn = srem >> 1, shalf = (srem & 1) * 4;
    // output-stage thread mapping: (obl, onl, oeh)
    const int obl = tid >> 5, onl = (tid >> 1) & 15, oeh = tid & 1;

    // stage u chunk 0
    *(float4*)&ulds[(sbl * 16 + snn) * 8 + shalf] =
        *(const float4*)&u[((size_t)sbl * NCAP + n0 + snn) * 8 + shalf];
    __syncthreads();

    for (int bc = 0; bc < 16; ++bc) {
        const int b0 = bc * 8;
        // compute + transpose into olds (b16 writes, 2-way bank = free)
#pragma unroll
        for (int bl = 0; bl < 8; ++bl) {
            float a = 0.f;
#pragma unroll
            for (int d = 0; d < 8; ++d) a += ulds[(bl * 16 + nl) * 8 + d] * wreg[d];
            olds[(bl * 16 + nl) * 16 + e] = __float2bfloat16(a);
        }
        __syncthreads();
        // stage next u chunk (ulds free after compute)
        if (bc + 1 < 16) {
            const int b1 = (bc + 1) * 8;
            *(float4*)&ulds[(sbl * 16 + snn) * 8 + shalf] =
                *(const float4*)&u[((size_t)(b1 + sbl) * NCAP + n0 + snn) * 8 + shalf];
        }
        // coalesced 16B output writes
        const short8v t = *(const short8v*)&olds[(obl * 16 + onl) * 16 + oeh * 8];
        *(short8v*)((__hip_bfloat16*)uh +
                    (((size_t)c * 128 + b0 + obl) * NCAP + n0 + onl) * 16 + oeh * 8) = t;
        __syncthreads();   // protects olds rewrite + ulds ready for next compute
    }
}

// ---------------- 3-iter routing per (c,b): u_hat rows in REGISTERS ----------------
__global__ __launch_bounds__(256) void k_routing(const __hip_bfloat16* __restrict__ uhg,
                                                 float* __restrict__ caps)
{
    __shared__ float sred[4][17];
    __shared__ float vvs[16];
    const int c = blockIdx.x, b = blockIdx.y;
    const int tid = threadIdx.x;
    const int w = tid >> 6;

    const __hip_bfloat16* base = uhg + ((size_t)c * 128 + b) * NCAP * 16;
    short8v uhr0[5], uhr1[5];
#pragma unroll
    for (int k = 0; k < 5; ++k) {
        if (k < 4 || tid < 128) {
            const int n = tid + (k << 8);
            uhr0[k] = *(const short8v*)(base + (size_t)n * 16);
            uhr1[k] = *(const short8v*)(base + (size_t)n * 16 + 8);
        }
    }
    float breg[5] = {0.f, 0.f, 0.f, 0.f, 0.f};
    float vv[16];

    for (int it = 0; it < 3; ++it) {
        float lm = fmaxf(fmaxf(breg[0], breg[1]), fmaxf(breg[2], breg[3]));
        if (tid < 128) lm = fmaxf(lm, breg[4]);
#pragma unroll
        for (int o = 1; o < 64; o <<= 1) lm = fmaxf(lm, __shfl_xor(lm, o));
        if ((tid & 63) == 0) sred[w][16] = lm;
        __syncthreads();
        const float mx = fmaxf(fmaxf(sred[0][16], sred[1][16]), fmaxf(sred[2][16], sred[3][16]));
        __syncthreads();
        float wl[5];
        float lz = 0.f;
        float ps[16];
#pragma unroll
        for (int e = 0; e < 16; ++e) ps[e] = 0.f;
#pragma unroll
        for (int k = 0; k < 5; ++k) {
            if (k < 4 || tid < 128) {
                wl[k] = __expf(breg[k] - mx);
                lz += wl[k];
#pragma unroll
                for (int q = 0; q < 8; ++q) {
                    ps[q]     += wl[k] * bf16s2f(uhr0[k][q]);
                    ps[q + 8] += wl[k] * bf16s2f(uhr1[k][q]);
                }
            }
        }
#pragma unroll
        for (int o = 1; o < 64; o <<= 1) {
            lz += __shfl_xor(lz, o);
#pragma unroll
            for (int e = 0; e < 16; ++e) ps[e] += __shfl_xor(ps[e], o);
        }
        if ((tid & 63) == 0) {
#pragma unroll
            for (int e = 0; e < 16; ++e) sred[w][e] = ps[e];
            sred[w][16] = lz;
        }
        __syncthreads();
        if (tid == 0) {
            const float Z = sred[0][16] + sred[1][16] + sred[2][16] + sred[3][16];
            float sv[16], sq = 0.f;
#pragma unroll
            for (int e = 0; e < 16; ++e) {
                sv[e] = (sred[0][e] + sred[1][e] + sred[2][e] + sred[3][e]) / Z;
                sq += sv[e] * sv[e];
            }
            const float sc = sqrtf(sq) / (1.f + sq);
#pragma unroll
            for (int e = 0; e < 16; ++e) vvs[e] = sv[e] * sc;
        }
        __syncthreads();
#pragma unroll
        for (int e = 0; e < 16; ++e) vv[e] = vvs[e];
        if (it < 2) {
#pragma unroll
            for (int k = 0; k < 5; ++k) {
                if (k < 4 || tid < 128) {
                    float dot = 0.f;
#pragma unroll
                    for (int q = 0; q < 8; ++q)
                        dot += bf16s2f(uhr0[k][q]) * vv[q] + bf16s2f(uhr1[k][q]) * vv[q + 8];
                    breg[k] += dot;
                }
            }
        }
    }
    if (tid < 16) caps[((size_t)b * 10 + c) * 16 + tid] = vv[tid];
}

// ---------------- fused argmax-mask + one-hot + decoder fc1 ----------------
__global__ __launch_bounds__(512) void k_self(const float* __restrict__ caps,
                                              const float* __restrict__ Wd1,
                                              const float* __restrict__ bd1,
                                              float* __restrict__ yout,
                                              float* __restrict__ h1)
{
    __shared__ float nrm[16];
    __shared__ float f[16];
    __shared__ int bi;
    const int b = blockIdx.x, j = threadIdx.x;
    if (j < 10) {
        const float* cp = caps + ((size_t)b * 10 + j) * 16;
        float s = 0.f;
#pragma unroll
        for (int q = 0; q < 16; ++q) s += cp[q] * cp[q];
        nrm[j] = s;
    }
    __syncthreads();
    if (j == 0) {
        int best = 0; float bv = nrm[0];
        for (int q = 1; q < 10; ++q) if (nrm[q] > bv) { bv = nrm[q]; best = q; }
        bi = best;
    }
    __syncthreads();
    if (j < 10) yout[b * 10 + j] = (j == bi) ? 1.f : 0.f;
    if (j < 16) f[j] = caps[((size_t)b * 10 + bi) * 16 + j];
    __syncthreads();
    float a = bd1[j];
    const float* w = Wd1 + (size_t)(bi * 16) * 512 + j;
#pragma unroll
    for (int q = 0; q < 16; ++q) a += f[q] * w[q * 512];
    h1[(size_t)b * 512 + j] = fmaxf(a, 0.f);
}

// ---------------- decoder fc2: 512 -> 1024, relu (16-row b-tiles, grid 4x8) ----------------
__global__ __launch_bounds__(256) void k_fc2(const float* __restrict__ h1,
                                             const float* __restrict__ Wd2,
                                             const float* __restrict__ bd2,
                                             float* __restrict__ h2)
{
    __shared__ float lh[16 * 512];
    const int jt = blockIdx.x, bt = blockIdx.y * 16;
    const int tid = threadIdx.x;
    for (int idx = tid; idx < 16 * 512; idx += 256)
        lh[idx] = h1[(size_t)(bt + (idx >> 9)) * 512 + (idx & 511)];
    __syncthreads();
    const int j = jt * 256 + tid;
    float acc[16];
#pragma unroll
    for (int q = 0; q < 16; ++q) acc[q] = 0.f;
    for (int k = 0; k < 512; k += 4) {
        const float w0 = Wd2[(size_t)(k + 0) * 1024 + j];
        const float w1 = Wd2[(size_t)(k + 1) * 1024 + j];
        const float w2 = Wd2[(size_t)(k + 2) * 1024 + j];
        const float w3 = Wd2[(size_t)(k + 3) * 1024 + j];
#pragma unroll
        for (int q = 0; q < 16; ++q) {
            const float4 lv = *(const float4*)&lh[q * 512 + k];
            acc[q] += lv.x * w0 + lv.y * w1 + lv.z * w2 + lv.w * w3;
        }
    }
    const float bias = bd2[j];
#pragma unroll
    for (int q = 0; q < 16; ++q)
        h2[(size_t)(bt + q) * 1024 + j] = fmaxf(acc[q] + bias, 0.f);
}

// ---------------- decoder fc3: 1024 -> 784, sigmoid (8-row b-tiles, grid 4x16) ----------------
__global__ __launch_bounds__(256) void k_fc3(const float* __restrict__ h2,
                                             const float* __restrict__ Wd3,
                                             const float* __restrict__ bd3,
                                             float* __restrict__ rec)
{
    __shared__ float lh[8 * 1024];
    const int jt = blockIdx.x, bt = blockIdx.y * 8;
    const int tid = threadIdx.x;
    for (int idx = tid; idx < 8 * 1024; idx += 256)
        lh[idx] = h2[(size_t)(bt + (idx >> 10)) * 1024 + (idx & 1023)];
    __syncthreads();
    const int j = jt * 256 + tid;
    if (j < 784) {
        float acc[8];
#pragma unroll
        for (int q = 0; q < 8; ++q) acc[q] = 0.f;
        for (int k = 0; k < 1024; k += 4) {
            const float w0 = Wd3[(size_t)(k + 0) * 784 + j];
            const float w1 = Wd3[(size_t)(k + 1) * 784 + j];
            const float w2 = Wd3[(size_t)(k + 2) * 784 + j];
            const float w3 = Wd3[(size_t)(k + 3) * 784 + j];
#pragma unroll
            for (int q = 0; q < 8; ++q) {
                const float4 lv = *(const float4*)&lh[q * 1024 + k];
                acc[q] += lv.x * w0 + lv.y * w1 + lv.z * w2 + lv.w * w3;
            }
        }
        const float bias = bd3[j];
#pragma unroll
        for (int q = 0; q < 8; ++q) {
            const float x = acc[q] + bias;
            rec[(size_t)(bt + q) * 784 + j] = 1.f / (1.f + __expf(-x));
        }
    }
}

extern "C" void kernel_launch(void* const* d_in, const int* in_sizes, int n_in,
                              void* d_out, int out_size, void* d_ws, size_t ws_size,
                              hipStream_t stream)
{
    const float* images = (const float*)d_in[0];
    const float* W1   = (const float*)d_in[1];
    const float* b1   = (const float*)d_in[2];
    const float* Wp   = (const float*)d_in[3];
    const float* bp   = (const float*)d_in[4];
    const float* Wdig = (const float*)d_in[5];
    const float* Wd1  = (const float*)d_in[6];
    const float* bd1  = (const float*)d_in[7];
    const float* Wd2  = (const float*)d_in[8];
    const float* bd2  = (const float*)d_in[9];
    const float* Wd3  = (const float*)d_in[10];
    const float* bd3  = (const float*)d_in[11];
    float* ws  = (float*)d_ws;
    float* out = (float*)d_out;
    __hip_bfloat16* wt = (__hip_bfloat16*)(ws + WT_OFF);   // hi then lo
    __hip_bfloat16* h  = (__hip_bfloat16*)(ws + H_OFF);    // hi then lo
    __hip_bfloat16* uh = (__hip_bfloat16*)(ws + UH_OFF);   // aliases h (dead after conv2m)
    float* u    = ws + U_OFF;     // aliases wt (dead after conv2m)
    float* h1   = ws + H1_OFF;
    float* h2   = ws + H1_OFF + 65536;
    float* w1t  = ws + W1T_OFF;
    float* pacc = ws + PACC_OFF;
    float* caps = out;                       // 128*10*16
    float* rec  = out + 20480;               // 128*784
    float* yout = out + 20480 + 100352;      // 128*10

    // split-K: proven best nz=12 (3 tap-groups(27) x 4 ci-chunks(64), ci-disjoint)
    const int nz = 12, tpz = 27, ncg = 4, lgci = 1;
    const int ksteps = (KDIM / nz) / 32;

    k_w1t   <<<16, 256, 0, stream>>>(W1, w1t);
    k_pre   <<<768, 256, 0, stream>>>(Wp, images, w1t, b1, wt, h);
    k_conv2m<<<36 * nz, 256, 0, stream>>>(h, wt, pacc, ksteps, lgci, ncg, tpz);
    k_cred  <<<4608, 256, 0, stream>>>(pacc, bp, u, nz);
    k_uhat  <<<dim3(72, 10), 256, 0, stream>>>(u, Wdig, uh);
    k_routing<<<dim3(10, 128), 256, 0, stream>>>(uh, caps);
    k_self  <<<128, 512, 0, stream>>>(caps, Wd1, bd1, yout, h1);
    k_fc2   <<<dim3(4, 8), 256, 0, stream>>>(h1, Wd2, bd2, h2);
    k_fc3   <<<dim3(4, 16), 256, 0, stream>>>(h2, Wd3, bd3, rec);
}

// Round 14
// 387.807 us; speedup vs baseline: 1.1248x; 1.0026x over previous
//
#include <hip/hip_runtime.h>
#include <hip/hip_bf16.h>

// ---------------- sizes ----------------
#define BATCH 128
#define IMG   28
#define NCAP  1152          // 32*36
#define KDIM  20736         // 256*81
#define HLO_DELTA 13107200  // h_hi -> h_lo element delta (shorts)
#define WLO_DELTA 5308416   // wt_hi -> wt_lo element delta (shorts)

// ws offsets in floats
#define WT_OFF   ((size_t)0)            // wt hi+lo bf16 = 5308416 floats
#define U_OFF    ((size_t)0)            // alias wt (dead after conv2m)
#define H_OFF    ((size_t)5308416)      // h hi+lo bf16 = 13107200 floats
#define UH_OFF   (H_OFF)                // alias h (dead after conv2m): uh bf16 = 11796480 floats
#define H1_OFF   (H_OFF + (size_t)11796480)
#define W1T_OFF  ((size_t)18415616)     // 20736 floats
#define PACC_OFF ((size_t)18436352)     // nz*4608*256 floats (nz=24 confirmed to fit, R10)

using short8v = __attribute__((ext_vector_type(8))) short;
using f32x4   = __attribute__((ext_vector_type(4))) float;

__device__ inline void split2(float x, __hip_bfloat16& hi, __hip_bfloat16& lo)
{
    hi = __float2bfloat16(x);
    lo = __float2bfloat16(x - __bfloat162float(hi));
}
__device__ inline float bf16s2f(short s)
{
    return __uint_as_float(((unsigned)(unsigned short)s) << 16);
}

// ---------------- W1 (256,81) -> w1t (81,256) ----------------
__global__ __launch_bounds__(256) void k_w1t(const float* __restrict__ w1, float* __restrict__ w1t)
{
    __shared__ float lds[16 * 81];
    const int r0 = blockIdx.x * 16;
    const int tid = threadIdx.x;
    for (int idx = tid; idx < 16 * 81; idx += 256)
        lds[idx] = w1[(size_t)(r0 + idx / 81) * 81 + (idx % 81)];
    __syncthreads();
    for (int idx = tid; idx < 81 * 16; idx += 256) {
        const int i = idx >> 4, rl = idx & 15;
        w1t[(size_t)i * 256 + r0 + rl] = lds[rl * 81 + i];
    }
}

// ---------------- merged: blocks [0,256) = Wp->wt; [256,768) = conv1 (row-buffer) ----------------
__global__ __launch_bounds__(256) void k_pre(const float* __restrict__ wp,
                                             const float* __restrict__ img,
                                             const float* __restrict__ w1t,
                                             const float* __restrict__ b1,
                                             __hip_bfloat16* __restrict__ wt,
                                             __hip_bfloat16* __restrict__ h)
{
    __shared__ float shl[64 * 82];
    const int tid = threadIdx.x;
    if (blockIdx.x < 256) {
        const int co = blockIdx.x;
        for (int ci0 = 0; ci0 < 256; ci0 += 64) {
            for (int idx = tid; idx < 64 * 81; idx += 256) {
                const int cil = idx / 81, t = idx - cil * 81;
                shl[cil * 82 + t] = wp[(size_t)co * KDIM + (size_t)(ci0 + cil) * 81 + t];
            }
            __syncthreads();
            for (int idx = tid; idx < 81 * 64; idx += 256) {
                const int t = idx >> 6, cil = idx & 63;
                __hip_bfloat16 hi, lo;
                split2(shl[cil * 82 + t], hi, lo);
                const size_t o = (size_t)co * KDIM + (size_t)t * 256 + ci0 + cil;
                wt[o] = hi;
                wt[o + WLO_DELTA] = lo;
            }
            __syncthreads();
        }
    } else {
        const int idx = blockIdx.x - 256;
        const int b = idx >> 2;
        const int y0 = (idx & 3) * 5;
        float* simg = shl;
        for (int i = tid; i < IMG * IMG; i += 256) simg[i] = img[(size_t)b * IMG * IMG + i];
        float w[81];
#pragma unroll
        for (int i = 0; i < 81; ++i) w[i] = w1t[(size_t)i * 256 + tid];
        const float bias = b1[tid];
        __syncthreads();
        for (int y = y0; y < y0 + 5; ++y) {
            float a[5][4];
#pragma unroll
            for (int xg = 0; xg < 5; ++xg)
#pragma unroll
                for (int j = 0; j < 4; ++j) a[xg][j] = 0.f;
#pragma unroll
            for (int ky = 0; ky < 9; ++ky) {
                const float* rp = &simg[(y + ky) * IMG];
                float rb[28];
#pragma unroll
                for (int v = 0; v < 7; ++v) {
                    const float4 r = *(const float4*)(rp + v * 4);
                    rb[v * 4 + 0] = r.x; rb[v * 4 + 1] = r.y;
                    rb[v * 4 + 2] = r.z; rb[v * 4 + 3] = r.w;
                }
#pragma unroll
                for (int kx = 0; kx < 9; ++kx) {
                    const float wv = w[ky * 9 + kx];
#pragma unroll
                    for (int xg = 0; xg < 5; ++xg) {
#pragma unroll
                        for (int j = 0; j < 4; ++j)
                            a[xg][j] += wv * rb[xg * 4 + kx + j];
                    }
                }
            }
#pragma unroll
            for (int xg = 0; xg < 5; ++xg) {
                const size_t ob = (((size_t)b * 20 + y) * 20 + xg * 4) * 256 + tid;
#pragma unroll
                for (int j = 0; j < 4; ++j) {
                    __hip_bfloat16 hi, lo;
                    split2(fmaxf(a[xg][j] + bias, 0.f), hi, lo);
                    h[ob + j * 256] = hi;
                    h[ob + j * 256 + HLO_DELTA] = lo;
                }
            }
        }
    }
}

// ---------------- conv2 split-bf16 MFMA implicit GEMM, nz=24 step-split ----------------
// Proven 128Mx256N / 4 waves 64x128 / BK=32 / T2-swizzle structure, unchanged.
// z (0..23) = (tg:3) x (cig:4) x (khalf:2); khalf splits the 54 K-steps of the
// (tg,cig) slice into s in [0,27) / [27,54). ci-chunks stay 64-wide (128B lines)
// so FETCH stays ~122 MB; grid 864 = 3.375 blocks/CU (LDS 48KB -> 3 resident).
__global__ __launch_bounds__(256, 2) void k_conv2m(const __hip_bfloat16* __restrict__ hH,
                                                   const __hip_bfloat16* __restrict__ wH,
                                                   float* __restrict__ pacc)
{
    __shared__ short Alds[128 * 64];
    __shared__ short Blds[256 * 64];
    const int q = gridDim.x >> 3;          // 108
    const int wg = blockIdx.x;
    const int wgid = (wg & 7) * q + (wg >> 3);   // bijective XCD swizzle
    const int z = wgid / 36;               // 0..23
    const int mt = wgid - z * 36;
    const int tg = z >> 3;                 // 0..2
    const int rem = z & 7;
    const int cig = rem >> 1;              // 0..3
    const int kh = rem & 1;                // 0..1
    const int tapbase = tg * 27;
    const int cibase = cig * 64;
    const int sbase = kh * 27;

    const int tid = threadIdx.x;
    const int lane = tid & 63, wid = tid >> 6;
    const int wm = wid >> 1, wn = wid & 1;
    const int lr = lane & 15, kg = lane >> 4;

    const int arow = tid >> 3, asub = tid & 7;
    const int aseg = asub & 3;
    const unsigned lodelA = (asub >= 4) ? (unsigned)HLO_DELTA : 0u;
    const unsigned lodelB = (asub >= 4) ? (unsigned)WLO_DELTA : 0u;

    unsigned aoffA[4];
#pragma unroll
    for (int i = 0; i < 4; ++i) {
        const int row = arow + 32 * i;
        const int m = mt * 128 + row;
        const int bb = m / 36, s = m - bb * 36;
        const int sy = s / 6, sx = s - sy * 6;
        aoffA[i] = (unsigned)((((bb * 20 + 2 * sy) * 20 + 2 * sx) * 256) + aseg * 8) + lodelA;
    }
    unsigned boffB[8];
#pragma unroll
    for (int i = 0; i < 8; ++i)
        boffB[i] = (unsigned)((arow + 32 * i) * KDIM + aseg * 8) + lodelB;
    int awr[4], bwr[8];
#pragma unroll
    for (int i = 0; i < 4; ++i) {
        const int row = arow + 32 * i;
        awr[i] = row * 64 + ((asub * 8) ^ ((row & 7) * 8));
    }
#pragma unroll
    for (int i = 0; i < 8; ++i) {
        const int row = arow + 32 * i;
        bwr[i] = row * 64 + ((asub * 8) ^ ((row & 7) * 8));
    }

    int ardH[4], ardL[4];
#pragma unroll
    for (int f = 0; f < 4; ++f) {
        const int row = wm * 64 + f * 16 + lr;
        const int sw = (row & 7) * 8;
        ardH[f] = row * 64 + ((kg * 8) ^ sw);
        ardL[f] = row * 64 + ((32 + kg * 8) ^ sw);
    }
    int brdH[8], brdL[8];
#pragma unroll
    for (int f = 0; f < 8; ++f) {
        const int row = wn * 128 + f * 16 + lr;
        const int sw = (row & 7) * 8;
        brdH[f] = row * 64 + ((kg * 8) ^ sw);
        brdL[f] = row * 64 + ((32 + kg * 8) ^ sw);
    }

    f32x4 acc[4][8];
#pragma unroll
    for (int i = 0; i < 4; ++i)
#pragma unroll
        for (int j = 0; j < 8; ++j)
            acc[i][j] = (f32x4){0.f, 0.f, 0.f, 0.f};

    short8v ra[4], rb[8];
    auto do_load = [&](int s) {
        const int sg = sbase + s;              // global step in [0,54)
        const int tap = tapbase + (sg >> 1);
        const int ci0 = cibase + (sg & 1) * 32;
        const int ky = tap / 9, kx = tap - ky * 9;
        const unsigned aoff = (unsigned)((ky * 20 + kx) * 256 + ci0);
        const unsigned boff = (unsigned)(tap * 256 + ci0);
#pragma unroll
        for (int i = 0; i < 4; ++i) ra[i] = *(const short8v*)(hH + aoffA[i] + aoff);
#pragma unroll
        for (int i = 0; i < 8; ++i) rb[i] = *(const short8v*)(wH + boffB[i] + boff);
    };

    do_load(0);
    for (int s = 0; s < 27; ++s) {
        __syncthreads();
#pragma unroll
        for (int i = 0; i < 4; ++i) *(short8v*)&Alds[awr[i]] = ra[i];
#pragma unroll
        for (int i = 0; i < 8; ++i) *(short8v*)&Blds[bwr[i]] = rb[i];
        __syncthreads();
        if (s + 1 < 27) do_load(s + 1);
        short8v ah[4], al[4];
#pragma unroll
        for (int f = 0; f < 4; ++f) {
            ah[f] = *(const short8v*)&Alds[ardH[f]];
            al[f] = *(const short8v*)&Alds[ardL[f]];
        }
#pragma unroll
        for (int nf = 0; nf < 8; ++nf) {
            const short8v bh = *(const short8v*)&Blds[brdH[nf]];
            const short8v bl = *(const short8v*)&Blds[brdL[nf]];
#pragma unroll
            for (int f = 0; f < 4; ++f) {
                f32x4 a = acc[f][nf];
                a = __builtin_amdgcn_mfma_f32_16x16x32_bf16(al[f], bh, a, 0, 0, 0);
                a = __builtin_amdgcn_mfma_f32_16x16x32_bf16(ah[f], bl, a, 0, 0, 0);
                a = __builtin_amdgcn_mfma_f32_16x16x32_bf16(ah[f], bh, a, 0, 0, 0);
                acc[f][nf] = a;
            }
        }
    }

    float* po = pacc + (size_t)z * 4608 * 256;
    const int r4 = (lane >> 4) * 4, cc = lane & 15;
#pragma unroll
    for (int f = 0; f < 4; ++f) {
        const int row = mt * 128 + wm * 64 + f * 16 + r4;
#pragma unroll
        for (int nf = 0; nf < 8; ++nf) {
            const int col = wn * 128 + nf * 16 + cc;
#pragma unroll
            for (int j = 0; j < 4; ++j)
                po[(size_t)(row + j) * 256 + col] = acc[f][nf][j];
        }
    }
}

// ---------------- reduce split-K partials + bias + squash -> u (coalesced float4 writes) ----------------
__global__ __launch_bounds__(256) void k_cred(const float* __restrict__ pacc,
                                              const float* __restrict__ bp,
                                              float* __restrict__ u, int nz)
{
    __shared__ float sv[256];
    __shared__ float scg[32];
    const int m = blockIdx.x;
    const int co = threadIdx.x;
    float v = bp[co];
    for (int z = 0; z < nz; ++z) v += pacc[((size_t)z * 4608 + m) * 256 + co];
    sv[co] = v;
    __syncthreads();
    if (co < 32) {
        float sq = 0.f;
#pragma unroll
        for (int dd = 0; dd < 8; ++dd) {
            const float t = sv[dd * 32 + co];
            sq += t * t;
        }
        scg[co] = sqrtf(sq) / (1.f + sq);
    }
    __syncthreads();
    if (co < 64) {
        const int g = co >> 1, half = co & 1;
        const float sc = scg[g];
        float4 w;
        w.x = sv[(half * 4 + 0) * 32 + g] * sc;
        w.y = sv[(half * 4 + 1) * 32 + g] * sc;
        w.z = sv[(half * 4 + 2) * 32 + g] * sc;
        w.w = sv[(half * 4 + 3) * 32 + g] * sc;
        const int bo = m / 36, so = m - bo * 36;
        *(float4*)&u[((size_t)bo * NCAP + g * 36 + so) * 8 + half * 4] = w;
    }
}

// ---------------- u_hat v4: W in regs, LDS-transposed 16B output writes ----------------
__global__ __launch_bounds__(256) void k_uhat(const float* __restrict__ u,
                                              const float* __restrict__ wdig,
                                              __hip_bfloat16* __restrict__ uh)
{
    __shared__ float ulds[8 * 16 * 8];          // 4 KB: [bl][nl][d]
    __shared__ __hip_bfloat16 olds[8 * 16 * 16]; // 4 KB: [bl][nl][e]
    const int n0 = blockIdx.x * 16, c = blockIdx.y;
    const int tid = threadIdx.x;
    const int nl = tid >> 4, e = tid & 15;
    float wreg[8];
#pragma unroll
    for (int d = 0; d < 8; ++d)
        wreg[d] = wdig[(((size_t)c * NCAP + n0 + nl) * 8 + d) * 16 + e];
    const int sbl = tid >> 5, srem = tid & 31;
    const int snn = srem >> 1, shalf = (srem & 1) * 4;
    const int obl = tid >> 5, onl = (tid >> 1) & 15, oeh = tid & 1;

    *(float4*)&ulds[(sbl * 16 + snn) * 8 + shalf] =
        *(const float4*)&u[((size_t)sbl * NCAP + n0 + snn) * 8 + shalf];
    __syncthreads();

    for (int bc = 0; bc < 16; ++bc) {
        const int b0 = bc * 8;
#pragma unroll
        for (int bl = 0; bl < 8; ++bl) {
            float a = 0.f;
#pragma unroll
            for (int d = 0; d < 8; ++d) a += ulds[(bl * 16 + nl) * 8 + d] * wreg[d];
            olds[(bl * 16 + nl) * 16 + e] = __float2bfloat16(a);
        }
        __syncthreads();
        if (bc + 1 < 16) {
            const int b1 = (bc + 1) * 8;
            *(float4*)&ulds[(sbl * 16 + snn) * 8 + shalf] =
                *(const float4*)&u[((size_t)(b1 + sbl) * NCAP + n0 + snn) * 8 + shalf];
        }
        const short8v t = *(const short8v*)&olds[(obl * 16 + onl) * 16 + oeh * 8];
        *(short8v*)((__hip_bfloat16*)uh +
                    (((size_t)c * 128 + b0 + obl) * NCAP + n0 + onl) * 16 + oeh * 8) = t;
        __syncthreads();
    }
}

// ---------------- 3-iter routing per (c,b): u_hat rows in REGISTERS ----------------
__global__ __launch_bounds__(256) void k_routing(const __hip_bfloat16* __restrict__ uhg,
                                                 float* __restrict__ caps)
{
    __shared__ float sred[4][17];
    __shared__ float vvs[16];
    const int c = blockIdx.x, b = blockIdx.y;
    const int tid = threadIdx.x;
    const int w = tid >> 6;

    const __hip_bfloat16* base = uhg + ((size_t)c * 128 + b) * NCAP * 16;
    short8v uhr0[5], uhr1[5];
#pragma unroll
    for (int k = 0; k < 5; ++k) {
        if (k < 4 || tid < 128) {
            const int n = tid + (k << 8);
            uhr0[k] = *(const short8v*)(base + (size_t)n * 16);
            uhr1[k] = *(const short8v*)(base + (size_t)n * 16 + 8);
        }
    }
    float breg[5] = {0.f, 0.f, 0.f, 0.f, 0.f};
    float vv[16];

    for (int it = 0; it < 3; ++it) {
        float lm = fmaxf(fmaxf(breg[0], breg[1]), fmaxf(breg[2], breg[3]));
        if (tid < 128) lm = fmaxf(lm, breg[4]);
#pragma unroll
        for (int o = 1; o < 64; o <<= 1) lm = fmaxf(lm, __shfl_xor(lm, o));
        if ((tid & 63) == 0) sred[w][16] = lm;
        __syncthreads();
        const float mx = fmaxf(fmaxf(sred[0][16], sred[1][16]), fmaxf(sred[2][16], sred[3][16]));
        __syncthreads();
        float wl[5];
        float lz = 0.f;
        float ps[16];
#pragma unroll
        for (int e = 0; e < 16; ++e) ps[e] = 0.f;
#pragma unroll
        for (int k = 0; k < 5; ++k) {
            if (k < 4 || tid < 128) {
                wl[k] = __expf(breg[k] - mx);
                lz += wl[k];
#pragma unroll
                for (int q = 0; q < 8; ++q) {
                    ps[q]     += wl[k] * bf16s2f(uhr0[k][q]);
                    ps[q + 8] += wl[k] * bf16s2f(uhr1[k][q]);
                }
            }
        }
#pragma unroll
        for (int o = 1; o < 64; o <<= 1) {
            lz += __shfl_xor(lz, o);
#pragma unroll
            for (int e = 0; e < 16; ++e) ps[e] += __shfl_xor(ps[e], o);
        }
        if ((tid & 63) == 0) {
#pragma unroll
            for (int e = 0; e < 16; ++e) sred[w][e] = ps[e];
            sred[w][16] = lz;
        }
        __syncthreads();
        if (tid == 0) {
            const float Z = sred[0][16] + sred[1][16] + sred[2][16] + sred[3][16];
            float sv[16], sq = 0.f;
#pragma unroll
            for (int e = 0; e < 16; ++e) {
                sv[e] = (sred[0][e] + sred[1][e] + sred[2][e] + sred[3][e]) / Z;
                sq += sv[e] * sv[e];
            }
            const float sc = sqrtf(sq) / (1.f + sq);
#pragma unroll
            for (int e = 0; e < 16; ++e) vvs[e] = sv[e] * sc;
        }
        __syncthreads();
#pragma unroll
        for (int e = 0; e < 16; ++e) vv[e] = vvs[e];
        if (it < 2) {
#pragma unroll
            for (int k = 0; k < 5; ++k) {
                if (k < 4 || tid < 128) {
                    float dot = 0.f;
#pragma unroll
                    for (int q = 0; q < 8; ++q)
                        dot += bf16s2f(uhr0[k][q]) * vv[q] + bf16s2f(uhr1[k][q]) * vv[q + 8];
                    breg[k] += dot;
                }
            }
        }
    }
    if (tid < 16) caps[((size_t)b * 10 + c) * 16 + tid] = vv[tid];
}

// ---------------- fused argmax-mask + one-hot + decoder fc1 ----------------
__global__ __launch_bounds__(512) void k_self(const float* __restrict__ caps,
                                              const float* __restrict__ Wd1,
                                              const float* __restrict__ bd1,
                                              float* __restrict__ yout,
                                              float* __restrict__ h1)
{
    __shared__ float nrm[16];
    __shared__ float f[16];
    __shared__ int bi;
    const int b = blockIdx.x, j = threadIdx.x;
    if (j < 10) {
        const float* cp = caps + ((size_t)b * 10 + j) * 16;
        float s = 0.f;
#pragma unroll
        for (int q = 0; q < 16; ++q) s += cp[q] * cp[q];
        nrm[j] = s;
    }
    __syncthreads();
    if (j == 0) {
        int best = 0; float bv = nrm[0];
        for (int q = 1; q < 10; ++q) if (nrm[q] > bv) { bv = nrm[q]; best = q; }
        bi = best;
    }
    __syncthreads();
    if (j < 10) yout[b * 10 + j] = (j == bi) ? 1.f : 0.f;
    if (j < 16) f[j] = caps[((size_t)b * 10 + bi) * 16 + j];
    __syncthreads();
    float a = bd1[j];
    const float* w = Wd1 + (size_t)(bi * 16) * 512 + j;
#pragma unroll
    for (int q = 0; q < 16; ++q) a += f[q] * w[q * 512];
    h1[(size_t)b * 512 + j] = fmaxf(a, 0.f);
}

// ---------------- decoder fc2: 512 -> 1024, relu (16-row b-tiles, grid 4x8) ----------------
__global__ __launch_bounds__(256) void k_fc2(const float* __restrict__ h1,
                                             const float* __restrict__ Wd2,
                                             const float* __restrict__ bd2,
                                             float* __restrict__ h2)
{
    __shared__ float lh[16 * 512];
    const int jt = blockIdx.x, bt = blockIdx.y * 16;
    const int tid = threadIdx.x;
    for (int idx = tid; idx < 16 * 512; idx += 256)
        lh[idx] = h1[(size_t)(bt + (idx >> 9)) * 512 + (idx & 511)];
    __syncthreads();
    const int j = jt * 256 + tid;
    float acc[16];
#pragma unroll
    for (int q = 0; q < 16; ++q) acc[q] = 0.f;
    for (int k = 0; k < 512; k += 4) {
        const float w0 = Wd2[(size_t)(k + 0) * 1024 + j];
        const float w1 = Wd2[(size_t)(k + 1) * 1024 + j];
        const float w2 = Wd2[(size_t)(k + 2) * 1024 + j];
        const float w3 = Wd2[(size_t)(k + 3) * 1024 + j];
#pragma unroll
        for (int q = 0; q < 16; ++q) {
            const float4 lv = *(const float4*)&lh[q * 512 + k];
            acc[q] += lv.x * w0 + lv.y * w1 + lv.z * w2 + lv.w * w3;
        }
    }
    const float bias = bd2[j];
#pragma unroll
    for (int q = 0; q < 16; ++q)
        h2[(size_t)(bt + q) * 1024 + j] = fmaxf(acc[q] + bias, 0.f);
}

// ---------------- decoder fc3: 1024 -> 784, sigmoid (8-row b-tiles, grid 4x16) ----------------
__global__ __launch_bounds__(256) void k_fc3(const float* __restrict__ h2,
                                             const float* __restrict__ Wd3,
                                             const float* __restrict__ bd3,
                                             float* __restrict__ rec)
{
    __shared__ float lh[8 * 1024];
    const int jt = blockIdx.x, bt = blockIdx.y * 8;
    const int tid = threadIdx.x;
    for (int idx = tid; idx < 8 * 1024; idx += 256)
        lh[idx] = h2[(size_t)(bt + (idx >> 10)) * 1024 + (idx & 1023)];
    __syncthreads();
    const int j = jt * 256 + tid;
    if (j < 784) {
        float acc[8];
#pragma unroll
        for (int q = 0; q < 8; ++q) acc[q] = 0.f;
        for (int k = 0; k < 1024; k += 4) {
            const float w0 = Wd3[(size_t)(k + 0) * 784 + j];
            const float w1 = Wd3[(size_t)(k + 1) * 784 + j];
            const float w2 = Wd3[(size_t)(k + 2) * 784 + j];
            const float w3 = Wd3[(size_t)(k + 3) * 784 + j];
#pragma unroll
            for (int q = 0; q < 8; ++q) {
                const float4 lv = *(const float4*)&lh[q * 1024 + k];
                acc[q] += lv.x * w0 + lv.y * w1 + lv.z * w2 + lv.w * w3;
            }
        }
        const float bias = bd3[j];
#pragma unroll
        for (int q = 0; q < 8; ++q) {
            const float x = acc[q] + bias;
            rec[(size_t)(bt + q) * 784 + j] = 1.f / (1.f + __expf(-x));
        }
    }
}

extern "C" void kernel_launch(void* const* d_in, const int* in_sizes, int n_in,
                              void* d_out, int out_size, void* d_ws, size_t ws_size,
                              hipStream_t stream)
{
    const float* images = (const float*)d_in[0];
    const float* W1   = (const float*)d_in[1];
    const float* b1   = (const float*)d_in[2];
    const float* Wp   = (const float*)d_in[3];
    const float* bp   = (const float*)d_in[4];
    const float* Wdig = (const float*)d_in[5];
    const float* Wd1  = (const float*)d_in[6];
    const float* bd1  = (const float*)d_in[7];
    const float* Wd2  = (const float*)d_in[8];
    const float* bd2  = (const float*)d_in[9];
    const float* Wd3  = (const float*)d_in[10];
    const float* bd3  = (const float*)d_in[11];
    float* ws  = (float*)d_ws;
    float* out = (float*)d_out;
    __hip_bfloat16* wt = (__hip_bfloat16*)(ws + WT_OFF);   // hi then lo
    __hip_bfloat16* h  = (__hip_bfloat16*)(ws + H_OFF);    // hi then lo
    __hip_bfloat16* uh = (__hip_bfloat16*)(ws + UH_OFF);   // aliases h (dead after conv2m)
    float* u    = ws + U_OFF;     // aliases wt (dead after conv2m)
    float* h1   = ws + H1_OFF;
    float* h2   = ws + H1_OFF + 65536;
    float* w1t  = ws + W1T_OFF;
    float* pacc = ws + PACC_OFF;
    float* caps = out;                       // 128*10*16
    float* rec  = out + 20480;               // 128*784
    float* yout = out + 20480 + 100352;      // 128*10

    // nz=24 via K-step-split of the proven 12 (tg,cig) slices; ci-chunks stay
    // 64-wide (full cache lines). ws for 24 slices confirmed fitting in R10.
    // Fallback to nz=12 semantics is not needed: gate kept for safety.
    const int nz = (ws_size >= (PACC_OFF + (size_t)24 * 1179648) * 4) ? 24 : 12;

    k_w1t   <<<16, 256, 0, stream>>>(W1, w1t);
    k_pre   <<<768, 256, 0, stream>>>(Wp, images, w1t, b1, wt, h);
    if (nz == 24) {
        k_conv2m<<<864, 256, 0, stream>>>(h, wt, pacc);
    } else {
        // degenerate safety path (should not trigger): run step-split halves
        // sequentially into first 12 slices is not implemented; nz=24 is known to fit.
        k_conv2m<<<864, 256, 0, stream>>>(h, wt, pacc);
    }
    k_cred  <<<4608, 256, 0, stream>>>(pacc, bp, u, 24);
    k_uhat  <<<dim3(72, 10), 256, 0, stream>>>(u, Wdig, uh);
    k_routing<<<dim3(10, 128), 256, 0, stream>>>(uh, caps);
    k_self  <<<128, 512, 0, stream>>>(caps, Wd1, bd1, yout, h1);
    k_fc2   <<<dim3(4, 8), 256, 0, stream>>>(h1, Wd2, bd2, h2);
    k_fc3   <<<dim3(4, 16), 256, 0, stream>>>(h2, Wd3, bd3, rec);
}

// Round 15
// 348.404 us; speedup vs baseline: 1.2520x; 1.1131x over previous
//
#include <hip/hip_runtime.h>
#include <hip/hip_bf16.h>

// ---------------- sizes ----------------
#define BATCH 128
#define IMG   28
#define NCAP  1152          // 32*36
#define KDIM  20736         // 256*81
#define HLO_DELTA 13107200  // h_hi -> h_lo element delta (shorts)
#define WLO_DELTA 5308416   // wt_hi -> wt_lo element delta (shorts)

// ws offsets in floats
#define WT_OFF   ((size_t)0)            // wt hi+lo bf16 = 5308416 floats
#define U_OFF    ((size_t)0)            // alias wt (dead after conv2m)
#define H_OFF    ((size_t)5308416)      // h hi+lo bf16 = 13107200 floats
#define UH_OFF   (H_OFF)                // alias h (dead after conv2m): uh bf16 = 11796480 floats
#define H1_OFF   (H_OFF + (size_t)11796480)
#define W1T_OFF  ((size_t)18415616)     // 20736 floats
#define PACC_OFF ((size_t)18436352)     // nz*4608*256 floats (nz=24 confirmed to fit, R10)

using short8v = __attribute__((ext_vector_type(8))) short;
using f32x4   = __attribute__((ext_vector_type(4))) float;

__device__ inline void split2(float x, __hip_bfloat16& hi, __hip_bfloat16& lo)
{
    hi = __float2bfloat16(x);
    lo = __float2bfloat16(x - __bfloat162float(hi));
}
__device__ inline float bf16s2f(short s)
{
    return __uint_as_float(((unsigned)(unsigned short)s) << 16);
}

// ---------------- W1 (256,81) -> w1t (81,256) ----------------
__global__ __launch_bounds__(256) void k_w1t(const float* __restrict__ w1, float* __restrict__ w1t)
{
    __shared__ float lds[16 * 81];
    const int r0 = blockIdx.x * 16;
    const int tid = threadIdx.x;
    for (int idx = tid; idx < 16 * 81; idx += 256)
        lds[idx] = w1[(size_t)(r0 + idx / 81) * 81 + (idx % 81)];
    __syncthreads();
    for (int idx = tid; idx < 81 * 16; idx += 256) {
        const int i = idx >> 4, rl = idx & 15;
        w1t[(size_t)i * 256 + r0 + rl] = lds[rl * 81 + i];
    }
}

// ---------------- merged: blocks [0,256) = Wp->wt; [256,768) = conv1 (row-buffer) ----------------
__global__ __launch_bounds__(256) void k_pre(const float* __restrict__ wp,
                                             const float* __restrict__ img,
                                             const float* __restrict__ w1t,
                                             const float* __restrict__ b1,
                                             __hip_bfloat16* __restrict__ wt,
                                             __hip_bfloat16* __restrict__ h)
{
    __shared__ float shl[64 * 82];
    const int tid = threadIdx.x;
    if (blockIdx.x < 256) {
        const int co = blockIdx.x;
        for (int ci0 = 0; ci0 < 256; ci0 += 64) {
            for (int idx = tid; idx < 64 * 81; idx += 256) {
                const int cil = idx / 81, t = idx - cil * 81;
                shl[cil * 82 + t] = wp[(size_t)co * KDIM + (size_t)(ci0 + cil) * 81 + t];
            }
            __syncthreads();
            for (int idx = tid; idx < 81 * 64; idx += 256) {
                const int t = idx >> 6, cil = idx & 63;
                __hip_bfloat16 hi, lo;
                split2(shl[cil * 82 + t], hi, lo);
                const size_t o = (size_t)co * KDIM + (size_t)t * 256 + ci0 + cil;
                wt[o] = hi;
                wt[o + WLO_DELTA] = lo;
            }
            __syncthreads();
        }
    } else {
        const int idx = blockIdx.x - 256;
        const int b = idx >> 2;
        const int y0 = (idx & 3) * 5;
        float* simg = shl;
        for (int i = tid; i < IMG * IMG; i += 256) simg[i] = img[(size_t)b * IMG * IMG + i];
        float w[81];
#pragma unroll
        for (int i = 0; i < 81; ++i) w[i] = w1t[(size_t)i * 256 + tid];
        const float bias = b1[tid];
        __syncthreads();
        for (int y = y0; y < y0 + 5; ++y) {
            float a[5][4];
#pragma unroll
            for (int xg = 0; xg < 5; ++xg)
#pragma unroll
                for (int j = 0; j < 4; ++j) a[xg][j] = 0.f;
#pragma unroll
            for (int ky = 0; ky < 9; ++ky) {
                const float* rp = &simg[(y + ky) * IMG];
                float rb[28];
#pragma unroll
                for (int v = 0; v < 7; ++v) {
                    const float4 r = *(const float4*)(rp + v * 4);
                    rb[v * 4 + 0] = r.x; rb[v * 4 + 1] = r.y;
                    rb[v * 4 + 2] = r.z; rb[v * 4 + 3] = r.w;
                }
#pragma unroll
                for (int kx = 0; kx < 9; ++kx) {
                    const float wv = w[ky * 9 + kx];
#pragma unroll
                    for (int xg = 0; xg < 5; ++xg) {
#pragma unroll
                        for (int j = 0; j < 4; ++j)
                            a[xg][j] += wv * rb[xg * 4 + kx + j];
                    }
                }
            }
#pragma unroll
            for (int xg = 0; xg < 5; ++xg) {
                const size_t ob = (((size_t)b * 20 + y) * 20 + xg * 4) * 256 + tid;
#pragma unroll
                for (int j = 0; j < 4; ++j) {
                    __hip_bfloat16 hi, lo;
                    split2(fmaxf(a[xg][j] + bias, 0.f), hi, lo);
                    h[ob + j * 256] = hi;
                    h[ob + j * 256 + HLO_DELTA] = lo;
                }
            }
        }
    }
}

// ---------------- conv2 split-bf16 MFMA implicit GEMM, nz=24 step-split ----------------
__global__ __launch_bounds__(256, 2) void k_conv2m(const __hip_bfloat16* __restrict__ hH,
                                                   const __hip_bfloat16* __restrict__ wH,
                                                   float* __restrict__ pacc)
{
    __shared__ short Alds[128 * 64];
    __shared__ short Blds[256 * 64];
    const int q = gridDim.x >> 3;          // 108
    const int wg = blockIdx.x;
    const int wgid = (wg & 7) * q + (wg >> 3);   // bijective XCD swizzle
    const int z = wgid / 36;               // 0..23
    const int mt = wgid - z * 36;
    const int tg = z >> 3;                 // 0..2
    const int rem = z & 7;
    const int cig = rem >> 1;              // 0..3
    const int kh = rem & 1;                // 0..1
    const int tapbase = tg * 27;
    const int cibase = cig * 64;
    const int sbase = kh * 27;

    const int tid = threadIdx.x;
    const int lane = tid & 63, wid = tid >> 6;
    const int wm = wid >> 1, wn = wid & 1;
    const int lr = lane & 15, kg = lane >> 4;

    const int arow = tid >> 3, asub = tid & 7;
    const int aseg = asub & 3;
    const unsigned lodelA = (asub >= 4) ? (unsigned)HLO_DELTA : 0u;
    const unsigned lodelB = (asub >= 4) ? (unsigned)WLO_DELTA : 0u;

    unsigned aoffA[4];
#pragma unroll
    for (int i = 0; i < 4; ++i) {
        const int row = arow + 32 * i;
        const int m = mt * 128 + row;
        const int bb = m / 36, s = m - bb * 36;
        const int sy = s / 6, sx = s - sy * 6;
        aoffA[i] = (unsigned)((((bb * 20 + 2 * sy) * 20 + 2 * sx) * 256) + aseg * 8) + lodelA;
    }
    unsigned boffB[8];
#pragma unroll
    for (int i = 0; i < 8; ++i)
        boffB[i] = (unsigned)((arow + 32 * i) * KDIM + aseg * 8) + lodelB;
    int awr[4], bwr[8];
#pragma unroll
    for (int i = 0; i < 4; ++i) {
        const int row = arow + 32 * i;
        awr[i] = row * 64 + ((asub * 8) ^ ((row & 7) * 8));
    }
#pragma unroll
    for (int i = 0; i < 8; ++i) {
        const int row = arow + 32 * i;
        bwr[i] = row * 64 + ((asub * 8) ^ ((row & 7) * 8));
    }

    int ardH[4], ardL[4];
#pragma unroll
    for (int f = 0; f < 4; ++f) {
        const int row = wm * 64 + f * 16 + lr;
        const int sw = (row & 7) * 8;
        ardH[f] = row * 64 + ((kg * 8) ^ sw);
        ardL[f] = row * 64 + ((32 + kg * 8) ^ sw);
    }
    int brdH[8], brdL[8];
#pragma unroll
    for (int f = 0; f < 8; ++f) {
        const int row = wn * 128 + f * 16 + lr;
        const int sw = (row & 7) * 8;
        brdH[f] = row * 64 + ((kg * 8) ^ sw);
        brdL[f] = row * 64 + ((32 + kg * 8) ^ sw);
    }

    f32x4 acc[4][8];
#pragma unroll
    for (int i = 0; i < 4; ++i)
#pragma unroll
        for (int j = 0; j < 8; ++j)
            acc[i][j] = (f32x4){0.f, 0.f, 0.f, 0.f};

    short8v ra[4], rb[8];
    auto do_load = [&](int s) {
        const int sg = sbase + s;
        const int tap = tapbase + (sg >> 1);
        const int ci0 = cibase + (sg & 1) * 32;
        const int ky = tap / 9, kx = tap - ky * 9;
        const unsigned aoff = (unsigned)((ky * 20 + kx) * 256 + ci0);
        const unsigned boff = (unsigned)(tap * 256 + ci0);
#pragma unroll
        for (int i = 0; i < 4; ++i) ra[i] = *(const short8v*)(hH + aoffA[i] + aoff);
#pragma unroll
        for (int i = 0; i < 8; ++i) rb[i] = *(const short8v*)(wH + boffB[i] + boff);
    };

    do_load(0);
    for (int s = 0; s < 27; ++s) {
        __syncthreads();
#pragma unroll
        for (int i = 0; i < 4; ++i) *(short8v*)&Alds[awr[i]] = ra[i];
#pragma unroll
        for (int i = 0; i < 8; ++i) *(short8v*)&Blds[bwr[i]] = rb[i];
        __syncthreads();
        if (s + 1 < 27) do_load(s + 1);
        short8v ah[4], al[4];
#pragma unroll
        for (int f = 0; f < 4; ++f) {
            ah[f] = *(const short8v*)&Alds[ardH[f]];
            al[f] = *(const short8v*)&Alds[ardL[f]];
        }
#pragma unroll
        for (int nf = 0; nf < 8; ++nf) {
            const short8v bh = *(const short8v*)&Blds[brdH[nf]];
            const short8v bl = *(const short8v*)&Blds[brdL[nf]];
#pragma unroll
            for (int f = 0; f < 4; ++f) {
                f32x4 a = acc[f][nf];
                a = __builtin_amdgcn_mfma_f32_16x16x32_bf16(al[f], bh, a, 0, 0, 0);
                a = __builtin_amdgcn_mfma_f32_16x16x32_bf16(ah[f], bl, a, 0, 0, 0);
                a = __builtin_amdgcn_mfma_f32_16x16x32_bf16(ah[f], bh, a, 0, 0, 0);
                acc[f][nf] = a;
            }
        }
    }

    float* po = pacc + (size_t)z * 4608 * 256;
    const int r4 = (lane >> 4) * 4, cc = lane & 15;
#pragma unroll
    for (int f = 0; f < 4; ++f) {
        const int row = mt * 128 + wm * 64 + f * 16 + r4;
#pragma unroll
        for (int nf = 0; nf < 8; ++nf) {
            const int col = wn * 128 + nf * 16 + cc;
#pragma unroll
            for (int j = 0; j < 4; ++j)
                po[(size_t)(row + j) * 256 + col] = acc[f][nf][j];
        }
    }
}

// ---------------- reduce split-K partials + bias + squash -> u (coalesced float4 writes) ----------------
__global__ __launch_bounds__(256) void k_cred(const float* __restrict__ pacc,
                                              const float* __restrict__ bp,
                                              float* __restrict__ u, int nz)
{
    __shared__ float sv[256];
    __shared__ float scg[32];
    const int m = blockIdx.x;
    const int co = threadIdx.x;
    float v = bp[co];
    for (int z = 0; z < nz; ++z) v += pacc[((size_t)z * 4608 + m) * 256 + co];
    sv[co] = v;
    __syncthreads();
    if (co < 32) {
        float sq = 0.f;
#pragma unroll
        for (int dd = 0; dd < 8; ++dd) {
            const float t = sv[dd * 32 + co];
            sq += t * t;
        }
        scg[co] = sqrtf(sq) / (1.f + sq);
    }
    __syncthreads();
    if (co < 64) {
        const int g = co >> 1, half = co & 1;
        const float sc = scg[g];
        float4 w;
        w.x = sv[(half * 4 + 0) * 32 + g] * sc;
        w.y = sv[(half * 4 + 1) * 32 + g] * sc;
        w.z = sv[(half * 4 + 2) * 32 + g] * sc;
        w.w = sv[(half * 4 + 3) * 32 + g] * sc;
        const int bo = m / 36, so = m - bo * 36;
        *(float4*)&u[((size_t)bo * NCAP + g * 36 + so) * 8 + half * 4] = w;
    }
}

// ---------------- u_hat v4: W in regs, LDS-transposed 16B output writes ----------------
__global__ __launch_bounds__(256) void k_uhat(const float* __restrict__ u,
                                              const float* __restrict__ wdig,
                                              __hip_bfloat16* __restrict__ uh)
{
    __shared__ float ulds[8 * 16 * 8];          // 4 KB: [bl][nl][d]
    __shared__ __hip_bfloat16 olds[8 * 16 * 16]; // 4 KB: [bl][nl][e]
    const int n0 = blockIdx.x * 16, c = blockIdx.y;
    const int tid = threadIdx.x;
    const int nl = tid >> 4, e = tid & 15;
    float wreg[8];
#pragma unroll
    for (int d = 0; d < 8; ++d)
        wreg[d] = wdig[(((size_t)c * NCAP + n0 + nl) * 8 + d) * 16 + e];
    const int sbl = tid >> 5, srem = tid & 31;
    const int snn = srem >> 1, shalf = (srem & 1) * 4;
    const int obl = tid >> 5, onl = (tid >> 1) & 15, oeh = tid & 1;

    *(float4*)&ulds[(sbl * 16 + snn) * 8 + shalf] =
        *(const float4*)&u[((size_t)sbl * NCAP + n0 + snn) * 8 + shalf];
    __syncthreads();

    for (int bc = 0; bc < 16; ++bc) {
        const int b0 = bc * 8;
#pragma unroll
        for (int bl = 0; bl < 8; ++bl) {
            float a = 0.f;
#pragma unroll
            for (int d = 0; d < 8; ++d) a += ulds[(bl * 16 + nl) * 8 + d] * wreg[d];
            olds[(bl * 16 + nl) * 16 + e] = __float2bfloat16(a);
        }
        __syncthreads();
        if (bc + 1 < 16) {
            const int b1 = (bc + 1) * 8;
            *(float4*)&ulds[(sbl * 16 + snn) * 8 + shalf] =
                *(const float4*)&u[((size_t)(b1 + sbl) * NCAP + n0 + snn) * 8 + shalf];
        }
        const short8v t = *(const short8v*)&olds[(obl * 16 + onl) * 16 + oeh * 8];
        *(short8v*)((__hip_bfloat16*)uh +
                    (((size_t)c * 128 + b0 + obl) * NCAP + n0 + onl) * 16 + oeh * 8) = t;
        __syncthreads();
    }
}

// ---------------- 3-iter routing per (c,b): u_hat rows in REGISTERS ----------------
__global__ __launch_bounds__(256) void k_routing(const __hip_bfloat16* __restrict__ uhg,
                                                 float* __restrict__ caps)
{
    __shared__ float sred[4][17];
    __shared__ float vvs[16];
    const int c = blockIdx.x, b = blockIdx.y;
    const int tid = threadIdx.x;
    const int w = tid >> 6;

    const __hip_bfloat16* base = uhg + ((size_t)c * 128 + b) * NCAP * 16;
    short8v uhr0[5], uhr1[5];
#pragma unroll
    for (int k = 0; k < 5; ++k) {
        if (k < 4 || tid < 128) {
            const int n = tid + (k << 8);
            uhr0[k] = *(const short8v*)(base + (size_t)n * 16);
            uhr1[k] = *(const short8v*)(base + (size_t)n * 16 + 8);
        }
    }
    float breg[5] = {0.f, 0.f, 0.f, 0.f, 0.f};
    float vv[16];

    for (int it = 0; it < 3; ++it) {
        float lm = fmaxf(fmaxf(breg[0], breg[1]), fmaxf(breg[2], breg[3]));
        if (tid < 128) lm = fmaxf(lm, breg[4]);
#pragma unroll
        for (int o = 1; o < 64; o <<= 1) lm = fmaxf(lm, __shfl_xor(lm, o));
        if ((tid & 63) == 0) sred[w][16] = lm;
        __syncthreads();
        const float mx = fmaxf(fmaxf(sred[0][16], sred[1][16]), fmaxf(sred[2][16], sred[3][16]));
        __syncthreads();
        float wl[5];
        float lz = 0.f;
        float ps[16];
#pragma unroll
        for (int e = 0; e < 16; ++e) ps[e] = 0.f;
#pragma unroll
        for (int k = 0; k < 5; ++k) {
            if (k < 4 || tid < 128) {
                wl[k] = __expf(breg[k] - mx);
                lz += wl[k];
#pragma unroll
                for (int q = 0; q < 8; ++q) {
                    ps[q]     += wl[k] * bf16s2f(uhr0[k][q]);
                    ps[q + 8] += wl[k] * bf16s2f(uhr1[k][q]);
                }
            }
        }
#pragma unroll
        for (int o = 1; o < 64; o <<= 1) {
            lz += __shfl_xor(lz, o);
#pragma unroll
            for (int e = 0; e < 16; ++e) ps[e] += __shfl_xor(ps[e], o);
        }
        if ((tid & 63) == 0) {
#pragma unroll
            for (int e = 0; e < 16; ++e) sred[w][e] = ps[e];
            sred[w][16] = lz;
        }
        __syncthreads();
        if (tid == 0) {
            const float Z = sred[0][16] + sred[1][16] + sred[2][16] + sred[3][16];
            float sv[16], sq = 0.f;
#pragma unroll
            for (int e = 0; e < 16; ++e) {
                sv[e] = (sred[0][e] + sred[1][e] + sred[2][e] + sred[3][e]) / Z;
                sq += sv[e] * sv[e];
            }
            const float sc = sqrtf(sq) / (1.f + sq);
#pragma unroll
            for (int e = 0; e < 16; ++e) vvs[e] = sv[e] * sc;
        }
        __syncthreads();
#pragma unroll
        for (int e = 0; e < 16; ++e) vv[e] = vvs[e];
        if (it < 2) {
#pragma unroll
            for (int k = 0; k < 5; ++k) {
                if (k < 4 || tid < 128) {
                    float dot = 0.f;
#pragma unroll
                    for (int q = 0; q < 8; ++q)
                        dot += bf16s2f(uhr0[k][q]) * vv[q] + bf16s2f(uhr1[k][q]) * vv[q + 8];
                    breg[k] += dot;
                }
            }
        }
    }
    if (tid < 16) caps[((size_t)b * 10 + c) * 16 + tid] = vv[tid];
}

// ---------------- fused argmax-mask + one-hot + decoder fc1 ----------------
__global__ __launch_bounds__(512) void k_self(const float* __restrict__ caps,
                                              const float* __restrict__ Wd1,
                                              const float* __restrict__ bd1,
                                              float* __restrict__ yout,
                                              float* __restrict__ h1)
{
    __shared__ float nrm[16];
    __shared__ float f[16];
    __shared__ int bi;
    const int b = blockIdx.x, j = threadIdx.x;
    if (j < 10) {
        const float* cp = caps + ((size_t)b * 10 + j) * 16;
        float s = 0.f;
#pragma unroll
        for (int q = 0; q < 16; ++q) s += cp[q] * cp[q];
        nrm[j] = s;
    }
    __syncthreads();
    if (j == 0) {
        int best = 0; float bv = nrm[0];
        for (int q = 1; q < 10; ++q) if (nrm[q] > bv) { bv = nrm[q]; best = q; }
        bi = best;
    }
    __syncthreads();
    if (j < 10) yout[b * 10 + j] = (j == bi) ? 1.f : 0.f;
    if (j < 16) f[j] = caps[((size_t)b * 10 + bi) * 16 + j];
    __syncthreads();
    float a = bd1[j];
    const float* w = Wd1 + (size_t)(bi * 16) * 512 + j;
#pragma unroll
    for (int q = 0; q < 16; ++q) a += f[q] * w[q * 512];
    h1[(size_t)b * 512 + j] = fmaxf(a, 0.f);
}

// ---------------- decoder fc2: 512 -> 1024, relu (4-row b-tiles, grid 4x32) ----------------
__global__ __launch_bounds__(256) void k_fc2(const float* __restrict__ h1,
                                             const float* __restrict__ Wd2,
                                             const float* __restrict__ bd2,
                                             float* __restrict__ h2)
{
    __shared__ float lh[4 * 512];
    const int jt = blockIdx.x, bt = blockIdx.y * 4;
    const int tid = threadIdx.x;
    for (int idx = tid; idx < 4 * 512; idx += 256)
        lh[idx] = h1[(size_t)(bt + (idx >> 9)) * 512 + (idx & 511)];
    __syncthreads();
    const int j = jt * 256 + tid;
    float acc[4];
#pragma unroll
    for (int q = 0; q < 4; ++q) acc[q] = 0.f;
    for (int k = 0; k < 512; k += 4) {
        const float w0 = Wd2[(size_t)(k + 0) * 1024 + j];
        const float w1 = Wd2[(size_t)(k + 1) * 1024 + j];
        const float w2 = Wd2[(size_t)(k + 2) * 1024 + j];
        const float w3 = Wd2[(size_t)(k + 3) * 1024 + j];
#pragma unroll
        for (int q = 0; q < 4; ++q) {
            const float4 lv = *(const float4*)&lh[q * 512 + k];
            acc[q] += lv.x * w0 + lv.y * w1 + lv.z * w2 + lv.w * w3;
        }
    }
    const float bias = bd2[j];
#pragma unroll
    for (int q = 0; q < 4; ++q)
        h2[(size_t)(bt + q) * 1024 + j] = fmaxf(acc[q] + bias, 0.f);
}

// ---------------- decoder fc3: 1024 -> 784, sigmoid (4-row b-tiles, grid 4x32) ----------------
__global__ __launch_bounds__(256) void k_fc3(const float* __restrict__ h2,
                                             const float* __restrict__ Wd3,
                                             const float* __restrict__ bd3,
                                             float* __restrict__ rec)
{
    __shared__ float lh[4 * 1024];
    const int jt = blockIdx.x, bt = blockIdx.y * 4;
    const int tid = threadIdx.x;
    for (int idx = tid; idx < 4 * 1024; idx += 256)
        lh[idx] = h2[(size_t)(bt + (idx >> 10)) * 1024 + (idx & 1023)];
    __syncthreads();
    const int j = jt * 256 + tid;
    if (j < 784) {
        float acc[4];
#pragma unroll
        for (int q = 0; q < 4; ++q) acc[q] = 0.f;
        for (int k = 0; k < 1024; k += 4) {
            const float w0 = Wd3[(size_t)(k + 0) * 784 + j];
            const float w1 = Wd3[(size_t)(k + 1) * 784 + j];
            const float w2 = Wd3[(size_t)(k + 2) * 784 + j];
            const float w3 = Wd3[(size_t)(k + 3) * 784 + j];
#pragma unroll
            for (int q = 0; q < 4; ++q) {
                const float4 lv = *(const float4*)&lh[q * 1024 + k];
                acc[q] += lv.x * w0 + lv.y * w1 + lv.z * w2 + lv.w * w3;
            }
        }
        const float bias = bd3[j];
#pragma unroll
        for (int q = 0; q < 4; ++q) {
            const float x = acc[q] + bias;
            rec[(size_t)(bt + q) * 784 + j] = 1.f / (1.f + __expf(-x));
        }
    }
}

extern "C" void kernel_launch(void* const* d_in, const int* in_sizes, int n_in,
                              void* d_out, int out_size, void* d_ws, size_t ws_size,
                              hipStream_t stream)
{
    const float* images = (const float*)d_in[0];
    const float* W1   = (const float*)d_in[1];
    const float* b1   = (const float*)d_in[2];
    const float* Wp   = (const float*)d_in[3];
    const float* bp   = (const float*)d_in[4];
    const float* Wdig = (const float*)d_in[5];
    const float* Wd1  = (const float*)d_in[6];
    const float* bd1  = (const float*)d_in[7];
    const float* Wd2  = (const float*)d_in[8];
    const float* bd2  = (const float*)d_in[9];
    const float* Wd3  = (const float*)d_in[10];
    const float* bd3  = (const float*)d_in[11];
    float* ws  = (float*)d_ws;
    float* out = (float*)d_out;
    __hip_bfloat16* wt = (__hip_bfloat16*)(ws + WT_OFF);   // hi then lo
    __hip_bfloat16* h  = (__hip_bfloat16*)(ws + H_OFF);    // hi then lo
    __hip_bfloat16* uh = (__hip_bfloat16*)(ws + UH_OFF);   // aliases h (dead after conv2m)
    float* u    = ws + U_OFF;     // aliases wt (dead after conv2m)
    float* h1   = ws + H1_OFF;
    float* h2   = ws + H1_OFF + 65536;
    float* w1t  = ws + W1T_OFF;
    float* pacc = ws + PACC_OFF;
    float* caps = out;                       // 128*10*16
    float* rec  = out + 20480;               // 128*784
    float* yout = out + 20480 + 100352;      // 128*10

    k_w1t   <<<16, 256, 0, stream>>>(W1, w1t);
    k_pre   <<<768, 256, 0, stream>>>(Wp, images, w1t, b1, wt, h);
    k_conv2m<<<864, 256, 0, stream>>>(h, wt, pacc);
    k_cred  <<<4608, 256, 0, stream>>>(pacc, bp, u, 24);
    k_uhat  <<<dim3(72, 10), 256, 0, stream>>>(u, Wdig, uh);
    k_routing<<<dim3(10, 128), 256, 0, stream>>>(uh, caps);
    k_self  <<<128, 512, 0, stream>>>(caps, Wd1, bd1, yout, h1);
    k_fc2   <<<dim3(4, 32), 256, 0, stream>>>(h1, Wd2, bd2, h2);
    k_fc3   <<<dim3(4, 32), 256, 0, stream>>>(h2, Wd3, bd3, rec);
}

// Round 16
// 313.824 us; speedup vs baseline: 1.3899x; 1.1102x over previous
//
#include <hip/hip_runtime.h>
#include <hip/hip_bf16.h>

// ---------------- sizes ----------------
#define BATCH 128
#define IMG   28
#define NCAP  1152          // 32*36
#define KDIM  20736         // 256*81
#define HLO_DELTA 13107200  // h_hi -> h_lo element delta (shorts)
#define WLO_DELTA 5308416   // wt_hi -> wt_lo element delta (shorts)

// ws offsets in floats
#define WT_OFF   ((size_t)0)            // wt hi+lo bf16 = 5308416 floats
#define U_OFF    ((size_t)0)            // alias wt (dead after conv2m)
#define H_OFF    ((size_t)5308416)      // h hi+lo bf16 = 13107200 floats
#define UH_OFF   (H_OFF)                // alias h (dead after conv2m): uh bf16 = 11796480 floats
#define H1_OFF   (H_OFF + (size_t)11796480)
#define W1T_OFF  ((size_t)18415616)     // 20736 floats
#define PACC_OFF ((size_t)18436352)     // 24*4608*256 floats (fits, R10/R14)

using short8v = __attribute__((ext_vector_type(8))) short;
using f32x4   = __attribute__((ext_vector_type(4))) float;

__device__ inline void split2(float x, __hip_bfloat16& hi, __hip_bfloat16& lo)
{
    hi = __float2bfloat16(x);
    lo = __float2bfloat16(x - __bfloat162float(hi));
}
__device__ inline float bf16s2f(short s)
{
    return __uint_as_float(((unsigned)(unsigned short)s) << 16);
}

// ---------------- W1 (256,81) -> w1t (81,256) ----------------
__global__ __launch_bounds__(256) void k_w1t(const float* __restrict__ w1, float* __restrict__ w1t)
{
    __shared__ float lds[16 * 81];
    const int r0 = blockIdx.x * 16;
    const int tid = threadIdx.x;
    for (int idx = tid; idx < 16 * 81; idx += 256)
        lds[idx] = w1[(size_t)(r0 + idx / 81) * 81 + (idx % 81)];
    __syncthreads();
    for (int idx = tid; idx < 81 * 16; idx += 256) {
        const int i = idx >> 4, rl = idx & 15;
        w1t[(size_t)i * 256 + r0 + rl] = lds[rl * 81 + i];
    }
}

// ---------------- merged: blocks [0,256) = Wp->wt; [256,1536) = conv1 (2-row y-tiles) ----------------
__global__ __launch_bounds__(256) void k_pre(const float* __restrict__ wp,
                                             const float* __restrict__ img,
                                             const float* __restrict__ w1t,
                                             const float* __restrict__ b1,
                                             __hip_bfloat16* __restrict__ wt,
                                             __hip_bfloat16* __restrict__ h)
{
    __shared__ float shl[64 * 82];
    const int tid = threadIdx.x;
    if (blockIdx.x < 256) {
        const int co = blockIdx.x;
        for (int ci0 = 0; ci0 < 256; ci0 += 64) {
            for (int idx = tid; idx < 64 * 81; idx += 256) {
                const int cil = idx / 81, t = idx - cil * 81;
                shl[cil * 82 + t] = wp[(size_t)co * KDIM + (size_t)(ci0 + cil) * 81 + t];
            }
            __syncthreads();
            for (int idx = tid; idx < 81 * 64; idx += 256) {
                const int t = idx >> 6, cil = idx & 63;
                __hip_bfloat16 hi, lo;
                split2(shl[cil * 82 + t], hi, lo);
                const size_t o = (size_t)co * KDIM + (size_t)t * 256 + ci0 + cil;
                wt[o] = hi;
                wt[o + WLO_DELTA] = lo;
            }
            __syncthreads();
        }
    } else {
        // conv1: 2-row y-tiles -> 1280 blocks for full-chip latency hiding
        const int idx = blockIdx.x - 256;
        const int b = idx / 10;
        const int y0 = (idx - b * 10) * 2;
        float* simg = shl;
        for (int i = tid; i < IMG * IMG; i += 256) simg[i] = img[(size_t)b * IMG * IMG + i];
        float w[81];
#pragma unroll
        for (int i = 0; i < 81; ++i) w[i] = w1t[(size_t)i * 256 + tid];
        const float bias = b1[tid];
        __syncthreads();
#pragma unroll
        for (int y = y0; y < y0 + 2; ++y) {
            float a[5][4];
#pragma unroll
            for (int xg = 0; xg < 5; ++xg)
#pragma unroll
                for (int j = 0; j < 4; ++j) a[xg][j] = 0.f;
#pragma unroll
            for (int ky = 0; ky < 9; ++ky) {
                const float* rp = &simg[(y + ky) * IMG];
                float rb[28];
#pragma unroll
                for (int v = 0; v < 7; ++v) {
                    const float4 r = *(const float4*)(rp + v * 4);
                    rb[v * 4 + 0] = r.x; rb[v * 4 + 1] = r.y;
                    rb[v * 4 + 2] = r.z; rb[v * 4 + 3] = r.w;
                }
#pragma unroll
                for (int kx = 0; kx < 9; ++kx) {
                    const float wv = w[ky * 9 + kx];
#pragma unroll
                    for (int xg = 0; xg < 5; ++xg) {
#pragma unroll
                        for (int j = 0; j < 4; ++j)
                            a[xg][j] += wv * rb[xg * 4 + kx + j];
                    }
                }
            }
#pragma unroll
            for (int xg = 0; xg < 5; ++xg) {
                const size_t ob = (((size_t)b * 20 + y) * 20 + xg * 4) * 256 + tid;
#pragma unroll
                for (int j = 0; j < 4; ++j) {
                    __hip_bfloat16 hi, lo;
                    split2(fmaxf(a[xg][j] + bias, 0.f), hi, lo);
                    h[ob + j * 256] = hi;
                    h[ob + j * 256 + HLO_DELTA] = lo;
                }
            }
        }
    }
}

// ---------------- conv2 split-bf16 MFMA implicit GEMM, nz=24 step-split ----------------
__global__ __launch_bounds__(256, 2) void k_conv2m(const __hip_bfloat16* __restrict__ hH,
                                                   const __hip_bfloat16* __restrict__ wH,
                                                   float* __restrict__ pacc)
{
    __shared__ short Alds[128 * 64];
    __shared__ short Blds[256 * 64];
    const int q = gridDim.x >> 3;          // 108
    const int wg = blockIdx.x;
    const int wgid = (wg & 7) * q + (wg >> 3);   // bijective XCD swizzle
    const int z = wgid / 36;               // 0..23
    const int mt = wgid - z * 36;
    const int tg = z >> 3;                 // 0..2
    const int rem = z & 7;
    const int cig = rem >> 1;              // 0..3
    const int kh = rem & 1;                // 0..1
    const int tapbase = tg * 27;
    const int cibase = cig * 64;
    const int sbase = kh * 27;

    const int tid = threadIdx.x;
    const int lane = tid & 63, wid = tid >> 6;
    const int wm = wid >> 1, wn = wid & 1;
    const int lr = lane & 15, kg = lane >> 4;

    const int arow = tid >> 3, asub = tid & 7;
    const int aseg = asub & 3;
    const unsigned lodelA = (asub >= 4) ? (unsigned)HLO_DELTA : 0u;
    const unsigned lodelB = (asub >= 4) ? (unsigned)WLO_DELTA : 0u;

    unsigned aoffA[4];
#pragma unroll
    for (int i = 0; i < 4; ++i) {
        const int row = arow + 32 * i;
        const int m = mt * 128 + row;
        const int bb = m / 36, s = m - bb * 36;
        const int sy = s / 6, sx = s - sy * 6;
        aoffA[i] = (unsigned)((((bb * 20 + 2 * sy) * 20 + 2 * sx) * 256) + aseg * 8) + lodelA;
    }
    unsigned boffB[8];
#pragma unroll
    for (int i = 0; i < 8; ++i)
        boffB[i] = (unsigned)((arow + 32 * i) * KDIM + aseg * 8) + lodelB;
    int awr[4], bwr[8];
#pragma unroll
    for (int i = 0; i < 4; ++i) {
        const int row = arow + 32 * i;
        awr[i] = row * 64 + ((asub * 8) ^ ((row & 7) * 8));
    }
#pragma unroll
    for (int i = 0; i < 8; ++i) {
        const int row = arow + 32 * i;
        bwr[i] = row * 64 + ((asub * 8) ^ ((row & 7) * 8));
    }

    int ardH[4], ardL[4];
#pragma unroll
    for (int f = 0; f < 4; ++f) {
        const int row = wm * 64 + f * 16 + lr;
        const int sw = (row & 7) * 8;
        ardH[f] = row * 64 + ((kg * 8) ^ sw);
        ardL[f] = row * 64 + ((32 + kg * 8) ^ sw);
    }
    int brdH[8], brdL[8];
#pragma unroll
    for (int f = 0; f < 8; ++f) {
        const int row = wn * 128 + f * 16 + lr;
        const int sw = (row & 7) * 8;
        brdH[f] = row * 64 + ((kg * 8) ^ sw);
        brdL[f] = row * 64 + ((32 + kg * 8) ^ sw);
    }

    f32x4 acc[4][8];
#pragma unroll
    for (int i = 0; i < 4; ++i)
#pragma unroll
        for (int j = 0; j < 8; ++j)
            acc[i][j] = (f32x4){0.f, 0.f, 0.f, 0.f};

    short8v ra[4], rb[8];
    auto do_load = [&](int s) {
        const int sg = sbase + s;
        const int tap = tapbase + (sg >> 1);
        const int ci0 = cibase + (sg & 1) * 32;
        const int ky = tap / 9, kx = tap - ky * 9;
        const unsigned aoff = (unsigned)((ky * 20 + kx) * 256 + ci0);
        const unsigned boff = (unsigned)(tap * 256 + ci0);
#pragma unroll
        for (int i = 0; i < 4; ++i) ra[i] = *(const short8v*)(hH + aoffA[i] + aoff);
#pragma unroll
        for (int i = 0; i < 8; ++i) rb[i] = *(const short8v*)(wH + boffB[i] + boff);
    };

    do_load(0);
    for (int s = 0; s < 27; ++s) {
        __syncthreads();
#pragma unroll
        for (int i = 0; i < 4; ++i) *(short8v*)&Alds[awr[i]] = ra[i];
#pragma unroll
        for (int i = 0; i < 8; ++i) *(short8v*)&Blds[bwr[i]] = rb[i];
        __syncthreads();
        if (s + 1 < 27) do_load(s + 1);
        short8v ah[4], al[4];
#pragma unroll
        for (int f = 0; f < 4; ++f) {
            ah[f] = *(const short8v*)&Alds[ardH[f]];
            al[f] = *(const short8v*)&Alds[ardL[f]];
        }
#pragma unroll
        for (int nf = 0; nf < 8; ++nf) {
            const short8v bh = *(const short8v*)&Blds[brdH[nf]];
            const short8v bl = *(const short8v*)&Blds[brdL[nf]];
#pragma unroll
            for (int f = 0; f < 4; ++f) {
                f32x4 a = acc[f][nf];
                a = __builtin_amdgcn_mfma_f32_16x16x32_bf16(al[f], bh, a, 0, 0, 0);
                a = __builtin_amdgcn_mfma_f32_16x16x32_bf16(ah[f], bl, a, 0, 0, 0);
                a = __builtin_amdgcn_mfma_f32_16x16x32_bf16(ah[f], bh, a, 0, 0, 0);
                acc[f][nf] = a;
            }
        }
    }

    float* po = pacc + (size_t)z * 4608 * 256;
    const int r4 = (lane >> 4) * 4, cc = lane & 15;
#pragma unroll
    for (int f = 0; f < 4; ++f) {
        const int row = mt * 128 + wm * 64 + f * 16 + r4;
#pragma unroll
        for (int nf = 0; nf < 8; ++nf) {
            const int col = wn * 128 + nf * 16 + cc;
#pragma unroll
            for (int j = 0; j < 4; ++j)
                po[(size_t)(row + j) * 256 + col] = acc[f][nf][j];
        }
    }
}

// ---------------- reduce split-K partials + bias + squash -> u (coalesced float4 writes) ----------------
__global__ __launch_bounds__(256) void k_cred(const float* __restrict__ pacc,
                                              const float* __restrict__ bp,
                                              float* __restrict__ u, int nz)
{
    __shared__ float sv[256];
    __shared__ float scg[32];
    const int m = blockIdx.x;
    const int co = threadIdx.x;
    float v = bp[co];
    for (int z = 0; z < nz; ++z) v += pacc[((size_t)z * 4608 + m) * 256 + co];
    sv[co] = v;
    __syncthreads();
    if (co < 32) {
        float sq = 0.f;
#pragma unroll
        for (int dd = 0; dd < 8; ++dd) {
            const float t = sv[dd * 32 + co];
            sq += t * t;
        }
        scg[co] = sqrtf(sq) / (1.f + sq);
    }
    __syncthreads();
    if (co < 64) {
        const int g = co >> 1, half = co & 1;
        const float sc = scg[g];
        float4 w;
        w.x = sv[(half * 4 + 0) * 32 + g] * sc;
        w.y = sv[(half * 4 + 1) * 32 + g] * sc;
        w.z = sv[(half * 4 + 2) * 32 + g] * sc;
        w.w = sv[(half * 4 + 3) * 32 + g] * sc;
        const int bo = m / 36, so = m - bo * 36;
        *(float4*)&u[((size_t)bo * NCAP + g * 36 + so) * 8 + half * 4] = w;
    }
}

// ---------------- u_hat v4: W in regs, LDS-transposed 16B output writes ----------------
__global__ __launch_bounds__(256) void k_uhat(const float* __restrict__ u,
                                              const float* __restrict__ wdig,
                                              __hip_bfloat16* __restrict__ uh)
{
    __shared__ float ulds[8 * 16 * 8];          // 4 KB: [bl][nl][d]
    __shared__ __hip_bfloat16 olds[8 * 16 * 16]; // 4 KB: [bl][nl][e]
    const int n0 = blockIdx.x * 16, c = blockIdx.y;
    const int tid = threadIdx.x;
    const int nl = tid >> 4, e = tid & 15;
    float wreg[8];
#pragma unroll
    for (int d = 0; d < 8; ++d)
        wreg[d] = wdig[(((size_t)c * NCAP + n0 + nl) * 8 + d) * 16 + e];
    const int sbl = tid >> 5, srem = tid & 31;
    const int snn = srem >> 1, shalf = (srem & 1) * 4;
    const int obl = tid >> 5, onl = (tid >> 1) & 15, oeh = tid & 1;

    *(float4*)&ulds[(sbl * 16 + snn) * 8 + shalf] =
        *(const float4*)&u[((size_t)sbl * NCAP + n0 + snn) * 8 + shalf];
    __syncthreads();

    for (int bc = 0; bc < 16; ++bc) {
        const int b0 = bc * 8;
#pragma unroll
        for (int bl = 0; bl < 8; ++bl) {
            float a = 0.f;
#pragma unroll
            for (int d = 0; d < 8; ++d) a += ulds[(bl * 16 + nl) * 8 + d] * wreg[d];
            olds[(bl * 16 + nl) * 16 + e] = __float2bfloat16(a);
        }
        __syncthreads();
        if (bc + 1 < 16) {
            const int b1 = (bc + 1) * 8;
            *(float4*)&ulds[(sbl * 16 + snn) * 8 + shalf] =
                *(const float4*)&u[((size_t)(b1 + sbl) * NCAP + n0 + snn) * 8 + shalf];
        }
        const short8v t = *(const short8v*)&olds[(obl * 16 + onl) * 16 + oeh * 8];
        *(short8v*)((__hip_bfloat16*)uh +
                    (((size_t)c * 128 + b0 + obl) * NCAP + n0 + onl) * 16 + oeh * 8) = t;
        __syncthreads();
    }
}

// ---------------- 3-iter routing per (c,b): u_hat rows in REGISTERS ----------------
__global__ __launch_bounds__(256) void k_routing(const __hip_bfloat16* __restrict__ uhg,
                                                 float* __restrict__ caps)
{
    __shared__ float sred[4][17];
    __shared__ float vvs[16];
    const int c = blockIdx.x, b = blockIdx.y;
    const int tid = threadIdx.x;
    const int w = tid >> 6;

    const __hip_bfloat16* base = uhg + ((size_t)c * 128 + b) * NCAP * 16;
    short8v uhr0[5], uhr1[5];
#pragma unroll
    for (int k = 0; k < 5; ++k) {
        if (k < 4 || tid < 128) {
            const int n = tid + (k << 8);
            uhr0[k] = *(const short8v*)(base + (size_t)n * 16);
            uhr1[k] = *(const short8v*)(base + (size_t)n * 16 + 8);
        }
    }
    float breg[5] = {0.f, 0.f, 0.f, 0.f, 0.f};
    float vv[16];

    for (int it = 0; it < 3; ++it) {
        float lm = fmaxf(fmaxf(breg[0], breg[1]), fmaxf(breg[2], breg[3]));
        if (tid < 128) lm = fmaxf(lm, breg[4]);
#pragma unroll
        for (int o = 1; o < 64; o <<= 1) lm = fmaxf(lm, __shfl_xor(lm, o));
        if ((tid & 63) == 0) sred[w][16] = lm;
        __syncthreads();
        const float mx = fmaxf(fmaxf(sred[0][16], sred[1][16]), fmaxf(sred[2][16], sred[3][16]));
        __syncthreads();
        float wl[5];
        float lz = 0.f;
        float ps[16];
#pragma unroll
        for (int e = 0; e < 16; ++e) ps[e] = 0.f;
#pragma unroll
        for (int k = 0; k < 5; ++k) {
            if (k < 4 || tid < 128) {
                wl[k] = __expf(breg[k] - mx);
                lz += wl[k];
#pragma unroll
                for (int q = 0; q < 8; ++q) {
                    ps[q]     += wl[k] * bf16s2f(uhr0[k][q]);
                    ps[q + 8] += wl[k] * bf16s2f(uhr1[k][q]);
                }
            }
        }
#pragma unroll
        for (int o = 1; o < 64; o <<= 1) {
            lz += __shfl_xor(lz, o);
#pragma unroll
            for (int e = 0; e < 16; ++e) ps[e] += __shfl_xor(ps[e], o);
        }
        if ((tid & 63) == 0) {
#pragma unroll
            for (int e = 0; e < 16; ++e) sred[w][e] = ps[e];
            sred[w][16] = lz;
        }
        __syncthreads();
        if (tid == 0) {
            const float Z = sred[0][16] + sred[1][16] + sred[2][16] + sred[3][16];
            float sv[16], sq = 0.f;
#pragma unroll
            for (int e = 0; e < 16; ++e) {
                sv[e] = (sred[0][e] + sred[1][e] + sred[2][e] + sred[3][e]) / Z;
                sq += sv[e] * sv[e];
            }
            const float sc = sqrtf(sq) / (1.f + sq);
#pragma unroll
            for (int e = 0; e < 16; ++e) vvs[e] = sv[e] * sc;
        }
        __syncthreads();
#pragma unroll
        for (int e = 0; e < 16; ++e) vv[e] = vvs[e];
        if (it < 2) {
#pragma unroll
            for (int k = 0; k < 5; ++k) {
                if (k < 4 || tid < 128) {
                    float dot = 0.f;
#pragma unroll
                    for (int q = 0; q < 8; ++q)
                        dot += bf16s2f(uhr0[k][q]) * vv[q] + bf16s2f(uhr1[k][q]) * vv[q + 8];
                    breg[k] += dot;
                }
            }
        }
    }
    if (tid < 16) caps[((size_t)b * 10 + c) * 16 + tid] = vv[tid];
}

// ---------------- fused argmax-mask + one-hot + decoder fc1 ----------------
__global__ __launch_bounds__(512) void k_self(const float* __restrict__ caps,
                                              const float* __restrict__ Wd1,
                                              const float* __restrict__ bd1,
                                              float* __restrict__ yout,
                                              float* __restrict__ h1)
{
    __shared__ float nrm[16];
    __shared__ float f[16];
    __shared__ int bi;
    const int b = blockIdx.x, j = threadIdx.x;
    if (j < 10) {
        const float* cp = caps + ((size_t)b * 10 + j) * 16;
        float s = 0.f;
#pragma unroll
        for (int q = 0; q < 16; ++q) s += cp[q] * cp[q];
        nrm[j] = s;
    }
    __syncthreads();
    if (j == 0) {
        int best = 0; float bv = nrm[0];
        for (int q = 1; q < 10; ++q) if (nrm[q] > bv) { bv = nrm[q]; best = q; }
        bi = best;
    }
    __syncthreads();
    if (j < 10) yout[b * 10 + j] = (j == bi) ? 1.f : 0.f;
    if (j < 16) f[j] = caps[((size_t)b * 10 + bi) * 16 + j];
    __syncthreads();
    float a = bd1[j];
    const float* w = Wd1 + (size_t)(bi * 16) * 512 + j;
#pragma unroll
    for (int q = 0; q < 16; ++q) a += f[q] * w[q * 512];
    h1[(size_t)b * 512 + j] = fmaxf(a, 0.f);
}

// ---------------- decoder fc2: 512 -> 1024, relu (2-row b-tiles, grid 4x64) ----------------
__global__ __launch_bounds__(256) void k_fc2(const float* __restrict__ h1,
                                             const float* __restrict__ Wd2,
                                             const float* __restrict__ bd2,
                                             float* __restrict__ h2)
{
    __shared__ float lh[2 * 512];
    const int jt = blockIdx.x, bt = blockIdx.y * 2;
    const int tid = threadIdx.x;
    for (int idx = tid; idx < 2 * 512; idx += 256)
        lh[idx] = h1[(size_t)(bt + (idx >> 9)) * 512 + (idx & 511)];
    __syncthreads();
    const int j = jt * 256 + tid;
    float acc[2];
    acc[0] = 0.f; acc[1] = 0.f;
    for (int k = 0; k < 512; k += 4) {
        const float w0 = Wd2[(size_t)(k + 0) * 1024 + j];
        const float w1 = Wd2[(size_t)(k + 1) * 1024 + j];
        const float w2 = Wd2[(size_t)(k + 2) * 1024 + j];
        const float w3 = Wd2[(size_t)(k + 3) * 1024 + j];
#pragma unroll
        for (int q = 0; q < 2; ++q) {
            const float4 lv = *(const float4*)&lh[q * 512 + k];
            acc[q] += lv.x * w0 + lv.y * w1 + lv.z * w2 + lv.w * w3;
        }
    }
    const float bias = bd2[j];
#pragma unroll
    for (int q = 0; q < 2; ++q)
        h2[(size_t)(bt + q) * 1024 + j] = fmaxf(acc[q] + bias, 0.f);
}

// ---------------- decoder fc3: 1024 -> 784, sigmoid (2-row b-tiles, grid 4x64) ----------------
__global__ __launch_bounds__(256) void k_fc3(const float* __restrict__ h2,
                                             const float* __restrict__ Wd3,
                                             const float* __restrict__ bd3,
                                             float* __restrict__ rec)
{
    __shared__ float lh[2 * 1024];
    const int jt = blockIdx.x, bt = blockIdx.y * 2;
    const int tid = threadIdx.x;
    for (int idx = tid; idx < 2 * 1024; idx += 256)
        lh[idx] = h2[(size_t)(bt + (idx >> 10)) * 1024 + (idx & 1023)];
    __syncthreads();
    const int j = jt * 256 + tid;
    if (j < 784) {
        float acc[2];
        acc[0] = 0.f; acc[1] = 0.f;
        for (int k = 0; k < 1024; k += 4) {
            const float w0 = Wd3[(size_t)(k + 0) * 784 + j];
            const float w1 = Wd3[(size_t)(k + 1) * 784 + j];
            const float w2 = Wd3[(size_t)(k + 2) * 784 + j];
            const float w3 = Wd3[(size_t)(k + 3) * 784 + j];
#pragma unroll
            for (int q = 0; q < 2; ++q) {
                const float4 lv = *(const float4*)&lh[q * 1024 + k];
                acc[q] += lv.x * w0 + lv.y * w1 + lv.z * w2 + lv.w * w3;
            }
        }
        const float bias = bd3[j];
#pragma unroll
        for (int q = 0; q < 2; ++q) {
            const float x = acc[q] + bias;
            rec[(size_t)(bt + q) * 784 + j] = 1.f / (1.f + __expf(-x));
        }
    }
}

extern "C" void kernel_launch(void* const* d_in, const int* in_sizes, int n_in,
                              void* d_out, int out_size, void* d_ws, size_t ws_size,
                              hipStream_t stream)
{
    const float* images = (const float*)d_in[0];
    const float* W1   = (const float*)d_in[1];
    const float* b1   = (const float*)d_in[2];
    const float* Wp   = (const float*)d_in[3];
    const float* bp   = (const float*)d_in[4];
    const float* Wdig = (const float*)d_in[5];
    const float* Wd1  = (const float*)d_in[6];
    const float* bd1  = (const float*)d_in[7];
    const float* Wd2  = (const float*)d_in[8];
    const float* bd2  = (const float*)d_in[9];
    const float* Wd3  = (const float*)d_in[10];
    const float* bd3  = (const float*)d_in[11];
    float* ws  = (float*)d_ws;
    float* out = (float*)d_out;
    __hip_bfloat16* wt = (__hip_bfloat16*)(ws + WT_OFF);   // hi then lo
    __hip_bfloat16* h  = (__hip_bfloat16*)(ws + H_OFF);    // hi then lo
    __hip_bfloat16* uh = (__hip_bfloat16*)(ws + UH_OFF);   // aliases h (dead after conv2m)
    float* u    = ws + U_OFF;     // aliases wt (dead after conv2m)
    float* h1   = ws + H1_OFF;
    float* h2   = ws + H1_OFF + 65536;
    float* w1t  = ws + W1T_OFF;
    float* pacc = ws + PACC_OFF;
    float* caps = out;                       // 128*10*16
    float* rec  = out + 20480;               // 128*784
    float* yout = out + 20480 + 100352;      // 128*10

    k_w1t   <<<16, 256, 0, stream>>>(W1, w1t);
    k_pre   <<<1536, 256, 0, stream>>>(Wp, images, w1t, b1, wt, h);
    k_conv2m<<<864, 256, 0, stream>>>(h, wt, pacc);
    k_cred  <<<4608, 256, 0, stream>>>(pacc, bp, u, 24);
    k_uhat  <<<dim3(72, 10), 256, 0, stream>>>(u, Wdig, uh);
    k_routing<<<dim3(10, 128), 256, 0, stream>>>(uh, caps);
    k_self  <<<128, 512, 0, stream>>>(caps, Wd1, bd1, yout, h1);
    k_fc2   <<<dim3(4, 64), 256, 0, stream>>>(h1, Wd2, bd2, h2);
    k_fc3   <<<dim3(4, 64), 256, 0, stream>>>(h2, Wd3, bd3, rec);
}

// Round 17
// 307.819 us; speedup vs baseline: 1.4170x; 1.0195x over previous
//
#include <hip/hip_runtime.h>
#include <hip/hip_bf16.h>

// ---------------- sizes ----------------
#define BATCH 128
#define IMG   28
#define NCAP  1152          // 32*36
#define KDIM  20736         // 256*81
#define HLO_DELTA 13107200  // h_hi -> h_lo element delta (shorts)
#define WLO_DELTA 5308416   // wt_hi -> wt_lo element delta (shorts)

// ws offsets in floats
#define WT_OFF   ((size_t)0)            // wt hi+lo bf16 = 5308416 floats
#define U_OFF    ((size_t)0)            // alias wt (dead after conv2m)
#define H_OFF    ((size_t)5308416)      // h hi+lo bf16 = 13107200 floats
#define UH_OFF   (H_OFF)                // alias h (dead after conv2m): uh bf16 = 11796480 floats
#define H1_OFF   (H_OFF + (size_t)11796480)
#define W1T_OFF  ((size_t)18415616)     // 20736 floats
#define PACC_OFF ((size_t)18436352)     // 24*4608*256 floats (fits, R10/R14)

using short8v = __attribute__((ext_vector_type(8))) short;
using f32x4   = __attribute__((ext_vector_type(4))) float;

__device__ inline void split2(float x, __hip_bfloat16& hi, __hip_bfloat16& lo)
{
    hi = __float2bfloat16(x);
    lo = __float2bfloat16(x - __bfloat162float(hi));
}
__device__ inline float bf16s2f(short s)
{
    return __uint_as_float(((unsigned)(unsigned short)s) << 16);
}

// ---------------- W1 (256,81) -> w1t (81,256) ----------------
__global__ __launch_bounds__(256) void k_w1t(const float* __restrict__ w1, float* __restrict__ w1t)
{
    __shared__ float lds[16 * 81];
    const int r0 = blockIdx.x * 16;
    const int tid = threadIdx.x;
    for (int idx = tid; idx < 16 * 81; idx += 256)
        lds[idx] = w1[(size_t)(r0 + idx / 81) * 81 + (idx % 81)];
    __syncthreads();
    for (int idx = tid; idx < 81 * 16; idx += 256) {
        const int i = idx >> 4, rl = idx & 15;
        w1t[(size_t)i * 256 + r0 + rl] = lds[rl * 81 + i];
    }
}

// ---------------- merged: blocks [0,256) = Wp->wt; [256,2816) = conv1 (1-row y-tiles) ----------------
__global__ __launch_bounds__(256) void k_pre(const float* __restrict__ wp,
                                             const float* __restrict__ img,
                                             const float* __restrict__ w1t,
                                             const float* __restrict__ b1,
                                             __hip_bfloat16* __restrict__ wt,
                                             __hip_bfloat16* __restrict__ h)
{
    __shared__ float shl[64 * 82];
    const int tid = threadIdx.x;
    if (blockIdx.x < 256) {
        const int co = blockIdx.x;
        for (int ci0 = 0; ci0 < 256; ci0 += 64) {
            for (int idx = tid; idx < 64 * 81; idx += 256) {
                const int cil = idx / 81, t = idx - cil * 81;
                shl[cil * 82 + t] = wp[(size_t)co * KDIM + (size_t)(ci0 + cil) * 81 + t];
            }
            __syncthreads();
            for (int idx = tid; idx < 81 * 64; idx += 256) {
                const int t = idx >> 6, cil = idx & 63;
                __hip_bfloat16 hi, lo;
                split2(shl[cil * 82 + t], hi, lo);
                const size_t o = (size_t)co * KDIM + (size_t)t * 256 + ci0 + cil;
                wt[o] = hi;
                wt[o + WLO_DELTA] = lo;
            }
            __syncthreads();
        }
    } else {
        // conv1: 1-row y-tiles -> 2560 blocks for full-chip latency hiding
        const int idx = blockIdx.x - 256;
        const int b = idx / 20;
        const int y = idx - b * 20;
        float* simg = shl;
        for (int i = tid; i < IMG * IMG; i += 256) simg[i] = img[(size_t)b * IMG * IMG + i];
        float w[81];
#pragma unroll
        for (int i = 0; i < 81; ++i) w[i] = w1t[(size_t)i * 256 + tid];
        const float bias = b1[tid];
        __syncthreads();
        float a[5][4];
#pragma unroll
        for (int xg = 0; xg < 5; ++xg)
#pragma unroll
            for (int j = 0; j < 4; ++j) a[xg][j] = 0.f;
#pragma unroll
        for (int ky = 0; ky < 9; ++ky) {
            const float* rp = &simg[(y + ky) * IMG];
            float rb[28];
#pragma unroll
            for (int v = 0; v < 7; ++v) {
                const float4 r = *(const float4*)(rp + v * 4);
                rb[v * 4 + 0] = r.x; rb[v * 4 + 1] = r.y;
                rb[v * 4 + 2] = r.z; rb[v * 4 + 3] = r.w;
            }
#pragma unroll
            for (int kx = 0; kx < 9; ++kx) {
                const float wv = w[ky * 9 + kx];
#pragma unroll
                for (int xg = 0; xg < 5; ++xg) {
#pragma unroll
                    for (int j = 0; j < 4; ++j)
                        a[xg][j] += wv * rb[xg * 4 + kx + j];
                }
            }
        }
#pragma unroll
        for (int xg = 0; xg < 5; ++xg) {
            const size_t ob = (((size_t)b * 20 + y) * 20 + xg * 4) * 256 + tid;
#pragma unroll
            for (int j = 0; j < 4; ++j) {
                __hip_bfloat16 hi, lo;
                split2(fmaxf(a[xg][j] + bias, 0.f), hi, lo);
                h[ob + j * 256] = hi;
                h[ob + j * 256 + HLO_DELTA] = lo;
            }
        }
    }
}

// ---------------- conv2 split-bf16 MFMA implicit GEMM, nz=24 step-split ----------------
__global__ __launch_bounds__(256, 2) void k_conv2m(const __hip_bfloat16* __restrict__ hH,
                                                   const __hip_bfloat16* __restrict__ wH,
                                                   float* __restrict__ pacc)
{
    __shared__ short Alds[128 * 64];
    __shared__ short Blds[256 * 64];
    const int q = gridDim.x >> 3;          // 108
    const int wg = blockIdx.x;
    const int wgid = (wg & 7) * q + (wg >> 3);   // bijective XCD swizzle
    const int z = wgid / 36;               // 0..23
    const int mt = wgid - z * 36;
    const int tg = z >> 3;                 // 0..2
    const int rem = z & 7;
    const int cig = rem >> 1;              // 0..3
    const int kh = rem & 1;                // 0..1
    const int tapbase = tg * 27;
    const int cibase = cig * 64;
    const int sbase = kh * 27;

    const int tid = threadIdx.x;
    const int lane = tid & 63, wid = tid >> 6;
    const int wm = wid >> 1, wn = wid & 1;
    const int lr = lane & 15, kg = lane >> 4;

    const int arow = tid >> 3, asub = tid & 7;
    const int aseg = asub & 3;
    const unsigned lodelA = (asub >= 4) ? (unsigned)HLO_DELTA : 0u;
    const unsigned lodelB = (asub >= 4) ? (unsigned)WLO_DELTA : 0u;

    unsigned aoffA[4];
#pragma unroll
    for (int i = 0; i < 4; ++i) {
        const int row = arow + 32 * i;
        const int m = mt * 128 + row;
        const int bb = m / 36, s = m - bb * 36;
        const int sy = s / 6, sx = s - sy * 6;
        aoffA[i] = (unsigned)((((bb * 20 + 2 * sy) * 20 + 2 * sx) * 256) + aseg * 8) + lodelA;
    }
    unsigned boffB[8];
#pragma unroll
    for (int i = 0; i < 8; ++i)
        boffB[i] = (unsigned)((arow + 32 * i) * KDIM + aseg * 8) + lodelB;
    int awr[4], bwr[8];
#pragma unroll
    for (int i = 0; i < 4; ++i) {
        const int row = arow + 32 * i;
        awr[i] = row * 64 + ((asub * 8) ^ ((row & 7) * 8));
    }
#pragma unroll
    for (int i = 0; i < 8; ++i) {
        const int row = arow + 32 * i;
        bwr[i] = row * 64 + ((asub * 8) ^ ((row & 7) * 8));
    }

    int ardH[4], ardL[4];
#pragma unroll
    for (int f = 0; f < 4; ++f) {
        const int row = wm * 64 + f * 16 + lr;
        const int sw = (row & 7) * 8;
        ardH[f] = row * 64 + ((kg * 8) ^ sw);
        ardL[f] = row * 64 + ((32 + kg * 8) ^ sw);
    }
    int brdH[8], brdL[8];
#pragma unroll
    for (int f = 0; f < 8; ++f) {
        const int row = wn * 128 + f * 16 + lr;
        const int sw = (row & 7) * 8;
        brdH[f] = row * 64 + ((kg * 8) ^ sw);
        brdL[f] = row * 64 + ((32 + kg * 8) ^ sw);
    }

    f32x4 acc[4][8];
#pragma unroll
    for (int i = 0; i < 4; ++i)
#pragma unroll
        for (int j = 0; j < 8; ++j)
            acc[i][j] = (f32x4){0.f, 0.f, 0.f, 0.f};

    short8v ra[4], rb[8];
    auto do_load = [&](int s) {
        const int sg = sbase + s;
        const int tap = tapbase + (sg >> 1);
        const int ci0 = cibase + (sg & 1) * 32;
        const int ky = tap / 9, kx = tap - ky * 9;
        const unsigned aoff = (unsigned)((ky * 20 + kx) * 256 + ci0);
        const unsigned boff = (unsigned)(tap * 256 + ci0);
#pragma unroll
        for (int i = 0; i < 4; ++i) ra[i] = *(const short8v*)(hH + aoffA[i] + aoff);
#pragma unroll
        for (int i = 0; i < 8; ++i) rb[i] = *(const short8v*)(wH + boffB[i] + boff);
    };

    do_load(0);
    for (int s = 0; s < 27; ++s) {
        __syncthreads();
#pragma unroll
        for (int i = 0; i < 4; ++i) *(short8v*)&Alds[awr[i]] = ra[i];
#pragma unroll
        for (int i = 0; i < 8; ++i) *(short8v*)&Blds[bwr[i]] = rb[i];
        __syncthreads();
        if (s + 1 < 27) do_load(s + 1);
        short8v ah[4], al[4];
#pragma unroll
        for (int f = 0; f < 4; ++f) {
            ah[f] = *(const short8v*)&Alds[ardH[f]];
            al[f] = *(const short8v*)&Alds[ardL[f]];
        }
#pragma unroll
        for (int nf = 0; nf < 8; ++nf) {
            const short8v bh = *(const short8v*)&Blds[brdH[nf]];
            const short8v bl = *(const short8v*)&Blds[brdL[nf]];
#pragma unroll
            for (int f = 0; f < 4; ++f) {
                f32x4 a = acc[f][nf];
                a = __builtin_amdgcn_mfma_f32_16x16x32_bf16(al[f], bh, a, 0, 0, 0);
                a = __builtin_amdgcn_mfma_f32_16x16x32_bf16(ah[f], bl, a, 0, 0, 0);
                a = __builtin_amdgcn_mfma_f32_16x16x32_bf16(ah[f], bh, a, 0, 0, 0);
                acc[f][nf] = a;
            }
        }
    }

    float* po = pacc + (size_t)z * 4608 * 256;
    const int r4 = (lane >> 4) * 4, cc = lane & 15;
#pragma unroll
    for (int f = 0; f < 4; ++f) {
        const int row = mt * 128 + wm * 64 + f * 16 + r4;
#pragma unroll
        for (int nf = 0; nf < 8; ++nf) {
            const int col = wn * 128 + nf * 16 + cc;
#pragma unroll
            for (int j = 0; j < 4; ++j)
                po[(size_t)(row + j) * 256 + col] = acc[f][nf][j];
        }
    }
}

// ---------------- reduce split-K partials + bias + squash -> u (coalesced float4 writes) ----------------
__global__ __launch_bounds__(256) void k_cred(const float* __restrict__ pacc,
                                              const float* __restrict__ bp,
                                              float* __restrict__ u, int nz)
{
    __shared__ float sv[256];
    __shared__ float scg[32];
    const int m = blockIdx.x;
    const int co = threadIdx.x;
    float v = bp[co];
    for (int z = 0; z < nz; ++z) v += pacc[((size_t)z * 4608 + m) * 256 + co];
    sv[co] = v;
    __syncthreads();
    if (co < 32) {
        float sq = 0.f;
#pragma unroll
        for (int dd = 0; dd < 8; ++dd) {
            const float t = sv[dd * 32 + co];
            sq += t * t;
        }
        scg[co] = sqrtf(sq) / (1.f + sq);
    }
    __syncthreads();
    if (co < 64) {
        const int g = co >> 1, half = co & 1;
        const float sc = scg[g];
        float4 w;
        w.x = sv[(half * 4 + 0) * 32 + g] * sc;
        w.y = sv[(half * 4 + 1) * 32 + g] * sc;
        w.z = sv[(half * 4 + 2) * 32 + g] * sc;
        w.w = sv[(half * 4 + 3) * 32 + g] * sc;
        const int bo = m / 36, so = m - bo * 36;
        *(float4*)&u[((size_t)bo * NCAP + g * 36 + so) * 8 + half * 4] = w;
    }
}

// ---------------- u_hat v5: W in regs, b-loop split 4-ways across blockIdx.z ----------------
__global__ __launch_bounds__(256) void k_uhat(const float* __restrict__ u,
                                              const float* __restrict__ wdig,
                                              __hip_bfloat16* __restrict__ uh)
{
    __shared__ float ulds[8 * 16 * 8];          // 4 KB: [bl][nl][d]
    __shared__ __hip_bfloat16 olds[8 * 16 * 16]; // 4 KB: [bl][nl][e]
    const int n0 = blockIdx.x * 16, c = blockIdx.y;
    const int bc0 = blockIdx.z * 4;
    const int tid = threadIdx.x;
    const int nl = tid >> 4, e = tid & 15;
    float wreg[8];
#pragma unroll
    for (int d = 0; d < 8; ++d)
        wreg[d] = wdig[(((size_t)c * NCAP + n0 + nl) * 8 + d) * 16 + e];
    const int sbl = tid >> 5, srem = tid & 31;
    const int snn = srem >> 1, shalf = (srem & 1) * 4;
    const int obl = tid >> 5, onl = (tid >> 1) & 15, oeh = tid & 1;

    *(float4*)&ulds[(sbl * 16 + snn) * 8 + shalf] =
        *(const float4*)&u[((size_t)(bc0 * 8 + sbl) * NCAP + n0 + snn) * 8 + shalf];
    __syncthreads();

    for (int bc = bc0; bc < bc0 + 4; ++bc) {
        const int b0 = bc * 8;
#pragma unroll
        for (int bl = 0; bl < 8; ++bl) {
            float a = 0.f;
#pragma unroll
            for (int d = 0; d < 8; ++d) a += ulds[(bl * 16 + nl) * 8 + d] * wreg[d];
            olds[(bl * 16 + nl) * 16 + e] = __float2bfloat16(a);
        }
        __syncthreads();
        if (bc + 1 < bc0 + 4) {
            const int b1 = (bc + 1) * 8;
            *(float4*)&ulds[(sbl * 16 + snn) * 8 + shalf] =
                *(const float4*)&u[((size_t)(b1 + sbl) * NCAP + n0 + snn) * 8 + shalf];
        }
        const short8v t = *(const short8v*)&olds[(obl * 16 + onl) * 16 + oeh * 8];
        *(short8v*)((__hip_bfloat16*)uh +
                    (((size_t)c * 128 + b0 + obl) * NCAP + n0 + onl) * 16 + oeh * 8) = t;
        __syncthreads();
    }
}

// ---------------- 3-iter routing per (c,b): u_hat rows in REGISTERS ----------------
__global__ __launch_bounds__(256) void k_routing(const __hip_bfloat16* __restrict__ uhg,
                                                 float* __restrict__ caps)
{
    __shared__ float sred[4][17];
    __shared__ float vvs[16];
    const int c = blockIdx.x, b = blockIdx.y;
    const int tid = threadIdx.x;
    const int w = tid >> 6;

    const __hip_bfloat16* base = uhg + ((size_t)c * 128 + b) * NCAP * 16;
    short8v uhr0[5], uhr1[5];
#pragma unroll
    for (int k = 0; k < 5; ++k) {
        if (k < 4 || tid < 128) {
            const int n = tid + (k << 8);
            uhr0[k] = *(const short8v*)(base + (size_t)n * 16);
            uhr1[k] = *(const short8v*)(base + (size_t)n * 16 + 8);
        }
    }
    float breg[5] = {0.f, 0.f, 0.f, 0.f, 0.f};
    float vv[16];

    for (int it = 0; it < 3; ++it) {
        float lm = fmaxf(fmaxf(breg[0], breg[1]), fmaxf(breg[2], breg[3]));
        if (tid < 128) lm = fmaxf(lm, breg[4]);
#pragma unroll
        for (int o = 1; o < 64; o <<= 1) lm = fmaxf(lm, __shfl_xor(lm, o));
        if ((tid & 63) == 0) sred[w][16] = lm;
        __syncthreads();
        const float mx = fmaxf(fmaxf(sred[0][16], sred[1][16]), fmaxf(sred[2][16], sred[3][16]));
        __syncthreads();
        float wl[5];
        float lz = 0.f;
        float ps[16];
#pragma unroll
        for (int e = 0; e < 16; ++e) ps[e] = 0.f;
#pragma unroll
        for (int k = 0; k < 5; ++k) {
            if (k < 4 || tid < 128) {
                wl[k] = __expf(breg[k] - mx);
                lz += wl[k];
#pragma unroll
                for (int q = 0; q < 8; ++q) {
                    ps[q]     += wl[k] * bf16s2f(uhr0[k][q]);
                    ps[q + 8] += wl[k] * bf16s2f(uhr1[k][q]);
                }
            }
        }
#pragma unroll
        for (int o = 1; o < 64; o <<= 1) {
            lz += __shfl_xor(lz, o);
#pragma unroll
            for (int e = 0; e < 16; ++e) ps[e] += __shfl_xor(ps[e], o);
        }
        if ((tid & 63) == 0) {
#pragma unroll
            for (int e = 0; e < 16; ++e) sred[w][e] = ps[e];
            sred[w][16] = lz;
        }
        __syncthreads();
        if (tid == 0) {
            const float Z = sred[0][16] + sred[1][16] + sred[2][16] + sred[3][16];
            float sv[16], sq = 0.f;
#pragma unroll
            for (int e = 0; e < 16; ++e) {
                sv[e] = (sred[0][e] + sred[1][e] + sred[2][e] + sred[3][e]) / Z;
                sq += sv[e] * sv[e];
            }
            const float sc = sqrtf(sq) / (1.f + sq);
#pragma unroll
            for (int e = 0; e < 16; ++e) vvs[e] = sv[e] * sc;
        }
        __syncthreads();
#pragma unroll
        for (int e = 0; e < 16; ++e) vv[e] = vvs[e];
        if (it < 2) {
#pragma unroll
            for (int k = 0; k < 5; ++k) {
                if (k < 4 || tid < 128) {
                    float dot = 0.f;
#pragma unroll
                    for (int q = 0; q < 8; ++q)
                        dot += bf16s2f(uhr0[k][q]) * vv[q] + bf16s2f(uhr1[k][q]) * vv[q + 8];
                    breg[k] += dot;
                }
            }
        }
    }
    if (tid < 16) caps[((size_t)b * 10 + c) * 16 + tid] = vv[tid];
}

// ---------------- fused argmax-mask + one-hot + decoder fc1 ----------------
__global__ __launch_bounds__(512) void k_self(const float* __restrict__ caps,
                                              const float* __restrict__ Wd1,
                                              const float* __restrict__ bd1,
                                              float* __restrict__ yout,
                                              float* __restrict__ h1)
{
    __shared__ float nrm[16];
    __shared__ float f[16];
    __shared__ int bi;
    const int b = blockIdx.x, j = threadIdx.x;
    if (j < 10) {
        const float* cp = caps + ((size_t)b * 10 + j) * 16;
        float s = 0.f;
#pragma unroll
        for (int q = 0; q < 16; ++q) s += cp[q] * cp[q];
        nrm[j] = s;
    }
    __syncthreads();
    if (j == 0) {
        int best = 0; float bv = nrm[0];
        for (int q = 1; q < 10; ++q) if (nrm[q] > bv) { bv = nrm[q]; best = q; }
        bi = best;
    }
    __syncthreads();
    if (j < 10) yout[b * 10 + j] = (j == bi) ? 1.f : 0.f;
    if (j < 16) f[j] = caps[((size_t)b * 10 + bi) * 16 + j];
    __syncthreads();
    float a = bd1[j];
    const float* w = Wd1 + (size_t)(bi * 16) * 512 + j;
#pragma unroll
    for (int q = 0; q < 16; ++q) a += f[q] * w[q * 512];
    h1[(size_t)b * 512 + j] = fmaxf(a, 0.f);
}

// ---------------- decoder fc2: 512 -> 1024, relu (1-row b-tiles, grid 4x128) ----------------
__global__ __launch_bounds__(256) void k_fc2(const float* __restrict__ h1,
                                             const float* __restrict__ Wd2,
                                             const float* __restrict__ bd2,
                                             float* __restrict__ h2)
{
    __shared__ float lh[512];
    const int jt = blockIdx.x, bt = blockIdx.y;
    const int tid = threadIdx.x;
    for (int idx = tid; idx < 512; idx += 256)
        lh[idx] = h1[(size_t)bt * 512 + idx];
    __syncthreads();
    const int j = jt * 256 + tid;
    float acc = 0.f;
    for (int k = 0; k < 512; k += 4) {
        const float w0 = Wd2[(size_t)(k + 0) * 1024 + j];
        const float w1 = Wd2[(size_t)(k + 1) * 1024 + j];
        const float w2 = Wd2[(size_t)(k + 2) * 1024 + j];
        const float w3 = Wd2[(size_t)(k + 3) * 1024 + j];
        const float4 lv = *(const float4*)&lh[k];
        acc += lv.x * w0 + lv.y * w1 + lv.z * w2 + lv.w * w3;
    }
    h2[(size_t)bt * 1024 + j] = fmaxf(acc + bd2[j], 0.f);
}

// ---------------- decoder fc3: 1024 -> 784, sigmoid (1-row b-tiles, grid 4x128) ----------------
__global__ __launch_bounds__(256) void k_fc3(const float* __restrict__ h2,
                                             const float* __restrict__ Wd3,
                                             const float* __restrict__ bd3,
                                             float* __restrict__ rec)
{
    __shared__ float lh[1024];
    const int jt = blockIdx.x, bt = blockIdx.y;
    const int tid = threadIdx.x;
    for (int idx = tid; idx < 1024; idx += 256)
        lh[idx] = h2[(size_t)bt * 1024 + idx];
    __syncthreads();
    const int j = jt * 256 + tid;
    if (j < 784) {
        float acc = 0.f;
        for (int k = 0; k < 1024; k += 4) {
            const float w0 = Wd3[(size_t)(k + 0) * 784 + j];
            const float w1 = Wd3[(size_t)(k + 1) * 784 + j];
            const float w2 = Wd3[(size_t)(k + 2) * 784 + j];
            const float w3 = Wd3[(size_t)(k + 3) * 784 + j];
            const float4 lv = *(const float4*)&lh[k];
            acc += lv.x * w0 + lv.y * w1 + lv.z * w2 + lv.w * w3;
        }
        const float x = acc + bd3[j];
        rec[(size_t)bt * 784 + j] = 1.f / (1.f + __expf(-x));
    }
}

extern "C" void kernel_launch(void* const* d_in, const int* in_sizes, int n_in,
                              void* d_out, int out_size, void* d_ws, size_t ws_size,
                              hipStream_t stream)
{
    const float* images = (const float*)d_in[0];
    const float* W1   = (const float*)d_in[1];
    const float* b1   = (const float*)d_in[2];
    const float* Wp   = (const float*)d_in[3];
    const float* bp   = (const float*)d_in[4];
    const float* Wdig = (const float*)d_in[5];
    const float* Wd1  = (const float*)d_in[6];
    const float* bd1  = (const float*)d_in[7];
    const float* Wd2  = (const float*)d_in[8];
    const float* bd2  = (const float*)d_in[9];
    const float* Wd3  = (const float*)d_in[10];
    const float* bd3  = (const float*)d_in[11];
    float* ws  = (float*)d_ws;
    float* out = (float*)d_out;
    __hip_bfloat16* wt = (__hip_bfloat16*)(ws + WT_OFF);   // hi then lo
    __hip_bfloat16* h  = (__hip_bfloat16*)(ws + H_OFF);    // hi then lo
    __hip_bfloat16* uh = (__hip_bfloat16*)(ws + UH_OFF);   // aliases h (dead after conv2m)
    float* u    = ws + U_OFF;     // aliases wt (dead after conv2m)
    float* h1   = ws + H1_OFF;
    float* h2   = ws + H1_OFF + 65536;
    float* w1t  = ws + W1T_OFF;
    float* pacc = ws + PACC_OFF;
    float* caps = out;                       // 128*10*16
    float* rec  = out + 20480;               // 128*784
    float* yout = out + 20480 + 100352;      // 128*10

    k_w1t   <<<16, 256, 0, stream>>>(W1, w1t);
    k_pre   <<<2816, 256, 0, stream>>>(Wp, images, w1t, b1, wt, h);
    k_conv2m<<<864, 256, 0, stream>>>(h, wt, pacc);
    k_cred  <<<4608, 256, 0, stream>>>(pacc, bp, u, 24);
    k_uhat  <<<dim3(72, 10, 4), 256, 0, stream>>>(u, Wdig, uh);
    k_routing<<<dim3(10, 128), 256, 0, stream>>>(uh, caps);
    k_self  <<<128, 512, 0, stream>>>(caps, Wd1, bd1, yout, h1);
    k_fc2   <<<dim3(4, 128), 256, 0, stream>>>(h1, Wd2, bd2, h2);
    k_fc3   <<<dim3(4, 128), 256, 0, stream>>>(h2, Wd3, bd3, rec);
}

// Round 18
// 307.271 us; speedup vs baseline: 1.4196x; 1.0018x over previous
//
#include <hip/hip_runtime.h>
#include <hip/hip_bf16.h>

// ---------------- sizes ----------------
#define BATCH 128
#define IMG   28
#define NCAP  1152          // 32*36
#define KDIM  20736         // 256*81
#define HLO_DELTA 13107200  // h_hi -> h_lo element delta (shorts)
#define WLO_DELTA 5308416   // wt_hi -> wt_lo element delta (shorts)

// ws offsets in floats
#define WT_OFF   ((size_t)0)            // wt hi+lo bf16 = 5308416 floats
#define U_OFF    ((size_t)0)            // alias wt (dead after conv2m)
#define H_OFF    ((size_t)5308416)      // h hi+lo bf16 = 13107200 floats
#define UH_OFF   (H_OFF)                // alias h (dead after conv2m): uh bf16 = 11796480 floats
#define H1_OFF   (H_OFF + (size_t)11796480)
#define W1T_OFF  ((size_t)18415616)     // 20736 floats
#define PACC_OFF ((size_t)18436352)     // 24*4608*256 floats (fits, R10/R14)

using short8v = __attribute__((ext_vector_type(8))) short;
using f32x4   = __attribute__((ext_vector_type(4))) float;

__device__ inline void split2(float x, __hip_bfloat16& hi, __hip_bfloat16& lo)
{
    hi = __float2bfloat16(x);
    lo = __float2bfloat16(x - __bfloat162float(hi));
}
__device__ inline float bf16s2f(short s)
{
    return __uint_as_float(((unsigned)(unsigned short)s) << 16);
}

// ---------------- W1 (256,81) -> w1t (81,256) ----------------
__global__ __launch_bounds__(256) void k_w1t(const float* __restrict__ w1, float* __restrict__ w1t)
{
    __shared__ float lds[16 * 81];
    const int r0 = blockIdx.x * 16;
    const int tid = threadIdx.x;
    for (int idx = tid; idx < 16 * 81; idx += 256)
        lds[idx] = w1[(size_t)(r0 + idx / 81) * 81 + (idx % 81)];
    __syncthreads();
    for (int idx = tid; idx < 81 * 16; idx += 256) {
        const int i = idx >> 4, rl = idx & 15;
        w1t[(size_t)i * 256 + r0 + rl] = lds[rl * 81 + i];
    }
}

// ---------------- merged: blocks [0,512) = Wp->wt (ci-halves); [512,3072) = conv1 (1-row) ----------------
__global__ __launch_bounds__(256) void k_pre(const float* __restrict__ wp,
                                             const float* __restrict__ img,
                                             const float* __restrict__ w1t,
                                             const float* __restrict__ b1,
                                             __hip_bfloat16* __restrict__ wt,
                                             __hip_bfloat16* __restrict__ h)
{
    __shared__ float shl[64 * 82];
    const int tid = threadIdx.x;
    if (blockIdx.x < 512) {
        const int co = blockIdx.x >> 1;
        const int ci0base = (blockIdx.x & 1) * 128;
        for (int cio = 0; cio < 128; cio += 64) {
            const int ci0 = ci0base + cio;
            for (int idx = tid; idx < 64 * 81; idx += 256) {
                const int cil = idx / 81, t = idx - cil * 81;
                shl[cil * 82 + t] = wp[(size_t)co * KDIM + (size_t)(ci0 + cil) * 81 + t];
            }
            __syncthreads();
            for (int idx = tid; idx < 81 * 64; idx += 256) {
                const int t = idx >> 6, cil = idx & 63;
                __hip_bfloat16 hi, lo;
                split2(shl[cil * 82 + t], hi, lo);
                const size_t o = (size_t)co * KDIM + (size_t)t * 256 + ci0 + cil;
                wt[o] = hi;
                wt[o + WLO_DELTA] = lo;
            }
            __syncthreads();
        }
    } else {
        // conv1: 1-row y-tiles -> 2560 blocks
        const int idx = blockIdx.x - 512;
        const int b = idx / 20;
        const int y = idx - b * 20;
        float* simg = shl;
        for (int i = tid; i < IMG * IMG; i += 256) simg[i] = img[(size_t)b * IMG * IMG + i];
        float w[81];
#pragma unroll
        for (int i = 0; i < 81; ++i) w[i] = w1t[(size_t)i * 256 + tid];
        const float bias = b1[tid];
        __syncthreads();
        float a[5][4];
#pragma unroll
        for (int xg = 0; xg < 5; ++xg)
#pragma unroll
            for (int j = 0; j < 4; ++j) a[xg][j] = 0.f;
#pragma unroll
        for (int ky = 0; ky < 9; ++ky) {
            const float* rp = &simg[(y + ky) * IMG];
            float rb[28];
#pragma unroll
            for (int v = 0; v < 7; ++v) {
                const float4 r = *(const float4*)(rp + v * 4);
                rb[v * 4 + 0] = r.x; rb[v * 4 + 1] = r.y;
                rb[v * 4 + 2] = r.z; rb[v * 4 + 3] = r.w;
            }
#pragma unroll
            for (int kx = 0; kx < 9; ++kx) {
                const float wv = w[ky * 9 + kx];
#pragma unroll
                for (int xg = 0; xg < 5; ++xg) {
#pragma unroll
                    for (int j = 0; j < 4; ++j)
                        a[xg][j] += wv * rb[xg * 4 + kx + j];
                }
            }
        }
#pragma unroll
        for (int xg = 0; xg < 5; ++xg) {
            const size_t ob = (((size_t)b * 20 + y) * 20 + xg * 4) * 256 + tid;
#pragma unroll
            for (int j = 0; j < 4; ++j) {
                __hip_bfloat16 hi, lo;
                split2(fmaxf(a[xg][j] + bias, 0.f), hi, lo);
                h[ob + j * 256] = hi;
                h[ob + j * 256 + HLO_DELTA] = lo;
            }
        }
    }
}

// ---------------- conv2 split-bf16 MFMA implicit GEMM, nz=24 step-split ----------------
__global__ __launch_bounds__(256, 2) void k_conv2m(const __hip_bfloat16* __restrict__ hH,
                                                   const __hip_bfloat16* __restrict__ wH,
                                                   float* __restrict__ pacc)
{
    __shared__ short Alds[128 * 64];
    __shared__ short Blds[256 * 64];
    const int q = gridDim.x >> 3;          // 108
    const int wg = blockIdx.x;
    const int wgid = (wg & 7) * q + (wg >> 3);   // bijective XCD swizzle
    const int z = wgid / 36;               // 0..23
    const int mt = wgid - z * 36;
    const int tg = z >> 3;                 // 0..2
    const int rem = z & 7;
    const int cig = rem >> 1;              // 0..3
    const int kh = rem & 1;                // 0..1
    const int tapbase = tg * 27;
    const int cibase = cig * 64;
    const int sbase = kh * 27;

    const int tid = threadIdx.x;
    const int lane = tid & 63, wid = tid >> 6;
    const int wm = wid >> 1, wn = wid & 1;
    const int lr = lane & 15, kg = lane >> 4;

    const int arow = tid >> 3, asub = tid & 7;
    const int aseg = asub & 3;
    const unsigned lodelA = (asub >= 4) ? (unsigned)HLO_DELTA : 0u;
    const unsigned lodelB = (asub >= 4) ? (unsigned)WLO_DELTA : 0u;

    unsigned aoffA[4];
#pragma unroll
    for (int i = 0; i < 4; ++i) {
        const int row = arow + 32 * i;
        const int m = mt * 128 + row;
        const int bb = m / 36, s = m - bb * 36;
        const int sy = s / 6, sx = s - sy * 6;
        aoffA[i] = (unsigned)((((bb * 20 + 2 * sy) * 20 + 2 * sx) * 256) + aseg * 8) + lodelA;
    }
    unsigned boffB[8];
#pragma unroll
    for (int i = 0; i < 8; ++i)
        boffB[i] = (unsigned)((arow + 32 * i) * KDIM + aseg * 8) + lodelB;
    int awr[4], bwr[8];
#pragma unroll
    for (int i = 0; i < 4; ++i) {
        const int row = arow + 32 * i;
        awr[i] = row * 64 + ((asub * 8) ^ ((row & 7) * 8));
    }
#pragma unroll
    for (int i = 0; i < 8; ++i) {
        const int row = arow + 32 * i;
        bwr[i] = row * 64 + ((asub * 8) ^ ((row & 7) * 8));
    }

    int ardH[4], ardL[4];
#pragma unroll
    for (int f = 0; f < 4; ++f) {
        const int row = wm * 64 + f * 16 + lr;
        const int sw = (row & 7) * 8;
        ardH[f] = row * 64 + ((kg * 8) ^ sw);
        ardL[f] = row * 64 + ((32 + kg * 8) ^ sw);
    }
    int brdH[8], brdL[8];
#pragma unroll
    for (int f = 0; f < 8; ++f) {
        const int row = wn * 128 + f * 16 + lr;
        const int sw = (row & 7) * 8;
        brdH[f] = row * 64 + ((kg * 8) ^ sw);
        brdL[f] = row * 64 + ((32 + kg * 8) ^ sw);
    }

    f32x4 acc[4][8];
#pragma unroll
    for (int i = 0; i < 4; ++i)
#pragma unroll
        for (int j = 0; j < 8; ++j)
            acc[i][j] = (f32x4){0.f, 0.f, 0.f, 0.f};

    short8v ra[4], rb[8];
    auto do_load = [&](int s) {
        const int sg = sbase + s;
        const int tap = tapbase + (sg >> 1);
        const int ci0 = cibase + (sg & 1) * 32;
        const int ky = tap / 9, kx = tap - ky * 9;
        const unsigned aoff = (unsigned)((ky * 20 + kx) * 256 + ci0);
        const unsigned boff = (unsigned)(tap * 256 + ci0);
#pragma unroll
        for (int i = 0; i < 4; ++i) ra[i] = *(const short8v*)(hH + aoffA[i] + aoff);
#pragma unroll
        for (int i = 0; i < 8; ++i) rb[i] = *(const short8v*)(wH + boffB[i] + boff);
    };

    do_load(0);
    for (int s = 0; s < 27; ++s) {
        __syncthreads();
#pragma unroll
        for (int i = 0; i < 4; ++i) *(short8v*)&Alds[awr[i]] = ra[i];
#pragma unroll
        for (int i = 0; i < 8; ++i) *(short8v*)&Blds[bwr[i]] = rb[i];
        __syncthreads();
        if (s + 1 < 27) do_load(s + 1);
        short8v ah[4], al[4];
#pragma unroll
        for (int f = 0; f < 4; ++f) {
            ah[f] = *(const short8v*)&Alds[ardH[f]];
            al[f] = *(const short8v*)&Alds[ardL[f]];
        }
#pragma unroll
        for (int nf = 0; nf < 8; ++nf) {
            const short8v bh = *(const short8v*)&Blds[brdH[nf]];
            const short8v bl = *(const short8v*)&Blds[brdL[nf]];
#pragma unroll
            for (int f = 0; f < 4; ++f) {
                f32x4 a = acc[f][nf];
                a = __builtin_amdgcn_mfma_f32_16x16x32_bf16(al[f], bh, a, 0, 0, 0);
                a = __builtin_amdgcn_mfma_f32_16x16x32_bf16(ah[f], bl, a, 0, 0, 0);
                a = __builtin_amdgcn_mfma_f32_16x16x32_bf16(ah[f], bh, a, 0, 0, 0);
                acc[f][nf] = a;
            }
        }
    }

    float* po = pacc + (size_t)z * 4608 * 256;
    const int r4 = (lane >> 4) * 4, cc = lane & 15;
#pragma unroll
    for (int f = 0; f < 4; ++f) {
        const int row = mt * 128 + wm * 64 + f * 16 + r4;
#pragma unroll
        for (int nf = 0; nf < 8; ++nf) {
            const int col = wn * 128 + nf * 16 + cc;
#pragma unroll
            for (int j = 0; j < 4; ++j)
                po[(size_t)(row + j) * 256 + col] = acc[f][nf][j];
        }
    }
}

// ---------------- reduce split-K partials + bias + squash -> u (coalesced float4 writes) ----------------
__global__ __launch_bounds__(256) void k_cred(const float* __restrict__ pacc,
                                              const float* __restrict__ bp,
                                              float* __restrict__ u, int nz)
{
    __shared__ float sv[256];
    __shared__ float scg[32];
    const int m = blockIdx.x;
    const int co = threadIdx.x;
    float v = bp[co];
    for (int z = 0; z < nz; ++z) v += pacc[((size_t)z * 4608 + m) * 256 + co];
    sv[co] = v;
    __syncthreads();
    if (co < 32) {
        float sq = 0.f;
#pragma unroll
        for (int dd = 0; dd < 8; ++dd) {
            const float t = sv[dd * 32 + co];
            sq += t * t;
        }
        scg[co] = sqrtf(sq) / (1.f + sq);
    }
    __syncthreads();
    if (co < 64) {
        const int g = co >> 1, half = co & 1;
        const float sc = scg[g];
        float4 w;
        w.x = sv[(half * 4 + 0) * 32 + g] * sc;
        w.y = sv[(half * 4 + 1) * 32 + g] * sc;
        w.z = sv[(half * 4 + 2) * 32 + g] * sc;
        w.w = sv[(half * 4 + 3) * 32 + g] * sc;
        const int bo = m / 36, so = m - bo * 36;
        *(float4*)&u[((size_t)bo * NCAP + g * 36 + so) * 8 + half * 4] = w;
    }
}

// ---------------- u_hat v6: W in regs, b-loop split 8-ways across blockIdx.z ----------------
__global__ __launch_bounds__(256) void k_uhat(const float* __restrict__ u,
                                              const float* __restrict__ wdig,
                                              __hip_bfloat16* __restrict__ uh)
{
    __shared__ float ulds[8 * 16 * 8];          // 4 KB: [bl][nl][d]
    __shared__ __hip_bfloat16 olds[8 * 16 * 16]; // 4 KB: [bl][nl][e]
    const int n0 = blockIdx.x * 16, c = blockIdx.y;
    const int bc0 = blockIdx.z * 2;
    const int tid = threadIdx.x;
    const int nl = tid >> 4, e = tid & 15;
    float wreg[8];
#pragma unroll
    for (int d = 0; d < 8; ++d)
        wreg[d] = wdig[(((size_t)c * NCAP + n0 + nl) * 8 + d) * 16 + e];
    const int sbl = tid >> 5, srem = tid & 31;
    const int snn = srem >> 1, shalf = (srem & 1) * 4;
    const int obl = tid >> 5, onl = (tid >> 1) & 15, oeh = tid & 1;

    *(float4*)&ulds[(sbl * 16 + snn) * 8 + shalf] =
        *(const float4*)&u[((size_t)(bc0 * 8 + sbl) * NCAP + n0 + snn) * 8 + shalf];
    __syncthreads();

    for (int bc = bc0; bc < bc0 + 2; ++bc) {
        const int b0 = bc * 8;
#pragma unroll
        for (int bl = 0; bl < 8; ++bl) {
            float a = 0.f;
#pragma unroll
            for (int d = 0; d < 8; ++d) a += ulds[(bl * 16 + nl) * 8 + d] * wreg[d];
            olds[(bl * 16 + nl) * 16 + e] = __float2bfloat16(a);
        }
        __syncthreads();
        if (bc + 1 < bc0 + 2) {
            const int b1 = (bc + 1) * 8;
            *(float4*)&ulds[(sbl * 16 + snn) * 8 + shalf] =
                *(const float4*)&u[((size_t)(b1 + sbl) * NCAP + n0 + snn) * 8 + shalf];
        }
        const short8v t = *(const short8v*)&olds[(obl * 16 + onl) * 16 + oeh * 8];
        *(short8v*)((__hip_bfloat16*)uh +
                    (((size_t)c * 128 + b0 + obl) * NCAP + n0 + onl) * 16 + oeh * 8) = t;
        __syncthreads();
    }
}

// ---------------- 3-iter routing per (c,b): u_hat rows in REGISTERS ----------------
__global__ __launch_bounds__(256) void k_routing(const __hip_bfloat16* __restrict__ uhg,
                                                 float* __restrict__ caps)
{
    __shared__ float sred[4][17];
    __shared__ float vvs[16];
    const int c = blockIdx.x, b = blockIdx.y;
    const int tid = threadIdx.x;
    const int w = tid >> 6;

    const __hip_bfloat16* base = uhg + ((size_t)c * 128 + b) * NCAP * 16;
    short8v uhr0[5], uhr1[5];
#pragma unroll
    for (int k = 0; k < 5; ++k) {
        if (k < 4 || tid < 128) {
            const int n = tid + (k << 8);
            uhr0[k] = *(const short8v*)(base + (size_t)n * 16);
            uhr1[k] = *(const short8v*)(base + (size_t)n * 16 + 8);
        }
    }
    float breg[5] = {0.f, 0.f, 0.f, 0.f, 0.f};
    float vv[16];

    for (int it = 0; it < 3; ++it) {
        float lm = fmaxf(fmaxf(breg[0], breg[1]), fmaxf(breg[2], breg[3]));
        if (tid < 128) lm = fmaxf(lm, breg[4]);
#pragma unroll
        for (int o = 1; o < 64; o <<= 1) lm = fmaxf(lm, __shfl_xor(lm, o));
        if ((tid & 63) == 0) sred[w][16] = lm;
        __syncthreads();
        const float mx = fmaxf(fmaxf(sred[0][16], sred[1][16]), fmaxf(sred[2][16], sred[3][16]));
        __syncthreads();
        float wl[5];
        float lz = 0.f;
        float ps[16];
#pragma unroll
        for (int e = 0; e < 16; ++e) ps[e] = 0.f;
#pragma unroll
        for (int k = 0; k < 5; ++k) {
            if (k < 4 || tid < 128) {
                wl[k] = __expf(breg[k] - mx);
                lz += wl[k];
#pragma unroll
                for (int q = 0; q < 8; ++q) {
                    ps[q]     += wl[k] * bf16s2f(uhr0[k][q]);
                    ps[q + 8] += wl[k] * bf16s2f(uhr1[k][q]);
                }
            }
        }
#pragma unroll
        for (int o = 1; o < 64; o <<= 1) {
            lz += __shfl_xor(lz, o);
#pragma unroll
            for (int e = 0; e < 16; ++e) ps[e] += __shfl_xor(ps[e], o);
        }
        if ((tid & 63) == 0) {
#pragma unroll
            for (int e = 0; e < 16; ++e) sred[w][e] = ps[e];
            sred[w][16] = lz;
        }
        __syncthreads();
        if (tid == 0) {
            const float Z = sred[0][16] + sred[1][16] + sred[2][16] + sred[3][16];
            float sv[16], sq = 0.f;
#pragma unroll
            for (int e = 0; e < 16; ++e) {
                sv[e] = (sred[0][e] + sred[1][e] + sred[2][e] + sred[3][e]) / Z;
                sq += sv[e] * sv[e];
            }
            const float sc = sqrtf(sq) / (1.f + sq);
#pragma unroll
            for (int e = 0; e < 16; ++e) vvs[e] = sv[e] * sc;
        }
        __syncthreads();
#pragma unroll
        for (int e = 0; e < 16; ++e) vv[e] = vvs[e];
        if (it < 2) {
#pragma unroll
            for (int k = 0; k < 5; ++k) {
                if (k < 4 || tid < 128) {
                    float dot = 0.f;
#pragma unroll
                    for (int q = 0; q < 8; ++q)
                        dot += bf16s2f(uhr0[k][q]) * vv[q] + bf16s2f(uhr1[k][q]) * vv[q + 8];
                    breg[k] += dot;
                }
            }
        }
    }
    if (tid < 16) caps[((size_t)b * 10 + c) * 16 + tid] = vv[tid];
}

// ---------------- fused argmax-mask + one-hot + decoder fc1 ----------------
__global__ __launch_bounds__(512) void k_self(const float* __restrict__ caps,
                                              const float* __restrict__ Wd1,
                                              const float* __restrict__ bd1,
                                              float* __restrict__ yout,
                                              float* __restrict__ h1)
{
    __shared__ float nrm[16];
    __shared__ float f[16];
    __shared__ int bi;
    const int b = blockIdx.x, j = threadIdx.x;
    if (j < 10) {
        const float* cp = caps + ((size_t)b * 10 + j) * 16;
        float s = 0.f;
#pragma unroll
        for (int q = 0; q < 16; ++q) s += cp[q] * cp[q];
        nrm[j] = s;
    }
    __syncthreads();
    if (j == 0) {
        int best = 0; float bv = nrm[0];
        for (int q = 1; q < 10; ++q) if (nrm[q] > bv) { bv = nrm[q]; best = q; }
        bi = best;
    }
    __syncthreads();
    if (j < 10) yout[b * 10 + j] = (j == bi) ? 1.f : 0.f;
    if (j < 16) f[j] = caps[((size_t)b * 10 + bi) * 16 + j];
    __syncthreads();
    float a = bd1[j];
    const float* w = Wd1 + (size_t)(bi * 16) * 512 + j;
#pragma unroll
    for (int q = 0; q < 16; ++q) a += f[q] * w[q * 512];
    h1[(size_t)b * 512 + j] = fmaxf(a, 0.f);
}

// ---------------- decoder fc2: 512 -> 1024, relu (1-row b-tiles, grid 4x128) ----------------
__global__ __launch_bounds__(256) void k_fc2(const float* __restrict__ h1,
                                             const float* __restrict__ Wd2,
                                             const float* __restrict__ bd2,
                                             float* __restrict__ h2)
{
    __shared__ float lh[512];
    const int jt = blockIdx.x, bt = blockIdx.y;
    const int tid = threadIdx.x;
    for (int idx = tid; idx < 512; idx += 256)
        lh[idx] = h1[(size_t)bt * 512 + idx];
    __syncthreads();
    const int j = jt * 256 + tid;
    float acc = 0.f;
    for (int k = 0; k < 512; k += 4) {
        const float w0 = Wd2[(size_t)(k + 0) * 1024 + j];
        const float w1 = Wd2[(size_t)(k + 1) * 1024 + j];
        const float w2 = Wd2[(size_t)(k + 2) * 1024 + j];
        const float w3 = Wd2[(size_t)(k + 3) * 1024 + j];
        const float4 lv = *(const float4*)&lh[k];
        acc += lv.x * w0 + lv.y * w1 + lv.z * w2 + lv.w * w3;
    }
    h2[(size_t)bt * 1024 + j] = fmaxf(acc + bd2[j], 0.f);
}

// ---------------- decoder fc3: 1024 -> 784, sigmoid (1-row b-tiles, grid 4x128) ----------------
__global__ __launch_bounds__(256) void k_fc3(const float* __restrict__ h2,
                                             const float* __restrict__ Wd3,
                                             const float* __restrict__ bd3,
                                             float* __restrict__ rec)
{
    __shared__ float lh[1024];
    const int jt = blockIdx.x, bt = blockIdx.y;
    const int tid = threadIdx.x;
    for (int idx = tid; idx < 1024; idx += 256)
        lh[idx] = h2[(size_t)bt * 1024 + idx];
    __syncthreads();
    const int j = jt * 256 + tid;
    if (j < 784) {
        float acc = 0.f;
        for (int k = 0; k < 1024; k += 4) {
            const float w0 = Wd3[(size_t)(k + 0) * 784 + j];
            const float w1 = Wd3[(size_t)(k + 1) * 784 + j];
            const float w2 = Wd3[(size_t)(k + 2) * 784 + j];
            const float w3 = Wd3[(size_t)(k + 3) * 784 + j];
            const float4 lv = *(const float4*)&lh[k];
            acc += lv.x * w0 + lv.y * w1 + lv.z * w2 + lv.w * w3;
        }
        const float x = acc + bd3[j];
        rec[(size_t)bt * 784 + j] = 1.f / (1.f + __expf(-x));
    }
}

extern "C" void kernel_launch(void* const* d_in, const int* in_sizes, int n_in,
                              void* d_out, int out_size, void* d_ws, size_t ws_size,
                              hipStream_t stream)
{
    const float* images = (const float*)d_in[0];
    const float* W1   = (const float*)d_in[1];
    const float* b1   = (const float*)d_in[2];
    const float* Wp   = (const float*)d_in[3];
    const float* bp   = (const float*)d_in[4];
    const float* Wdig = (const float*)d_in[5];
    const float* Wd1  = (const float*)d_in[6];
    const float* bd1  = (const float*)d_in[7];
    const float* Wd2  = (const float*)d_in[8];
    const float* bd2  = (const float*)d_in[9];
    const float* Wd3  = (const float*)d_in[10];
    const float* bd3  = (const float*)d_in[11];
    float* ws  = (float*)d_ws;
    float* out = (float*)d_out;
    __hip_bfloat16* wt = (__hip_bfloat16*)(ws + WT_OFF);   // hi then lo
    __hip_bfloat16* h  = (__hip_bfloat16*)(ws + H_OFF);    // hi then lo
    __hip_bfloat16* uh = (__hip_bfloat16*)(ws + UH_OFF);   // aliases h (dead after conv2m)
    float* u    = ws + U_OFF;     // aliases wt (dead after conv2m)
    float* h1   = ws + H1_OFF;
    float* h2   = ws + H1_OFF + 65536;
    float* w1t  = ws + W1T_OFF;
    float* pacc = ws + PACC_OFF;
    float* caps = out;                       // 128*10*16
    float* rec  = out + 20480;               // 128*784
    float* yout = out + 20480 + 100352;      // 128*10

    k_w1t   <<<16, 256, 0, stream>>>(W1, w1t);
    k_pre   <<<3072, 256, 0, stream>>>(Wp, images, w1t, b1, wt, h);
    k_conv2m<<<864, 256, 0, stream>>>(h, wt, pacc);
    k_cred  <<<4608, 256, 0, stream>>>(pacc, bp, u, 24);
    k_uhat  <<<dim3(72, 10, 8), 256, 0, stream>>>(u, Wdig, uh);
    k_routing<<<dim3(10, 128), 256, 0, stream>>>(uh, caps);
    k_self  <<<128, 512, 0, stream>>>(caps, Wd1, bd1, yout, h1);
    k_fc2   <<<dim3(4, 128), 256, 0, stream>>>(h1, Wd2, bd2, h2);
    k_fc3   <<<dim3(4, 128), 256, 0, stream>>>(h2, Wd3, bd3, rec);
}